// Round 4
// baseline (1460.773 us; speedup 1.0000x reference)
//
#include <hip/hip_runtime.h>
#include <cstdio>

#define NB 40
#define NS 8
#define NT 441
#define NTP 448
#define DIN 768
#define DD 128
#define NTOT (NB*NT)
#define FSCALE 0.08838834764831843f

typedef short s8v __attribute__((ext_vector_type(8)));
typedef float f4v __attribute__((ext_vector_type(4)));

__device__ inline ushort f2bf(float f){
  unsigned u = __float_as_uint(f);
  unsigned r = (u + 0x7fffu + ((u >> 16) & 1u)) >> 16;
  return (ushort)r;
}
__device__ inline float bf2f(ushort h){ return __uint_as_float(((unsigned)h) << 16); }
__device__ inline float dot4(float4 a, float4 b){
  return fmaf(a.x,b.x, fmaf(a.y,b.y, fmaf(a.z,b.z, a.w*b.w)));
}

struct PP {
  const float *inputs; const int *tok_idx; const float *abs_grid;
  const float *slots_init, *Sp_init, *Ss_init;
  const float *WQ, *ln_g, *ln_b;
  const float *gru_w_ih, *gru_w_hh, *gru_b_ih, *gru_b_hh;
  const float *mlp_ln_g, *mlp_ln_b, *mlp_w1, *mlp_b1, *mlp_w2, *mlp_b2;
  const float *WK, *WV, *Wg, *bg, *Wf1, *bf1, *Wf2, *bf2;
  const float *im_ln1_g, *im_ln1_b, *im_w1, *im_b1, *im_w2, *im_b2, *im_ln2_g, *im_ln2_b;
  const float *fin_w, *fin_b;
  float *x, *A_K, *A_V, *WKf, *WVf, *Wg1, *c1, *Wf2T;
  float *WQT, *gihT, *ghhT, *w1T, *w2T, *finT;
  ushort *xnh, *xnl, *hh, *hl, *W1Th, *W1Tl, *W2Th, *W2Tl;
  float *out;
};

// ---------- weight prep: WKf=WK@Wf1, WVf=WV@Wf1, Wg1=Wg@Wf1, c1=bg@Wf1+bf1, Wf2T ----------
__global__ __launch_bounds__(128) void prep_weights(PP p){
  int r = blockIdx.x, d = threadIdx.x;
  float accK = 0.f, accV = 0.f;
  for (int kk = 0; kk < DD; kk++){
    float w = p.Wf1[kk*DD + d];
    accK = fmaf(p.WK[r*DD+kk], w, accK);
    accV = fmaf(p.WV[r*DD+kk], w, accV);
  }
  p.WKf[r*DD+d] = accK; p.WVf[r*DD+d] = accV;
  if (r < 2){
    float a = 0.f;
    for (int kk = 0; kk < DD; kk++) a = fmaf(p.Wg[r*DD+kk], p.Wf1[kk*DD+d], a);
    p.Wg1[r*DD+d] = a;
  }
  if (r == 2){
    float a = 0.f;
    for (int kk = 0; kk < DD; kk++) a = fmaf(p.bg[kk], p.Wf1[kk*DD+d], a);
    p.c1[d] = a + p.bf1[d];
  }
  p.Wf2T[d*DD + r] = p.Wf2[r*DD + d];
}

// ---------- transposes for the fused iteration kernel ----------
__global__ __launch_bounds__(256) void prep_transposes(PP p){
  long i = (long)blockIdx.x*256 + threadIdx.x;
  if (i < 16384){ int r = i >> 7, c = i & 127; p.WQT[c*128 + r] = p.WQ[i]; return; }
  i -= 16384;
  if (i < 49152){ int r = i / 384, c = i % 384; p.gihT[c*128 + r] = p.gru_w_ih[i]; return; }
  i -= 49152;
  if (i < 49152){ int r = i / 384, c = i % 384; p.ghhT[c*128 + r] = p.gru_w_hh[i]; return; }
  i -= 49152;
  if (i < 65536){ int r = i / 512, c = i % 512; p.w1T[c*128 + r] = p.mlp_w1[i]; return; }
  i -= 65536;
  if (i < 65536){ int r = i / 128, c = i % 128; p.w2T[c*512 + r] = p.mlp_w2[i]; return; }
  i -= 65536;
  { int r = i >> 7, c = i & 127; p.finT[c*128 + r] = p.fin_w[i]; }
}

// ---------- transpose + bf16 split: WT[n][k] = W[k][n] ----------
__global__ __launch_bounds__(256) void transpose_split(const float* __restrict__ W,
                                                       ushort* __restrict__ WTh,
                                                       ushort* __restrict__ WTl,
                                                       int K, int N){
  __shared__ float tile[64][65];
  int tid = threadIdx.x;
  int k0 = blockIdx.x * 64, n0 = blockIdx.y * 64;
  #pragma unroll
  for (int i = 0; i < 4; i++){
    int k = i*16 + (tid >> 4);
    int n4 = (tid & 15) * 4;
    float4 v = *(const float4*)(W + (long)(k0+k)*N + n0 + n4);
    tile[k][n4+0] = v.x; tile[k][n4+1] = v.y; tile[k][n4+2] = v.z; tile[k][n4+3] = v.w;
  }
  __syncthreads();
  #pragma unroll
  for (int i = 0; i < 4; i++){
    int n = i*16 + (tid >> 4);
    int k4 = (tid & 15) * 4;
    ushort4 h4, l4;
    float v0 = tile[k4+0][n], v1 = tile[k4+1][n], v2 = tile[k4+2][n], v3 = tile[k4+3][n];
    h4.x = f2bf(v0); l4.x = f2bf(v0 - bf2f(h4.x));
    h4.y = f2bf(v1); l4.y = f2bf(v1 - bf2f(h4.y));
    h4.z = f2bf(v2); l4.z = f2bf(v2 - bf2f(h4.z));
    h4.w = f2bf(v3); l4.w = f2bf(v3 - bf2f(h4.w));
    *(ushort4*)(WTh + (long)(n0+n)*K + k0 + k4) = h4;
    *(ushort4*)(WTl + (long)(n0+n)*K + k0 + k4) = l4;
  }
}

// ---------- LN1 + bf16 hi/lo split ----------
__global__ __launch_bounds__(256) void ln1_split(PP p){
  int tok = blockIdx.x*4 + (threadIdx.x >> 6);
  int l = threadIdx.x & 63;
  const float* src = p.inputs + (long)tok*DIN;
  float4 v[3];
  float s = 0.f, s2 = 0.f;
  #pragma unroll
  for (int pp = 0; pp < 3; pp++){
    v[pp] = *(const float4*)(src + pp*256 + l*4);
    s  += v[pp].x + v[pp].y + v[pp].z + v[pp].w;
    s2 += v[pp].x*v[pp].x + v[pp].y*v[pp].y + v[pp].z*v[pp].z + v[pp].w*v[pp].w;
  }
  #pragma unroll
  for (int m = 1; m < 64; m <<= 1){ s += __shfl_xor(s, m); s2 += __shfl_xor(s2, m); }
  float mean = s*(1.f/DIN), var = s2*(1.f/DIN) - mean*mean;
  float rstd = rsqrtf(var + 1e-5f);
  #pragma unroll
  for (int pp = 0; pp < 3; pp++){
    int idx = pp*256 + l*4;
    float4 g = *(const float4*)(p.im_ln1_g + idx);
    float4 b = *(const float4*)(p.im_ln1_b + idx);
    float y0 = (v[pp].x-mean)*rstd*g.x + b.x;
    float y1 = (v[pp].y-mean)*rstd*g.y + b.y;
    float y2 = (v[pp].z-mean)*rstd*g.z + b.z;
    float y3 = (v[pp].w-mean)*rstd*g.w + b.w;
    ushort4 h4, l4;
    h4.x = f2bf(y0); l4.x = f2bf(y0 - bf2f(h4.x));
    h4.y = f2bf(y1); l4.y = f2bf(y1 - bf2f(h4.y));
    h4.z = f2bf(y2); l4.z = f2bf(y2 - bf2f(h4.z));
    h4.w = f2bf(y3); l4.w = f2bf(y3 - bf2f(h4.w));
    *(ushort4*)(p.xnh + (long)tok*DIN + idx) = h4;
    *(ushort4*)(p.xnl + (long)tok*DIN + idx) = l4;
  }
}

// ---------- split-bf16 MFMA GEMM (3-pass hi/lo) ----------
template<int EPI>
__global__ __launch_bounds__(256) void gemm_split(
    const ushort* __restrict__ Ah, const ushort* __restrict__ Al,
    const ushort* __restrict__ Bh, const ushort* __restrict__ Bl,
    const float* __restrict__ bias,
    ushort* __restrict__ Ch, ushort* __restrict__ Cl,
    float* __restrict__ Xout, const float* __restrict__ g2, const float* __restrict__ b2,
    int M)
{
  __shared__ __align__(16) char smem[64*132*4];
  ushort* As = (ushort*)smem;               // [2][64][40]
  ushort* Bs = (ushort*)(smem + 10240);     // [2][128][40]
  int tid = threadIdx.x;
  int n0 = blockIdx.x * 128, m0 = blockIdx.y * 64;
  int w = tid >> 6, lane = tid & 63;
  f4v acc[4][2];
  #pragma unroll
  for (int mf = 0; mf < 4; mf++)
    #pragma unroll
    for (int nf = 0; nf < 2; nf++) acc[mf][nf] = (f4v)(0.f);

  for (int kb = 0; kb < DIN; kb += 32){
    __syncthreads();
    #pragma unroll
    for (int i = 0; i < 2; i++){
      int c = tid + i*256;
      int s = c >> 8, r = (c >> 2) & 63, kg = c & 3;
      int gr = min(m0 + r, M-1);
      const float4 va = *(const float4*)((s ? Al : Ah) + (long)gr*DIN + kb + kg*8);
      *(float4*)(As + s*2560 + r*40 + kg*8) = va;
    }
    #pragma unroll
    for (int i = 0; i < 4; i++){
      int c = tid + i*256;
      int s = c >> 9, r = (c >> 2) & 127, kg = c & 3;
      const float4 vb = *(const float4*)((s ? Bl : Bh) + (long)(n0 + r)*DIN + kb + kg*8);
      *(float4*)(Bs + s*5120 + r*40 + kg*8) = vb;
    }
    __syncthreads();
    int kg = lane >> 4, rA = lane & 15;
    s8v a0[4], a1[4], b0[2], b1[2];
    #pragma unroll
    for (int mf = 0; mf < 4; mf++){
      a0[mf] = *(const s8v*)(As +        (mf*16 + rA)*40 + kg*8);
      a1[mf] = *(const s8v*)(As + 2560 + (mf*16 + rA)*40 + kg*8);
    }
    #pragma unroll
    for (int nf = 0; nf < 2; nf++){
      int rb = w*32 + nf*16 + rA;
      b0[nf] = *(const s8v*)(Bs +        rb*40 + kg*8);
      b1[nf] = *(const s8v*)(Bs + 5120 + rb*40 + kg*8);
    }
    #pragma unroll
    for (int mf = 0; mf < 4; mf++)
      #pragma unroll
      for (int nf = 0; nf < 2; nf++){
        acc[mf][nf] = __builtin_amdgcn_mfma_f32_16x16x32_bf16(a0[mf], b0[nf], acc[mf][nf], 0, 0, 0);
        acc[mf][nf] = __builtin_amdgcn_mfma_f32_16x16x32_bf16(a0[mf], b1[nf], acc[mf][nf], 0, 0, 0);
        acc[mf][nf] = __builtin_amdgcn_mfma_f32_16x16x32_bf16(a1[mf], b0[nf], acc[mf][nf], 0, 0, 0);
      }
  }

  int rbase = (lane >> 4) * 4, cn = lane & 15;
  if (EPI == 1){
    #pragma unroll
    for (int mf = 0; mf < 4; mf++)
      #pragma unroll
      for (int nf = 0; nf < 2; nf++){
        int n = n0 + w*32 + nf*16 + cn;
        float bs = bias[n];
        #pragma unroll
        for (int r = 0; r < 4; r++){
          int m = m0 + mf*16 + rbase + r;
          if (m < M){
            float v = fmaxf(acc[mf][nf][r] + bs, 0.f);
            ushort h = f2bf(v);
            Ch[(long)m*DIN + n] = h;
            Cl[(long)m*DIN + n] = f2bf(v - bf2f(h));
          }
        }
      }
  } else {
    __syncthreads();
    float* Dl = (float*)smem;   // [64][132]
    #pragma unroll
    for (int mf = 0; mf < 4; mf++)
      #pragma unroll
      for (int nf = 0; nf < 2; nf++){
        int n = w*32 + nf*16 + cn;
        float bs = bias[n];
        #pragma unroll
        for (int r = 0; r < 4; r++)
          Dl[(mf*16 + rbase + r)*132 + n] = acc[mf][nf][r] + bs;
      }
    __syncthreads();
    for (int rr = 0; rr < 16; rr++){
      int row = w*16 + rr;
      float e0 = Dl[row*132 + lane], e1 = Dl[row*132 + 64 + lane];
      float s = e0 + e1, s2 = e0*e0 + e1*e1;
      #pragma unroll
      for (int m2 = 1; m2 < 64; m2 <<= 1){ s += __shfl_xor(s, m2); s2 += __shfl_xor(s2, m2); }
      float mean = s*(1.f/DD), var = s2*(1.f/DD) - mean*mean;
      float rstd = rsqrtf(var + 1e-5f);
      int m = m0 + row;
      if (m < M){
        Xout[(long)m*DD + lane]      = (e0-mean)*rstd*g2[lane]      + b2[lane];
        Xout[(long)m*DD + 64 + lane] = (e1-mean)*rstd*g2[64 + lane] + b2[64 + lane];
      }
    }
  }
}

// ---------- A_K = x@WKf + c1 ; A_V = x@WVf + c1 ----------
__global__ __launch_bounds__(256) void k2_proj(PP p){
  __shared__ float xt[32][132];
  int tid = threadIdx.x; int g0 = blockIdx.x * 32;
  for (int f = tid; f < 32*32; f += 256){
    int tok = f >> 5, pos = (f & 31) * 4;
    int gt = g0 + tok;
    float4 v = (gt < NTOT) ? *(const float4*)(p.x + (long)gt*DD + pos)
                           : make_float4(0.f,0.f,0.f,0.f);
    *(float4*)&xt[tok][pos] = v;
  }
  __syncthreads();
  int d = tid & 127, grp = tid >> 7;
  float aK[16], aV[16];
  float c1v = p.c1[d];
  #pragma unroll
  for (int t = 0; t < 16; t++){ aK[t] = c1v; aV[t] = c1v; }
  for (int kk = 0; kk < DD; kk += 4){
    float k0 = p.WKf[(kk+0)*DD+d], k1 = p.WKf[(kk+1)*DD+d], k2 = p.WKf[(kk+2)*DD+d], k3 = p.WKf[(kk+3)*DD+d];
    float v0 = p.WVf[(kk+0)*DD+d], v1 = p.WVf[(kk+1)*DD+d], v2 = p.WVf[(kk+2)*DD+d], v3 = p.WVf[(kk+3)*DD+d];
    #pragma unroll
    for (int t = 0; t < 16; t++){
      float4 xv = *(const float4*)&xt[grp*16+t][kk];
      aK[t] = fmaf(xv.x,k0, fmaf(xv.y,k1, fmaf(xv.z,k2, fmaf(xv.w,k3, aK[t]))));
      aV[t] = fmaf(xv.x,v0, fmaf(xv.y,v1, fmaf(xv.z,v2, fmaf(xv.w,v3, aV[t]))));
    }
  }
  #pragma unroll
  for (int t = 0; t < 16; t++){
    int gt = g0 + grp*16 + t;
    if (gt < NTOT){ p.A_K[(long)gt*DD+d] = aK[t]; p.A_V[(long)gt*DD+d] = aV[t]; }
  }
}

// ---------- fused 4-iteration slot attention: one block per b ----------
__global__ __launch_bounds__(512) void k_iter(PP p){
  const int b = blockIdx.x;
  const int tid = threadIdx.x;
  const int wid = tid >> 6, lane = tid & 63;

  __shared__ float slots_s[8][128];
  __shared__ float sns[8][128];
  __shared__ float qs[8][128];
  __shared__ float ys[8][128];
  __shared__ float hbar_s[8][128];
  __shared__ float upds[8][128];
  __shared__ float qws[8][132];
  __shared__ float qbs[8];
  __shared__ float spss[8][4];
  __shared__ float Sp_c[8][2], Ss_c[8][2];
  __shared__ float agl[NTP][2];
  __shared__ float wg01[2][128];
  __shared__ float red[8][16];
  __shared__ float sums[8];
  __shared__ float u_a[4096];   // dots[8][448] / hpart[4][8][128]
  __shared__ float u_b[4096];   // attn[8][448] / h1[8][512]

  // ---- init ----
  for (int f = tid; f < NS*DD; f += 512) slots_s[f>>7][f&127] = p.slots_init[f];
  if (tid < 16){ Sp_c[tid>>1][tid&1] = p.Sp_init[tid]; Ss_c[tid>>1][tid&1] = p.Ss_init[tid]; }
  for (int f = tid; f < NT; f += 512){
    int idx = p.tok_idx[b*NT + f];
    agl[f][0] = p.abs_grid[idx*2+0];
    agl[f][1] = p.abs_grid[idx*2+1];
  }
  if (tid < 256) wg01[tid>>7][tid&127] = p.Wg1[tid];
  __syncthreads();

  for (int t = 0; t < 4; t++){
    // ===== P0: per-slot LN, q, qW, qb, spss (wave = slot) =====
    {
      int s = wid;
      float v0 = slots_s[s][lane], v1 = slots_s[s][lane+64];
      float sm = v0+v1, sq = v0*v0 + v1*v1;
      #pragma unroll
      for (int m = 1; m < 64; m <<= 1){ sm += __shfl_xor(sm, m); sq += __shfl_xor(sq, m); }
      float mean = sm*(1.f/DD), var = sq*(1.f/DD) - mean*mean;
      float rstd = rsqrtf(var + 1e-5f);
      float sn0 = (v0-mean)*rstd*p.ln_g[lane]    + p.ln_b[lane];
      float sn1 = (v1-mean)*rstd*p.ln_g[lane+64] + p.ln_b[lane+64];
      sns[s][lane] = sn0; sns[s][lane+64] = sn1;
      __syncthreads();
      float q0 = 0.f, q1 = 0.f;
      for (int k4 = 0; k4 < 32; k4++){
        float4 sv  = *(const float4*)&sns[s][k4*4];
        float4 wa  = *(const float4*)(p.WQT + (long)lane*128      + k4*4);
        float4 wb  = *(const float4*)(p.WQT + (long)(lane+64)*128 + k4*4);
        q0 += dot4(sv, wa); q1 += dot4(sv, wb);
      }
      qs[s][lane] = q0; qs[s][lane+64] = q1;
      __syncthreads();
      float a0 = 0.f, a1 = 0.f;
      for (int k4 = 0; k4 < 32; k4++){
        float4 qv = *(const float4*)&qs[s][k4*4];
        float4 wa = *(const float4*)(p.Wf2 + (long)lane*128      + k4*4);
        float4 wb = *(const float4*)(p.Wf2 + (long)(lane+64)*128 + k4*4);
        a0 += dot4(qv, wa); a1 += dot4(qv, wb);
      }
      qws[s][(lane&31)*4 + (lane>>5)] = a0;
      int d1 = lane + 64;
      qws[s][(d1&31)*4 + (d1>>5)] = a1;
      float pb = p.bf2[lane]*q0 + p.bf2[d1]*q1;
      #pragma unroll
      for (int m = 1; m < 64; m <<= 1) pb += __shfl_xor(pb, m);
      if (lane == 0) qbs[s] = pb * FSCALE;
      if (lane < 4) spss[s][lane] = (lane < 2) ? Sp_c[s][lane] : 1.f/(Ss_c[s][lane-2]*5.0f);
      __syncthreads();
    }

    // ===== P1: dots (4 lanes per token) =====
    {
      int jl = tid >> 2, dg = tid & 3;
      float w0[32], w1[32];
      #pragma unroll
      for (int i = 0; i < 32; i++){ w0[i] = wg01[0][dg*32+i]; w1[i] = wg01[1][dg*32+i]; }
      float sp0[8], sp1[8], si0[8], si1[8];
      #pragma unroll
      for (int s = 0; s < 8; s++){
        sp0[s]=spss[s][0]; sp1[s]=spss[s][1]; si0[s]=spss[s][2]; si1[s]=spss[s][3];
      }
      for (int jp = 0; jp < 4; jp++){
        int j = jp*128 + jl;
        bool valid = j < NT;
        int jj = valid ? j : 0;
        const float* src = p.A_K + ((long)(b*NT+jj))*DD + dg*32;
        float aa[32];
        #pragma unroll
        for (int i4 = 0; i4 < 8; i4++){
          float4 tt = *(const float4*)(src + i4*4);
          aa[i4*4+0]=tt.x; aa[i4*4+1]=tt.y; aa[i4*4+2]=tt.z; aa[i4*4+3]=tt.w;
        }
        float g0 = agl[jj][0], g1 = agl[jj][1];
        #pragma unroll
        for (int s = 0; s < 8; s++){
          float rel0 = (g0 - sp0[s])*si0[s];
          float rel1 = (g1 - sp1[s])*si1[s];
          float acc = 0.f;
          #pragma unroll
          for (int i = 0; i < 32; i++){
            float hk = fmaxf(fmaf(rel0, w0[i], fmaf(rel1, w1[i], aa[i])), 0.f);
            acc = fmaf(hk, qws[s][i*4+dg], acc);
          }
          acc += __shfl_xor(acc, 1); acc += __shfl_xor(acc, 2);
          if (dg == 0 && valid) u_a[s*NTP + j] = acc*FSCALE + qbs[s];
        }
      }
      __syncthreads();
    }

    // ===== P2: softmax over s, +eps, renorm over j; Sp/Ss (t<3) or output (t==3) =====
    {
      int j = tid; bool jv = j < NT;
      float a[8];
      float psum[8];
      if (jv){
        float dv[8]; float m = -1e30f;
        #pragma unroll
        for (int s = 0; s < 8; s++){ dv[s] = u_a[s*NTP+j]; m = fmaxf(m, dv[s]); }
        float tot = 0.f;
        #pragma unroll
        for (int s = 0; s < 8; s++){ dv[s] = expf(dv[s]-m); tot += dv[s]; }
        float inv = 1.f/tot;
        #pragma unroll
        for (int s = 0; s < 8; s++){ a[s] = dv[s]*inv + 1e-8f; }
      } else {
        #pragma unroll
        for (int s = 0; s < 8; s++) a[s] = 0.f;
      }
      #pragma unroll
      for (int s = 0; s < 8; s++){
        psum[s] = a[s];
        #pragma unroll
        for (int m2 = 1; m2 < 64; m2 <<= 1) psum[s] += __shfl_xor(psum[s], m2);
      }
      if (lane == 0){
        #pragma unroll
        for (int s = 0; s < 8; s++) red[wid][s] = psum[s];
      }
      __syncthreads();
      if (tid < 8){
        float tsum = 0.f;
        #pragma unroll
        for (int w2 = 0; w2 < 8; w2++) tsum += red[w2][tid];
        sums[tid] = tsum;
      }
      __syncthreads();
      float g0 = jv ? agl[j][0] : 0.f, g1 = jv ? agl[j][1] : 0.f;
      float av[8];
      #pragma unroll
      for (int s = 0; s < 8; s++){
        av[s] = a[s]/sums[s];
        if (jv) u_b[s*NTP + j] = av[s];
      }
      if (t < 3){
        // Sp = sum_j attn*ag   (av is 0 for !jv lanes already)
        float spp[16];
        #pragma unroll
        for (int s = 0; s < 8; s++){ spp[s*2] = av[s]*g0; spp[s*2+1] = av[s]*g1; }
        #pragma unroll
        for (int k = 0; k < 16; k++){
          #pragma unroll
          for (int m2 = 1; m2 < 64; m2 <<= 1) spp[k] += __shfl_xor(spp[k], m2);
        }
        if (lane == 0){
          #pragma unroll
          for (int k = 0; k < 16; k++) red[wid][k] = spp[k];
        }
        __syncthreads();
        if (tid < 16){
          float tt = 0.f;
          #pragma unroll
          for (int w2 = 0; w2 < 8; w2++) tt += red[w2][tid];
          Sp_c[tid>>1][tid&1] = tt;
        }
        __syncthreads();
        // Ss = sqrt(sum_j attn*(ag-Sp)^2)
        float qq[16];
        #pragma unroll
        for (int s = 0; s < 8; s++){
          float e0 = g0 - Sp_c[s][0], e1 = g1 - Sp_c[s][1];
          float q0v = av[s]*e0*e0, q1v = av[s]*e1*e1;
          qq[s*2]   = jv ? q0v : 0.f;
          qq[s*2+1] = jv ? q1v : 0.f;
        }
        #pragma unroll
        for (int k = 0; k < 16; k++){
          #pragma unroll
          for (int m2 = 1; m2 < 64; m2 <<= 1) qq[k] += __shfl_xor(qq[k], m2);
        }
        if (lane == 0){
          #pragma unroll
          for (int k = 0; k < 16; k++) red[wid][k] = qq[k];
        }
        __syncthreads();
        if (tid < 16){
          float tt = 0.f;
          #pragma unroll
          for (int w2 = 0; w2 < 8; w2++) tt += red[w2][tid];
          Ss_c[tid>>1][tid&1] = sqrtf(tt);
        }
        __syncthreads();
      } else {
        if ((b % 5) == 2 && jv){
          long base = (long)NB*NS*DD + (long)(b/5)*NS*NT;
          #pragma unroll
          for (int s = 0; s < 8; s++) p.out[base + s*NT + j] = av[s];
        }
        __syncthreads();
      }
    }

    if (t < 3){
      // ===== P3: hbar[s][d] = sum_j attn * relu(A_V + rel@Wg1) =====
      {
        int d = tid & 127, jg = tid >> 7;
        float wgd0 = wg01[0][d], wgd1 = wg01[1][d];
        float sp0[8], sp1[8], si0[8], si1[8];
        #pragma unroll
        for (int s = 0; s < 8; s++){
          sp0[s]=spss[s][0]; sp1[s]=spss[s][1]; si0[s]=spss[s][2]; si1[s]=spss[s][3];
        }
        float acc[8];
        #pragma unroll
        for (int s = 0; s < 8; s++) acc[s] = 0.f;
        for (int jj = jg; jj < NT; jj += 4){
          float avv = p.A_V[((long)(b*NT+jj))*DD + d];
          float g0 = agl[jj][0], g1 = agl[jj][1];
          #pragma unroll
          for (int s = 0; s < 8; s++){
            float rel0 = (g0 - sp0[s])*si0[s];
            float rel1 = (g1 - sp1[s])*si1[s];
            float hv = fmaxf(fmaf(rel0, wgd0, fmaf(rel1, wgd1, avv)), 0.f);
            acc[s] = fmaf(u_b[s*NTP + jj], hv, acc[s]);
          }
        }
        #pragma unroll
        for (int s = 0; s < 8; s++) u_a[jg*1024 + s*128 + d] = acc[s];
        __syncthreads();
        for (int f = tid; f < 1024; f += 512){
          int s = f >> 7, dd = f & 127;
          hbar_s[s][dd] = u_a[s*128+dd] + u_a[1024 + s*128+dd] + u_a[2048 + s*128+dd] + u_a[3072 + s*128+dd];
        }
        __syncthreads();
      }

      // ===== P4: updates = hbar@Wf2+bf2; GRU; residual pre-LN MLP (wave = slot) =====
      {
        int s = wid, d0 = lane, d1 = lane + 64;
        float u0 = p.bf2[d0], u1 = p.bf2[d1];
        for (int k4 = 0; k4 < 32; k4++){
          float4 hb = *(const float4*)&hbar_s[s][k4*4];
          float4 wa = *(const float4*)(p.Wf2T + (long)d0*128 + k4*4);
          float4 wb = *(const float4*)(p.Wf2T + (long)d1*128 + k4*4);
          u0 += dot4(hb, wa); u1 += dot4(hb, wb);
        }
        upds[s][d0] = u0; upds[s][d1] = u1;
        __syncthreads();
        float gia[3], gib[3], gha[3], ghb[3];
        #pragma unroll
        for (int i = 0; i < 3; i++){
          gia[i] = p.gru_b_ih[d0+128*i]; gib[i] = p.gru_b_ih[d1+128*i];
          gha[i] = p.gru_b_hh[d0+128*i]; ghb[i] = p.gru_b_hh[d1+128*i];
        }
        for (int k4 = 0; k4 < 32; k4++){
          float4 xv = *(const float4*)&upds[s][k4*4];
          float4 hv = *(const float4*)&slots_s[s][k4*4];
          #pragma unroll
          for (int i = 0; i < 3; i++){
            float4 wia = *(const float4*)(p.gihT + (long)(d0+128*i)*128 + k4*4);
            float4 wib = *(const float4*)(p.gihT + (long)(d1+128*i)*128 + k4*4);
            float4 wha = *(const float4*)(p.ghhT + (long)(d0+128*i)*128 + k4*4);
            float4 whb = *(const float4*)(p.ghhT + (long)(d1+128*i)*128 + k4*4);
            gia[i] += dot4(xv, wia); gib[i] += dot4(xv, wib);
            gha[i] += dot4(hv, wha); ghb[i] += dot4(hv, whb);
          }
        }
        float hp0 = slots_s[s][d0], hp1 = slots_s[s][d1];
        float r0 = 1.f/(1.f+expf(-(gia[0]+gha[0])));
        float z0 = 1.f/(1.f+expf(-(gia[1]+gha[1])));
        float n0 = tanhf(gia[2] + r0*gha[2]);
        float hn0 = (1.f-z0)*n0 + z0*hp0;
        float r1 = 1.f/(1.f+expf(-(gib[0]+ghb[0])));
        float z1 = 1.f/(1.f+expf(-(gib[1]+ghb[1])));
        float n1 = tanhf(gib[2] + r1*ghb[2]);
        float hn1 = (1.f-z1)*n1 + z1*hp1;
        float sm = hn0+hn1, sq = hn0*hn0 + hn1*hn1;
        #pragma unroll
        for (int m = 1; m < 64; m <<= 1){ sm += __shfl_xor(sm, m); sq += __shfl_xor(sq, m); }
        float mean = sm*(1.f/DD), var = sq*(1.f/DD) - mean*mean;
        float rstd = rsqrtf(var + 1e-5f);
        ys[s][d0] = (hn0-mean)*rstd*p.mlp_ln_g[d0] + p.mlp_ln_b[d0];
        ys[s][d1] = (hn1-mean)*rstd*p.mlp_ln_g[d1] + p.mlp_ln_b[d1];
        __syncthreads();
        #pragma unroll
        for (int i = 0; i < 8; i++){
          int o = i*64 + lane;
          float acc = p.mlp_b1[o];
          for (int k4 = 0; k4 < 32; k4++){
            float4 yv = *(const float4*)&ys[s][k4*4];
            float4 wv = *(const float4*)(p.w1T + (long)o*128 + k4*4);
            acc += dot4(yv, wv);
          }
          u_b[s*512 + o] = fmaxf(acc, 0.f);
        }
        __syncthreads();
        float a0 = p.mlp_b2[d0], a1 = p.mlp_b2[d1];
        for (int o4 = 0; o4 < 128; o4++){
          float4 hvv = *(const float4*)&u_b[s*512 + o4*4];
          float4 wa = *(const float4*)(p.w2T + (long)d0*512 + o4*4);
          float4 wb = *(const float4*)(p.w2T + (long)d1*512 + o4*4);
          a0 += dot4(hvv, wa); a1 += dot4(hvv, wb);
        }
        slots_s[s][d0] = hn0 + a0;
        slots_s[s][d1] = hn1 + a1;
        __syncthreads();
      }
    }
  }

  // ===== P5: final slot projection =====
  {
    int s = wid, d0 = lane, d1 = lane + 64;
    float a0 = p.fin_b[d0], a1 = p.fin_b[d1];
    for (int k4 = 0; k4 < 32; k4++){
      float4 sl = *(const float4*)&slots_s[s][k4*4];
      float4 wa = *(const float4*)(p.finT + (long)d0*128 + k4*4);
      float4 wb = *(const float4*)(p.finT + (long)d1*128 + k4*4);
      a0 += dot4(sl, wa); a1 += dot4(sl, wb);
    }
    p.out[(long)(b*NS + s)*DD + d0] = a0;
    p.out[(long)(b*NS + s)*DD + d1] = a1;
  }
}

extern "C" void kernel_launch(void* const* d_in, const int* in_sizes, int n_in,
                              void* d_out, int out_size, void* d_ws, size_t ws_size,
                              hipStream_t stream){
  PP p;
  p.inputs=(const float*)d_in[0]; p.tok_idx=(const int*)d_in[1]; p.abs_grid=(const float*)d_in[2];
  p.slots_init=(const float*)d_in[3]; p.Sp_init=(const float*)d_in[4]; p.Ss_init=(const float*)d_in[5];
  p.WQ=(const float*)d_in[6]; p.ln_g=(const float*)d_in[7]; p.ln_b=(const float*)d_in[8];
  p.gru_w_ih=(const float*)d_in[9]; p.gru_w_hh=(const float*)d_in[10];
  p.gru_b_ih=(const float*)d_in[11]; p.gru_b_hh=(const float*)d_in[12];
  p.mlp_ln_g=(const float*)d_in[13]; p.mlp_ln_b=(const float*)d_in[14];
  p.mlp_w1=(const float*)d_in[15]; p.mlp_b1=(const float*)d_in[16];
  p.mlp_w2=(const float*)d_in[17]; p.mlp_b2=(const float*)d_in[18];
  p.WK=(const float*)d_in[19]; p.WV=(const float*)d_in[20]; p.Wg=(const float*)d_in[21]; p.bg=(const float*)d_in[22];
  p.Wf1=(const float*)d_in[23]; p.bf1=(const float*)d_in[24]; p.Wf2=(const float*)d_in[25]; p.bf2=(const float*)d_in[26];
  p.im_ln1_g=(const float*)d_in[27]; p.im_ln1_b=(const float*)d_in[28];
  p.im_w1=(const float*)d_in[29]; p.im_b1=(const float*)d_in[30];
  p.im_w2=(const float*)d_in[31]; p.im_b2=(const float*)d_in[32];
  p.im_ln2_g=(const float*)d_in[33]; p.im_ln2_b=(const float*)d_in[34];
  p.fin_w=(const float*)d_in[35]; p.fin_b=(const float*)d_in[36];

  float* w = (float*)d_ws;
  size_t need = 0;
  auto alloc = [&](size_t nfl){ nfl = (nfl + 3) & ~(size_t)3; float* r = w + need; need += nfl; return r; };
  p.x    = alloc((size_t)NTOT*DD);
  p.A_K  = alloc((size_t)NTOT*DD);
  p.A_V  = alloc((size_t)NTOT*DD);
  p.WKf  = alloc(DD*DD);
  p.WVf  = alloc(DD*DD);
  p.Wg1  = alloc(2*DD);
  p.c1   = alloc(DD);
  p.Wf2T = alloc(DD*DD);
  p.WQT  = alloc(DD*DD);
  p.gihT = alloc(3*DD*DD);
  p.ghhT = alloc(3*DD*DD);
  p.w1T  = alloc(4*DD*DD);
  p.w2T  = alloc(4*DD*DD);
  p.finT = alloc(DD*DD);
  p.xnh  = (ushort*)alloc((size_t)NTOT*DIN/2);
  p.xnl  = (ushort*)alloc((size_t)NTOT*DIN/2);
  p.hh   = (ushort*)alloc((size_t)NTOT*DIN/2);
  p.hl   = (ushort*)alloc((size_t)NTOT*DIN/2);
  p.W1Th = (ushort*)alloc((size_t)DIN*DIN/2);
  p.W1Tl = (ushort*)alloc((size_t)DIN*DIN/2);
  p.W2Th = (ushort*)alloc((size_t)DD*DIN/2);
  p.W2Tl = (ushort*)alloc((size_t)DD*DIN/2);
  p.out = (float*)d_out;
  if (ws_size < need*sizeof(float)){
    fprintf(stderr, "kernel_launch: ws too small (%zu < %zu)\n", ws_size, need*sizeof(float));
    return;
  }

  prep_weights<<<dim3(DD), dim3(128), 0, stream>>>(p);
  prep_transposes<<<dim3(1024), dim3(256), 0, stream>>>(p);
  transpose_split<<<dim3(DIN/64, DIN/64), dim3(256), 0, stream>>>(p.im_w1, p.W1Th, p.W1Tl, DIN, DIN);
  transpose_split<<<dim3(DIN/64, DD/64), dim3(256), 0, stream>>>(p.im_w2, p.W2Th, p.W2Tl, DIN, DD);
  ln1_split<<<dim3(NTOT/4), dim3(256), 0, stream>>>(p);
  gemm_split<1><<<dim3(DIN/128, (NTOT+63)/64), dim3(256), 0, stream>>>(
      p.xnh, p.xnl, p.W1Th, p.W1Tl, p.im_b1, p.hh, p.hl,
      nullptr, nullptr, nullptr, NTOT);
  gemm_split<2><<<dim3(1, (NTOT+63)/64), dim3(256), 0, stream>>>(
      p.hh, p.hl, p.W2Th, p.W2Tl, p.im_b2, nullptr, nullptr,
      p.x, p.im_ln2_g, p.im_ln2_b, NTOT);
  k2_proj<<<dim3((NTOT+31)/32), dim3(256), 0, stream>>>(p);
  k_iter<<<dim3(NB), dim3(512), 0, stream>>>(p);
}

// Round 6
// 1393.255 us; speedup vs baseline: 1.0485x; 1.0485x over previous
//
#include <hip/hip_runtime.h>
#include <cstdio>

#define NB 40
#define NS 8
#define NT 441
#define DIN 768
#define DD 128
#define NTOT (NB*NT)
#define NBLK 320
#define FSCALE 0.08838834764831843f

typedef short s8v __attribute__((ext_vector_type(8)));
typedef float f4v __attribute__((ext_vector_type(4)));

__device__ inline ushort f2bf(float f){
  unsigned u = __float_as_uint(f);
  unsigned r = (u + 0x7fffu + ((u >> 16) & 1u)) >> 16;
  return (ushort)r;
}
__device__ inline float bf2f(ushort h){ return __uint_as_float(((unsigned)h) << 16); }

struct PP {
  const float *inputs; const int *tok_idx; const float *abs_grid;
  const float *slots_init, *Sp_init, *Ss_init;
  const float *WQ, *ln_g, *ln_b;
  const float *gru_w_ih, *gru_w_hh, *gru_b_ih, *gru_b_hh;
  const float *mlp_ln_g, *mlp_ln_b, *mlp_w1, *mlp_b1, *mlp_w2, *mlp_b2;
  const float *WK, *WV, *Wg, *bg, *Wf1, *bf1, *Wf2, *bf2;
  const float *im_ln1_g, *im_ln1_b, *im_w1, *im_b1, *im_w2, *im_b2, *im_ln2_g, *im_ln2_b;
  const float *fin_w, *fin_b;
  float *x, *A_K, *A_V, *WKf, *WVf, *Wg1, *c1, *Wf2T;
  float *qw_g, *qb_g, *spss_g, *a_g, *ag_g;
  int *bar;
  ushort *xnh, *xnl, *hh, *hl, *W1Th, *W1Tl, *W2Th, *W2Tl;
  float *out;
};

// ---------- software grid barrier (device-scope; safe cross-XCD) ----------
__device__ inline void gsync(int* bar, int idx, int nblk){
  __syncthreads();
  if (threadIdx.x == 0){
    __threadfence();
    atomicAdd(&bar[idx], 1);
    while (__hip_atomic_load(&bar[idx], __ATOMIC_ACQUIRE, __HIP_MEMORY_SCOPE_AGENT) < nblk)
      __builtin_amdgcn_s_sleep(1);
  }
  __syncthreads();
}

// ---------- weight prep (also zeroes barrier counters) ----------
__global__ __launch_bounds__(128) void prep_weights(PP p){
  int r = blockIdx.x, d = threadIdx.x;
  if (r == 0 && d < 16) p.bar[d] = 0;
  float accK = 0.f, accV = 0.f;
  for (int kk = 0; kk < DD; kk++){
    float w = p.Wf1[kk*DD + d];
    accK = fmaf(p.WK[r*DD+kk], w, accK);
    accV = fmaf(p.WV[r*DD+kk], w, accV);
  }
  p.WKf[r*DD+d] = accK; p.WVf[r*DD+d] = accV;
  if (r < 2){
    float a = 0.f;
    for (int kk = 0; kk < DD; kk++) a = fmaf(p.Wg[r*DD+kk], p.Wf1[kk*DD+d], a);
    p.Wg1[r*DD+d] = a;
  }
  if (r == 2){
    float a = 0.f;
    for (int kk = 0; kk < DD; kk++) a = fmaf(p.bg[kk], p.Wf1[kk*DD+d], a);
    p.c1[d] = a + p.bf1[d];
  }
  p.Wf2T[d*DD + r] = p.Wf2[r*DD + d];
}

// ---------- transpose + bf16 split ----------
__global__ __launch_bounds__(256) void transpose_split(const float* __restrict__ W,
                                                       ushort* __restrict__ WTh,
                                                       ushort* __restrict__ WTl,
                                                       int K, int N){
  __shared__ float tile[64][65];
  int tid = threadIdx.x;
  int k0 = blockIdx.x * 64, n0 = blockIdx.y * 64;
  #pragma unroll
  for (int i = 0; i < 4; i++){
    int k = i*16 + (tid >> 4);
    int n4 = (tid & 15) * 4;
    float4 v = *(const float4*)(W + (long)(k0+k)*N + n0 + n4);
    tile[k][n4+0] = v.x; tile[k][n4+1] = v.y; tile[k][n4+2] = v.z; tile[k][n4+3] = v.w;
  }
  __syncthreads();
  #pragma unroll
  for (int i = 0; i < 4; i++){
    int n = i*16 + (tid >> 4);
    int k4 = (tid & 15) * 4;
    ushort4 h4, l4;
    float v0 = tile[k4+0][n], v1 = tile[k4+1][n], v2 = tile[k4+2][n], v3 = tile[k4+3][n];
    h4.x = f2bf(v0); l4.x = f2bf(v0 - bf2f(h4.x));
    h4.y = f2bf(v1); l4.y = f2bf(v1 - bf2f(h4.y));
    h4.z = f2bf(v2); l4.z = f2bf(v2 - bf2f(h4.z));
    h4.w = f2bf(v3); l4.w = f2bf(v3 - bf2f(h4.w));
    *(ushort4*)(WTh + (long)(n0+n)*K + k0 + k4) = h4;
    *(ushort4*)(WTl + (long)(n0+n)*K + k0 + k4) = l4;
  }
}

// ---------- LN1 + bf16 hi/lo split ----------
__global__ __launch_bounds__(256) void ln1_split(PP p){
  int tok = blockIdx.x*4 + (threadIdx.x >> 6);
  int l = threadIdx.x & 63;
  const float* src = p.inputs + (long)tok*DIN;
  float4 v[3];
  float s = 0.f, s2 = 0.f;
  #pragma unroll
  for (int pp = 0; pp < 3; pp++){
    v[pp] = *(const float4*)(src + pp*256 + l*4);
    s  += v[pp].x + v[pp].y + v[pp].z + v[pp].w;
    s2 += v[pp].x*v[pp].x + v[pp].y*v[pp].y + v[pp].z*v[pp].z + v[pp].w*v[pp].w;
  }
  #pragma unroll
  for (int m = 1; m < 64; m <<= 1){ s += __shfl_xor(s, m); s2 += __shfl_xor(s2, m); }
  float mean = s*(1.f/DIN), var = s2*(1.f/DIN) - mean*mean;
  float rstd = rsqrtf(var + 1e-5f);
  #pragma unroll
  for (int pp = 0; pp < 3; pp++){
    int idx = pp*256 + l*4;
    float4 g = *(const float4*)(p.im_ln1_g + idx);
    float4 b = *(const float4*)(p.im_ln1_b + idx);
    float y0 = (v[pp].x-mean)*rstd*g.x + b.x;
    float y1 = (v[pp].y-mean)*rstd*g.y + b.y;
    float y2 = (v[pp].z-mean)*rstd*g.z + b.z;
    float y3 = (v[pp].w-mean)*rstd*g.w + b.w;
    ushort4 h4, l4;
    h4.x = f2bf(y0); l4.x = f2bf(y0 - bf2f(h4.x));
    h4.y = f2bf(y1); l4.y = f2bf(y1 - bf2f(h4.y));
    h4.z = f2bf(y2); l4.z = f2bf(y2 - bf2f(h4.z));
    h4.w = f2bf(y3); l4.w = f2bf(y3 - bf2f(h4.w));
    *(ushort4*)(p.xnh + (long)tok*DIN + idx) = h4;
    *(ushort4*)(p.xnl + (long)tok*DIN + idx) = l4;
  }
}

// ---------- split-bf16 MFMA GEMM ----------
template<int EPI>
__global__ __launch_bounds__(256) void gemm_split(
    const ushort* __restrict__ Ah, const ushort* __restrict__ Al,
    const ushort* __restrict__ Bh, const ushort* __restrict__ Bl,
    const float* __restrict__ bias,
    ushort* __restrict__ Ch, ushort* __restrict__ Cl,
    float* __restrict__ Xout, const float* __restrict__ g2, const float* __restrict__ b2,
    int M)
{
  __shared__ __align__(16) char smemc[64*132*4];
  ushort* As = (ushort*)smemc;
  ushort* Bs = (ushort*)(smemc + 10240);
  int tid = threadIdx.x;
  int n0 = blockIdx.x * 128, m0 = blockIdx.y * 64;
  int w = tid >> 6, lane = tid & 63;
  f4v acc[4][2];
  #pragma unroll
  for (int mf = 0; mf < 4; mf++)
    #pragma unroll
    for (int nf = 0; nf < 2; nf++) acc[mf][nf] = (f4v)(0.f);

  for (int kb = 0; kb < DIN; kb += 32){
    __syncthreads();
    #pragma unroll
    for (int i = 0; i < 2; i++){
      int c = tid + i*256;
      int s = c >> 8, r = (c >> 2) & 63, kg = c & 3;
      int gr = min(m0 + r, M-1);
      const float4 va = *(const float4*)((s ? Al : Ah) + (long)gr*DIN + kb + kg*8);
      *(float4*)(As + s*2560 + r*40 + kg*8) = va;
    }
    #pragma unroll
    for (int i = 0; i < 4; i++){
      int c = tid + i*256;
      int s = c >> 9, r = (c >> 2) & 127, kg = c & 3;
      const float4 vb = *(const float4*)((s ? Bl : Bh) + (long)(n0 + r)*DIN + kb + kg*8);
      *(float4*)(Bs + s*5120 + r*40 + kg*8) = vb;
    }
    __syncthreads();
    int kg = lane >> 4, rA = lane & 15;
    s8v a0[4], a1[4], b0[2], b1[2];
    #pragma unroll
    for (int mf = 0; mf < 4; mf++){
      a0[mf] = *(const s8v*)(As +        (mf*16 + rA)*40 + kg*8);
      a1[mf] = *(const s8v*)(As + 2560 + (mf*16 + rA)*40 + kg*8);
    }
    #pragma unroll
    for (int nf = 0; nf < 2; nf++){
      int rb = w*32 + nf*16 + rA;
      b0[nf] = *(const s8v*)(Bs +        rb*40 + kg*8);
      b1[nf] = *(const s8v*)(Bs + 5120 + rb*40 + kg*8);
    }
    #pragma unroll
    for (int mf = 0; mf < 4; mf++)
      #pragma unroll
      for (int nf = 0; nf < 2; nf++){
        acc[mf][nf] = __builtin_amdgcn_mfma_f32_16x16x32_bf16(a0[mf], b0[nf], acc[mf][nf], 0, 0, 0);
        acc[mf][nf] = __builtin_amdgcn_mfma_f32_16x16x32_bf16(a0[mf], b1[nf], acc[mf][nf], 0, 0, 0);
        acc[mf][nf] = __builtin_amdgcn_mfma_f32_16x16x32_bf16(a1[mf], b0[nf], acc[mf][nf], 0, 0, 0);
      }
  }

  int rbase = (lane >> 4) * 4, cn = lane & 15;
  if (EPI == 1){
    #pragma unroll
    for (int mf = 0; mf < 4; mf++)
      #pragma unroll
      for (int nf = 0; nf < 2; nf++){
        int n = n0 + w*32 + nf*16 + cn;
        float bs = bias[n];
        #pragma unroll
        for (int r = 0; r < 4; r++){
          int m = m0 + mf*16 + rbase + r;
          if (m < M){
            float v = fmaxf(acc[mf][nf][r] + bs, 0.f);
            ushort h = f2bf(v);
            Ch[(long)m*DIN + n] = h;
            Cl[(long)m*DIN + n] = f2bf(v - bf2f(h));
          }
        }
      }
  } else {
    __syncthreads();
    float* Dl = (float*)smemc;
    #pragma unroll
    for (int mf = 0; mf < 4; mf++)
      #pragma unroll
      for (int nf = 0; nf < 2; nf++){
        int n = w*32 + nf*16 + cn;
        float bs = bias[n];
        #pragma unroll
        for (int r = 0; r < 4; r++)
          Dl[(mf*16 + rbase + r)*132 + n] = acc[mf][nf][r] + bs;
      }
    __syncthreads();
    for (int rr = 0; rr < 16; rr++){
      int row = w*16 + rr;
      float e0 = Dl[row*132 + lane], e1 = Dl[row*132 + 64 + lane];
      float s = e0 + e1, s2 = e0*e0 + e1*e1;
      #pragma unroll
      for (int m2 = 1; m2 < 64; m2 <<= 1){ s += __shfl_xor(s, m2); s2 += __shfl_xor(s2, m2); }
      float mean = s*(1.f/DD), var = s2*(1.f/DD) - mean*mean;
      float rstd = rsqrtf(var + 1e-5f);
      int m = m0 + row;
      if (m < M){
        Xout[(long)m*DD + lane]      = (e0-mean)*rstd*g2[lane]      + b2[lane];
        Xout[(long)m*DD + 64 + lane] = (e1-mean)*rstd*g2[64 + lane] + b2[64 + lane];
      }
    }
  }
}

// ---------- A_K = x@WKf + c1 ; A_V = x@WVf + c1 ----------
__global__ __launch_bounds__(256) void k2_proj(PP p){
  __shared__ float xt[32][132];
  int tid = threadIdx.x; int g0 = blockIdx.x * 32;
  for (int f = tid; f < 32*32; f += 256){
    int tok = f >> 5, pos = (f & 31) * 4;
    int gt = g0 + tok;
    float4 v = (gt < NTOT) ? *(const float4*)(p.x + (long)gt*DD + pos)
                           : make_float4(0.f,0.f,0.f,0.f);
    *(float4*)&xt[tok][pos] = v;
  }
  __syncthreads();
  int d = tid & 127, grp = tid >> 7;
  float aK[16], aV[16];
  float c1v = p.c1[d];
  #pragma unroll
  for (int t = 0; t < 16; t++){ aK[t] = c1v; aV[t] = c1v; }
  for (int kk = 0; kk < DD; kk += 4){
    float k0 = p.WKf[(kk+0)*DD+d], k1 = p.WKf[(kk+1)*DD+d], k2 = p.WKf[(kk+2)*DD+d], k3 = p.WKf[(kk+3)*DD+d];
    float v0 = p.WVf[(kk+0)*DD+d], v1 = p.WVf[(kk+1)*DD+d], v2 = p.WVf[(kk+2)*DD+d], v3 = p.WVf[(kk+3)*DD+d];
    #pragma unroll
    for (int t = 0; t < 16; t++){
      float4 xv = *(const float4*)&xt[grp*16+t][kk];
      aK[t] = fmaf(xv.x,k0, fmaf(xv.y,k1, fmaf(xv.z,k2, fmaf(xv.w,k3, aK[t]))));
      aV[t] = fmaf(xv.x,v0, fmaf(xv.y,v1, fmaf(xv.z,v2, fmaf(xv.w,v3, aV[t]))));
    }
  }
  #pragma unroll
  for (int t = 0; t < 16; t++){
    int gt = g0 + grp*16 + t;
    if (gt < NTOT){ p.A_K[(long)gt*DD+d] = aK[t]; p.A_V[(long)gt*DD+d] = aV[t]; }
  }
}

// ---------- phase0: LN(slots)->q->qW,qb; publish spss from spst ----------
// uses sm[0..520); slrow/spst outside that range
__device__ void phase0(const PP& p, int bs, int tid, float* sm, const float* slrow, const float* spst){
  float* sn   = sm;        // 128
  float* qv   = sm + 128;  // 128
  float* part = sm + 256;  // 256
  float* red  = sm + 512;  // 8
  int o = tid & 127, h = tid >> 7;
  float v = (tid < 128) ? slrow[tid] : 0.f;
  float s1 = v, s2 = v*v;
  #pragma unroll
  for (int m = 1; m < 64; m <<= 1){ s1 += __shfl_xor(s1, m); s2 += __shfl_xor(s2, m); }
  if (tid < 128 && (tid & 63) == 0){ red[(tid>>6)*2] = s1; red[(tid>>6)*2+1] = s2; }
  __syncthreads();
  float mean = (red[0]+red[2])*(1.f/128.f);
  float var  = (red[1]+red[3])*(1.f/128.f) - mean*mean;
  float rstd = rsqrtf(var + 1e-5f);
  if (tid < 128) sn[tid] = (v-mean)*rstd*p.ln_g[tid] + p.ln_b[tid];
  __syncthreads();
  float acc = 0.f;
  for (int k = 0; k < 64; k++) acc = fmaf(sn[h*64+k], p.WQ[(h*64+k)*128+o], acc);
  part[h*128+o] = acc;
  __syncthreads();
  if (tid < 128) qv[tid] = part[tid] + part[128+tid];
  __syncthreads();
  float acc2 = 0.f;
  for (int k = 0; k < 64; k++) acc2 = fmaf(qv[h*64+k], p.Wf2T[(h*64+k)*128+o], acc2);
  part[h*128+o] = acc2;
  __syncthreads();
  if (tid < 128) p.qw_g[(long)bs*128+tid] = part[tid] + part[128+tid];
  float pb = (tid < 128) ? qv[tid]*p.bf2[tid] : 0.f;
  #pragma unroll
  for (int m = 1; m < 64; m <<= 1) pb += __shfl_xor(pb, m);
  if ((tid & 63) == 0) red[4 + (tid>>6)] = pb;
  __syncthreads();
  if (tid == 0){
    p.qb_g[bs] = FSCALE*(red[4]+red[5]+red[6]+red[7]);
    p.spss_g[bs*4+0] = spst[0]; p.spss_g[bs*4+1] = spst[1];
    p.spss_g[bs*4+2] = 1.f/(spst[2]*5.0f); p.spss_g[bs*4+3] = 1.f/(spst[3]*5.0f);
  }
  __syncthreads();
}

// ---------- persistent iteration kernel: 320 blocks x 256, software grid barrier ----------
__global__ __launch_bounds__(256, 2) void k_pers(PP p){
  __shared__ float smem[4608];
  const int blk = blockIdx.x, tid = threadIdx.x;
  const int bs = blk, bb = blk >> 3, ss = blk & 7;
  float* sl   = smem + 4352;   // persistent slots [128]
  float* spst = smem + 4480;   // persistent Sp0,Sp1,Ss0,Ss1 [4]
  int bi = 0;

  // ---- init ----
  if (tid < 128) sl[tid] = p.slots_init[ss*128+tid];
  if (tid < 4)   spst[tid] = (tid < 2) ? p.Sp_init[ss*2+tid] : p.Ss_init[ss*2+(tid-2)];
  if (ss == 0){
    for (int f = tid; f < 448; f += 256){
      float g0 = 0.f, g1 = 0.f;
      if (f < NT){ int idx = p.tok_idx[bb*NT+f]; g0 = p.abs_grid[idx*2]; g1 = p.abs_grid[idx*2+1]; }
      p.ag_g[((long)bb*448+f)*2]   = g0;
      p.ag_g[((long)bb*448+f)*2+1] = g1;
    }
  }
  __syncthreads();
  phase0(p, bs, tid, smem, sl, spst);
  gsync(p.bar, bi++, NBLK);

  for (int t = 0; t < 4; t++){
    // ===== P1: dots + softmax-over-s (+eps) for (b=bb, jtile=ss: 56 tokens) =====
    {
      float* qws = smem;            // 1024, swizzled
      float* wg  = smem + 1024;     // 256
      float* qbs = smem + 1280;     // 8
      float* spl = smem + 1288;     // 32
      for (int f = tid; f < 1024; f += 256){
        int s = f >> 7, d = f & 127;
        qws[s*128 + (d&15)*8 + (d>>4)] = p.qw_g[((long)bb*8+s)*128 + d];
      }
      wg[tid] = p.Wg1[tid];
      if (tid < 8)  qbs[tid] = p.qb_g[bb*8+tid];
      if (tid < 32) spl[tid] = p.spss_g[bb*32+tid];
      __syncthreads();
      int dg = tid & 7;
      float w0[16], w1[16];
      #pragma unroll
      for (int i = 0; i < 16; i++){ w0[i] = wg[dg*16+i]; w1[i] = wg[128+dg*16+i]; }
      #pragma unroll
      for (int pass = 0; pass < 2; pass++){
        int jj = pass*32 + (tid >> 3);
        int j = ss*56 + jj;
        bool valid = (jj < 56) && (j < NT);
        int jcl = valid ? j : 0;
        float aa[16];
        const float* src = p.A_K + ((long)(bb*NT+jcl))*DD + dg*16;
        #pragma unroll
        for (int i4 = 0; i4 < 4; i4++){
          float4 tt = *(const float4*)(src + i4*4);
          aa[i4*4]=tt.x; aa[i4*4+1]=tt.y; aa[i4*4+2]=tt.z; aa[i4*4+3]=tt.w;
        }
        float g0 = p.ag_g[((long)bb*448+jcl)*2], g1 = p.ag_g[((long)bb*448+jcl)*2+1];
        float dv[8];
        #pragma unroll
        for (int s = 0; s < 8; s++){
          float rel0 = (g0 - spl[s*4])*spl[s*4+2];
          float rel1 = (g1 - spl[s*4+1])*spl[s*4+3];
          float acc = 0.f;
          #pragma unroll
          for (int i = 0; i < 16; i++){
            float hk = fmaxf(fmaf(rel0, w0[i], fmaf(rel1, w1[i], aa[i])), 0.f);
            acc = fmaf(hk, qws[s*128 + i*8 + dg], acc);
          }
          acc += __shfl_xor(acc, 1); acc += __shfl_xor(acc, 2); acc += __shfl_xor(acc, 4);
          dv[s] = acc*FSCALE + qbs[s];
        }
        if (dg == 0 && valid){
          float m = -1e30f;
          #pragma unroll
          for (int s = 0; s < 8; s++) m = fmaxf(m, dv[s]);
          float tot = 0.f;
          #pragma unroll
          for (int s = 0; s < 8; s++){ dv[s] = expf(dv[s]-m); tot += dv[s]; }
          float inv = 1.f/tot;
          #pragma unroll
          for (int s = 0; s < 8; s++) p.a_g[((long)(bb*8+s))*448 + j] = dv[s]*inv + 1e-8f;
        }
      }
    }
    gsync(p.bar, bi++, NBLK);

    // ===== P234: per (b,s) — sums/Sp/Ss (or attn out), hbar, GRU, MLP, next phase0 =====
    {
      float* a_l = smem;          // 448
      float* agx = smem + 448;    // 448
      float* agy = smem + 896;    // 448
      float* red = smem + 1344;   // 16
      float* bc  = smem + 1360;   // 4
      float* spl = smem + 1376;   // 4 (old spss, own slot)
      for (int f = tid; f < 448; f += 256){
        bool v = f < NT;
        a_l[f] = v ? p.a_g[(long)bs*448+f] : 0.f;
        agx[f] = v ? p.ag_g[((long)bb*448+f)*2]   : 0.f;
        agy[f] = v ? p.ag_g[((long)bb*448+f)*2+1] : 0.f;
      }
      if (tid < 4) spl[tid] = p.spss_g[bs*4+tid];
      __syncthreads();
      float sa = 0.f, s0 = 0.f, s1 = 0.f;
      for (int jx = tid; jx < 448; jx += 256){
        float a = a_l[jx];
        sa += a; s0 = fmaf(a, agx[jx], s0); s1 = fmaf(a, agy[jx], s1);
      }
      #pragma unroll
      for (int m = 1; m < 64; m <<= 1){ sa += __shfl_xor(sa,m); s0 += __shfl_xor(s0,m); s1 += __shfl_xor(s1,m); }
      if ((tid & 63) == 0){ int w = tid>>6; red[w*4]=sa; red[w*4+1]=s0; red[w*4+2]=s1; }
      __syncthreads();
      if (tid == 0){
        float SA = red[0]+red[4]+red[8]+red[12];
        float S0 = red[1]+red[5]+red[9]+red[13];
        float S1 = red[2]+red[6]+red[10]+red[14];
        bc[0] = S0/SA; bc[1] = S1/SA; bc[2] = 1.f/SA;
      }
      __syncthreads();
      if (t == 3){
        if ((bb % 5) == 2){
          float inv = bc[2];
          long base = (long)NB*NS*DD + (long)(bb/5)*(NS*NT) + (long)ss*NT;
          for (int jx = tid; jx < NT; jx += 256) p.out[base+jx] = a_l[jx]*inv;
        }
      } else {
        float Sp0 = bc[0], Sp1 = bc[1];
        float q0 = 0.f, q1 = 0.f;
        for (int jx = tid; jx < 448; jx += 256){
          float a = a_l[jx];
          float e0 = agx[jx]-Sp0, e1 = agy[jx]-Sp1;
          q0 = fmaf(a, e0*e0, q0); q1 = fmaf(a, e1*e1, q1);
        }
        #pragma unroll
        for (int m = 1; m < 64; m <<= 1){ q0 += __shfl_xor(q0,m); q1 += __shfl_xor(q1,m); }
        if ((tid & 63) == 0){ int w = tid>>6; red[w*4]=q0; red[w*4+1]=q1; }
        __syncthreads();
        if (tid == 0){
          float Q0 = red[0]+red[4]+red[8]+red[12];
          float Q1 = red[1]+red[5]+red[9]+red[13];
          spst[0] = Sp0; spst[1] = Sp1;
          spst[2] = sqrtf(Q0*bc[2]); spst[3] = sqrtf(Q1*bc[2]);
        }
        __syncthreads();
        // ---- hbar over all j (old spss in spl) ----
        int d = tid & 127, jp = tid >> 7;
        float sp0 = spl[0], sp1 = spl[1], si0 = spl[2], si1 = spl[3];
        float wgd0 = p.Wg1[d], wgd1 = p.Wg1[DD+d];
        float acc = 0.f;
        for (int j = jp; j < NT; j += 2){
          float av = p.A_V[((long)(bb*NT+j))*DD + d];
          float rel0 = (agx[j]-sp0)*si0, rel1 = (agy[j]-sp1)*si1;
          float hv = fmaxf(fmaf(rel0, wgd0, fmaf(rel1, wgd1, av)), 0.f);
          acc = fmaf(a_l[j], hv, acc);
        }
        float* hpart = smem + 1536;  // 256
        float* hb    = smem + 1792;  // 128
        hpart[jp*128+d] = acc;
        __syncthreads();
        if (tid < 128) hb[tid] = (hpart[tid] + hpart[128+tid]) * bc[2];
        __syncthreads();
        // ---- updates = hb@Wf2 + bf2 ----
        float* part = smem + 1920;   // 256
        int o = tid & 127, h = tid >> 7;
        float acc2 = 0.f;
        for (int k = 0; k < 64; k++) acc2 = fmaf(hb[h*64+k], p.Wf2[(h*64+k)*128+o], acc2);
        part[h*128+o] = acc2;
        __syncthreads();
        float* upd = smem + 2176;    // 128
        if (tid < 128) upd[tid] = part[tid] + part[128+tid] + p.bf2[tid];
        __syncthreads();
        // ---- GRU ----
        float* gil = smem + 2432;    // 384
        float* ghl = smem + 2816;    // 384
        int oA = tid, oB = tid + 256;
        float giA = p.gru_b_ih[oA], ghA = p.gru_b_hh[oA];
        float giB = 0.f, ghB = 0.f;
        if (tid < 128){ giB = p.gru_b_ih[oB]; ghB = p.gru_b_hh[oB]; }
        for (int k = 0; k < 128; k++){
          float uk = upd[k], sk = sl[k];
          giA = fmaf(uk, p.gru_w_ih[k*384+oA], giA);
          ghA = fmaf(sk, p.gru_w_hh[k*384+oA], ghA);
          if (tid < 128){
            giB = fmaf(uk, p.gru_w_ih[k*384+oB], giB);
            ghB = fmaf(sk, p.gru_w_hh[k*384+oB], ghB);
          }
        }
        gil[oA] = giA; ghl[oA] = ghA;
        if (tid < 128){ gil[oB] = giB; ghl[oB] = ghB; }
        __syncthreads();
        float* hnl = smem + 1408;    // 128
        float hnv = 0.f;
        if (tid < 128){
          float r = 1.f/(1.f+expf(-(gil[tid]+ghl[tid])));
          float z = 1.f/(1.f+expf(-(gil[128+tid]+ghl[128+tid])));
          float n = tanhf(gil[256+tid] + r*ghl[256+tid]);
          hnv = (1.f-z)*n + z*sl[tid];
        }
        float t1 = hnv, t2 = hnv*hnv;
        #pragma unroll
        for (int m = 1; m < 64; m <<= 1){ t1 += __shfl_xor(t1,m); t2 += __shfl_xor(t2,m); }
        if (tid < 128 && (tid & 63) == 0){ red[(tid>>6)*2] = t1; red[(tid>>6)*2+1] = t2; }
        __syncthreads();
        float mean = (red[0]+red[2])*(1.f/128.f);
        float var  = (red[1]+red[3])*(1.f/128.f) - mean*mean;
        float rstd = rsqrtf(var + 1e-5f);
        float* yv = smem + 3200;     // 128
        if (tid < 128){
          hnl[tid] = hnv;
          yv[tid] = (hnv-mean)*rstd*p.mlp_ln_g[tid] + p.mlp_ln_b[tid];
        }
        __syncthreads();
        float* h1 = smem + 3328;     // 512
        float m1A = p.mlp_b1[tid], m1B = p.mlp_b1[tid+256];
        for (int k = 0; k < 128; k++){
          float y = yv[k];
          m1A = fmaf(y, p.mlp_w1[k*512+tid], m1A);
          m1B = fmaf(y, p.mlp_w1[k*512+tid+256], m1B);
        }
        h1[tid] = fmaxf(m1A, 0.f); h1[tid+256] = fmaxf(m1B, 0.f);
        __syncthreads();
        float a2 = 0.f;
        for (int kk = 0; kk < 256; kk++) a2 = fmaf(h1[h*256+kk], p.mlp_w2[(h*256+kk)*128+o], a2);
        part[h*128+o] = a2;
        __syncthreads();
        if (tid < 128) sl[tid] = hnl[tid] + p.mlp_b2[tid] + part[tid] + part[128+tid];
        __syncthreads();
        phase0(p, bs, tid, smem, sl, spst);
      }
    }
    if (t < 3) gsync(p.bar, bi++, NBLK);
  }

  // ===== P5: final slot projection =====
  {
    __syncthreads();
    float* part = smem + 256;
    int o = tid & 127, h = tid >> 7;
    float acc = 0.f;
    for (int k = 0; k < 64; k++) acc = fmaf(sl[h*64+k], p.fin_w[(h*64+k)*128+o], acc);
    part[h*128+o] = acc;
    __syncthreads();
    if (tid < 128) p.out[(long)bs*128+tid] = p.fin_b[tid] + part[tid] + part[128+tid];
  }
}

extern "C" void kernel_launch(void* const* d_in, const int* in_sizes, int n_in,
                              void* d_out, int out_size, void* d_ws, size_t ws_size,
                              hipStream_t stream){
  PP p;
  p.inputs=(const float*)d_in[0]; p.tok_idx=(const int*)d_in[1]; p.abs_grid=(const float*)d_in[2];
  p.slots_init=(const float*)d_in[3]; p.Sp_init=(const float*)d_in[4]; p.Ss_init=(const float*)d_in[5];
  p.WQ=(const float*)d_in[6]; p.ln_g=(const float*)d_in[7]; p.ln_b=(const float*)d_in[8];
  p.gru_w_ih=(const float*)d_in[9]; p.gru_w_hh=(const float*)d_in[10];
  p.gru_b_ih=(const float*)d_in[11]; p.gru_b_hh=(const float*)d_in[12];
  p.mlp_ln_g=(const float*)d_in[13]; p.mlp_ln_b=(const float*)d_in[14];
  p.mlp_w1=(const float*)d_in[15]; p.mlp_b1=(const float*)d_in[16];
  p.mlp_w2=(const float*)d_in[17]; p.mlp_b2=(const float*)d_in[18];
  p.WK=(const float*)d_in[19]; p.WV=(const float*)d_in[20]; p.Wg=(const float*)d_in[21]; p.bg=(const float*)d_in[22];
  p.Wf1=(const float*)d_in[23]; p.bf1=(const float*)d_in[24]; p.Wf2=(const float*)d_in[25]; p.bf2=(const float*)d_in[26];
  p.im_ln1_g=(const float*)d_in[27]; p.im_ln1_b=(const float*)d_in[28];
  p.im_w1=(const float*)d_in[29]; p.im_b1=(const float*)d_in[30];
  p.im_w2=(const float*)d_in[31]; p.im_b2=(const float*)d_in[32];
  p.im_ln2_g=(const float*)d_in[33]; p.im_ln2_b=(const float*)d_in[34];
  p.fin_w=(const float*)d_in[35]; p.fin_b=(const float*)d_in[36];

  float* w = (float*)d_ws;
  size_t need = 0;
  auto alloc = [&](size_t nfl){ nfl = (nfl + 3) & ~(size_t)3; float* r = w + need; need += nfl; return r; };
  p.x    = alloc((size_t)NTOT*DD);
  p.A_K  = alloc((size_t)NTOT*DD);
  p.A_V  = alloc((size_t)NTOT*DD);
  p.WKf  = alloc(DD*DD);
  p.WVf  = alloc(DD*DD);
  p.Wg1  = alloc(2*DD);
  p.c1   = alloc(DD);
  p.Wf2T = alloc(DD*DD);
  p.qw_g   = alloc(320*128);
  p.qb_g   = alloc(320);
  p.spss_g = alloc(320*4);
  p.a_g    = alloc((size_t)320*448);
  p.ag_g   = alloc((size_t)40*448*2);
  p.bar    = (int*)alloc(16);
  p.xnh  = (ushort*)alloc((size_t)NTOT*DIN/2);
  p.xnl  = (ushort*)alloc((size_t)NTOT*DIN/2);
  p.hh   = (ushort*)alloc((size_t)NTOT*DIN/2);
  p.hl   = (ushort*)alloc((size_t)NTOT*DIN/2);
  p.W1Th = (ushort*)alloc((size_t)DIN*DIN/2);
  p.W1Tl = (ushort*)alloc((size_t)DIN*DIN/2);
  p.W2Th = (ushort*)alloc((size_t)DD*DIN/2);
  p.W2Tl = (ushort*)alloc((size_t)DD*DIN/2);
  p.out = (float*)d_out;
  if (ws_size < need*sizeof(float)){
    fprintf(stderr, "kernel_launch: ws too small (%zu < %zu)\n", ws_size, need*sizeof(float));
    return;
  }

  prep_weights<<<dim3(DD), dim3(128), 0, stream>>>(p);
  transpose_split<<<dim3(DIN/64, DIN/64), dim3(256), 0, stream>>>(p.im_w1, p.W1Th, p.W1Tl, DIN, DIN);
  transpose_split<<<dim3(DIN/64, DD/64), dim3(256), 0, stream>>>(p.im_w2, p.W2Th, p.W2Tl, DIN, DD);
  ln1_split<<<dim3(NTOT/4), dim3(256), 0, stream>>>(p);
  gemm_split<1><<<dim3(DIN/128, (NTOT+63)/64), dim3(256), 0, stream>>>(
      p.xnh, p.xnl, p.W1Th, p.W1Tl, p.im_b1, p.hh, p.hl,
      nullptr, nullptr, nullptr, NTOT);
  gemm_split<2><<<dim3(1, (NTOT+63)/64), dim3(256), 0, stream>>>(
      p.hh, p.hl, p.W2Th, p.W2Tl, p.im_b2, nullptr, nullptr,
      p.x, p.im_ln2_g, p.im_ln2_b, NTOT);
  k2_proj<<<dim3((NTOT+31)/32), dim3(256), 0, stream>>>(p);
  k_pers<<<dim3(NBLK), dim3(256), 0, stream>>>(p);
}

// Round 8
// 1187.176 us; speedup vs baseline: 1.2305x; 1.1736x over previous
//
#include <hip/hip_runtime.h>
#include <cstdio>

#define NB 40
#define NS 8
#define NT 441
#define DIN 768
#define DD 128
#define NTOT (NB*NT)
#define NBLK 320
#define FSCALE 0.08838834764831843f

typedef short s8v __attribute__((ext_vector_type(8)));
typedef float f4v __attribute__((ext_vector_type(4)));

__device__ inline ushort f2bf(float f){
  unsigned u = __float_as_uint(f);
  unsigned r = (u + 0x7fffu + ((u >> 16) & 1u)) >> 16;
  return (ushort)r;
}
__device__ inline float bf2f(ushort h){ return __uint_as_float(((unsigned)h) << 16); }

struct PP {
  const float *inputs; const int *tok_idx; const float *abs_grid;
  const float *slots_init, *Sp_init, *Ss_init;
  const float *WQ, *ln_g, *ln_b;
  const float *gru_w_ih, *gru_w_hh, *gru_b_ih, *gru_b_hh;
  const float *mlp_ln_g, *mlp_ln_b, *mlp_w1, *mlp_b1, *mlp_w2, *mlp_b2;
  const float *WK, *WV, *Wg, *bg, *Wf1, *bf1, *Wf2, *bf2;
  const float *im_ln1_g, *im_ln1_b, *im_w1, *im_b1, *im_w2, *im_b2, *im_ln2_g, *im_ln2_b;
  const float *fin_w, *fin_b;
  float *x, *A_K, *A_V, *WKf, *WVf, *Wg1, *c1, *Wf2T;
  float *dots_g;
  int *bar;
  ushort *xnh, *xnl, *hh, *hl, *W1Th, *W1Tl, *W2Th, *W2Tl;
  float *out;
};

// ---------- per-group barrier: RELAXED polls (no per-poll invalidate), one ACQUIRE load at exit ----------
__device__ inline void gsync(int* bar, int idx, int n){
  __syncthreads();
  if (threadIdx.x == 0){
    __threadfence();                                   // release: flush own writes
    atomicAdd(&bar[idx], 1);
    while (__hip_atomic_load(&bar[idx], __ATOMIC_RELAXED, __HIP_MEMORY_SCOPE_AGENT) < n)
      __builtin_amdgcn_s_sleep(2);
    (void)__hip_atomic_load(&bar[idx], __ATOMIC_ACQUIRE, __HIP_MEMORY_SCOPE_AGENT);  // invalidate once
  }
  __syncthreads();
}

// ---------- weight prep (also zeroes barrier counters: 40*32 ints) ----------
__global__ __launch_bounds__(128) void prep_weights(PP p){
  int r = blockIdx.x, d = threadIdx.x;
  if (r < 10) p.bar[r*128 + d] = 0;
  float accK = 0.f, accV = 0.f;
  for (int kk = 0; kk < DD; kk++){
    float w = p.Wf1[kk*DD + d];
    accK = fmaf(p.WK[r*DD+kk], w, accK);
    accV = fmaf(p.WV[r*DD+kk], w, accV);
  }
  p.WKf[r*DD+d] = accK; p.WVf[r*DD+d] = accV;
  if (r < 2){
    float a = 0.f;
    for (int kk = 0; kk < DD; kk++) a = fmaf(p.Wg[r*DD+kk], p.Wf1[kk*DD+d], a);
    p.Wg1[r*DD+d] = a;
  }
  if (r == 2){
    float a = 0.f;
    for (int kk = 0; kk < DD; kk++) a = fmaf(p.bg[kk], p.Wf1[kk*DD+d], a);
    p.c1[d] = a + p.bf1[d];
  }
  p.Wf2T[d*DD + r] = p.Wf2[r*DD + d];
}

// ---------- transpose + bf16 split ----------
__global__ __launch_bounds__(256) void transpose_split(const float* __restrict__ W,
                                                       ushort* __restrict__ WTh,
                                                       ushort* __restrict__ WTl,
                                                       int K, int N){
  __shared__ float tile[64][65];
  int tid = threadIdx.x;
  int k0 = blockIdx.x * 64, n0 = blockIdx.y * 64;
  #pragma unroll
  for (int i = 0; i < 4; i++){
    int k = i*16 + (tid >> 4);
    int n4 = (tid & 15) * 4;
    float4 v = *(const float4*)(W + (long)(k0+k)*N + n0 + n4);
    tile[k][n4+0] = v.x; tile[k][n4+1] = v.y; tile[k][n4+2] = v.z; tile[k][n4+3] = v.w;
  }
  __syncthreads();
  #pragma unroll
  for (int i = 0; i < 4; i++){
    int n = i*16 + (tid >> 4);
    int k4 = (tid & 15) * 4;
    ushort4 h4, l4;
    float v0 = tile[k4+0][n], v1 = tile[k4+1][n], v2 = tile[k4+2][n], v3 = tile[k4+3][n];
    h4.x = f2bf(v0); l4.x = f2bf(v0 - bf2f(h4.x));
    h4.y = f2bf(v1); l4.y = f2bf(v1 - bf2f(h4.y));
    h4.z = f2bf(v2); l4.z = f2bf(v2 - bf2f(h4.z));
    h4.w = f2bf(v3); l4.w = f2bf(v3 - bf2f(h4.w));
    *(ushort4*)(WTh + (long)(n0+n)*K + k0 + k4) = h4;
    *(ushort4*)(WTl + (long)(n0+n)*K + k0 + k4) = l4;
  }
}

// ---------- LN1 + bf16 hi/lo split ----------
__global__ __launch_bounds__(256) void ln1_split(PP p){
  int tok = blockIdx.x*4 + (threadIdx.x >> 6);
  int l = threadIdx.x & 63;
  const float* src = p.inputs + (long)tok*DIN;
  float4 v[3];
  float s = 0.f, s2 = 0.f;
  #pragma unroll
  for (int pp = 0; pp < 3; pp++){
    v[pp] = *(const float4*)(src + pp*256 + l*4);
    s  += v[pp].x + v[pp].y + v[pp].z + v[pp].w;
    s2 += v[pp].x*v[pp].x + v[pp].y*v[pp].y + v[pp].z*v[pp].z + v[pp].w*v[pp].w;
  }
  #pragma unroll
  for (int m = 1; m < 64; m <<= 1){ s += __shfl_xor(s, m); s2 += __shfl_xor(s2, m); }
  float mean = s*(1.f/DIN), var = s2*(1.f/DIN) - mean*mean;
  float rstd = rsqrtf(var + 1e-5f);
  #pragma unroll
  for (int pp = 0; pp < 3; pp++){
    int idx = pp*256 + l*4;
    float4 g = *(const float4*)(p.im_ln1_g + idx);
    float4 b = *(const float4*)(p.im_ln1_b + idx);
    float y0 = (v[pp].x-mean)*rstd*g.x + b.x;
    float y1 = (v[pp].y-mean)*rstd*g.y + b.y;
    float y2 = (v[pp].z-mean)*rstd*g.z + b.z;
    float y3 = (v[pp].w-mean)*rstd*g.w + b.w;
    ushort4 h4, l4;
    h4.x = f2bf(y0); l4.x = f2bf(y0 - bf2f(h4.x));
    h4.y = f2bf(y1); l4.y = f2bf(y1 - bf2f(h4.y));
    h4.z = f2bf(y2); l4.z = f2bf(y2 - bf2f(h4.z));
    h4.w = f2bf(y3); l4.w = f2bf(y3 - bf2f(h4.w));
    *(ushort4*)(p.xnh + (long)tok*DIN + idx) = h4;
    *(ushort4*)(p.xnl + (long)tok*DIN + idx) = l4;
  }
}

// ---------- split-bf16 MFMA GEMM ----------
template<int EPI>
__global__ __launch_bounds__(256) void gemm_split(
    const ushort* __restrict__ Ah, const ushort* __restrict__ Al,
    const ushort* __restrict__ Bh, const ushort* __restrict__ Bl,
    const float* __restrict__ bias,
    ushort* __restrict__ Ch, ushort* __restrict__ Cl,
    float* __restrict__ Xout, const float* __restrict__ g2, const float* __restrict__ b2,
    int M)
{
  __shared__ __align__(16) char smemc[64*132*4];
  ushort* As = (ushort*)smemc;
  ushort* Bs = (ushort*)(smemc + 10240);
  int tid = threadIdx.x;
  int n0 = blockIdx.x * 128, m0 = blockIdx.y * 64;
  int w = tid >> 6, lane = tid & 63;
  f4v acc[4][2];
  #pragma unroll
  for (int mf = 0; mf < 4; mf++)
    #pragma unroll
    for (int nf = 0; nf < 2; nf++) acc[mf][nf] = (f4v)(0.f);

  for (int kb = 0; kb < DIN; kb += 32){
    __syncthreads();
    #pragma unroll
    for (int i = 0; i < 2; i++){
      int c = tid + i*256;
      int s = c >> 8, r = (c >> 2) & 63, kg = c & 3;
      int gr = min(m0 + r, M-1);
      const float4 va = *(const float4*)((s ? Al : Ah) + (long)gr*DIN + kb + kg*8);
      *(float4*)(As + s*2560 + r*40 + kg*8) = va;
    }
    #pragma unroll
    for (int i = 0; i < 4; i++){
      int c = tid + i*256;
      int s = c >> 9, r = (c >> 2) & 127, kg = c & 3;
      const float4 vb = *(const float4*)((s ? Bl : Bh) + (long)(n0 + r)*DIN + kb + kg*8);
      *(float4*)(Bs + s*5120 + r*40 + kg*8) = vb;
    }
    __syncthreads();
    int kg = lane >> 4, rA = lane & 15;
    s8v a0[4], a1[4], b0[2], b1[2];
    #pragma unroll
    for (int mf = 0; mf < 4; mf++){
      a0[mf] = *(const s8v*)(As +        (mf*16 + rA)*40 + kg*8);
      a1[mf] = *(const s8v*)(As + 2560 + (mf*16 + rA)*40 + kg*8);
    }
    #pragma unroll
    for (int nf = 0; nf < 2; nf++){
      int rb = w*32 + nf*16 + rA;
      b0[nf] = *(const s8v*)(Bs +        rb*40 + kg*8);
      b1[nf] = *(const s8v*)(Bs + 5120 + rb*40 + kg*8);
    }
    #pragma unroll
    for (int mf = 0; mf < 4; mf++)
      #pragma unroll
      for (int nf = 0; nf < 2; nf++){
        acc[mf][nf] = __builtin_amdgcn_mfma_f32_16x16x32_bf16(a0[mf], b0[nf], acc[mf][nf], 0, 0, 0);
        acc[mf][nf] = __builtin_amdgcn_mfma_f32_16x16x32_bf16(a0[mf], b1[nf], acc[mf][nf], 0, 0, 0);
        acc[mf][nf] = __builtin_amdgcn_mfma_f32_16x16x32_bf16(a1[mf], b0[nf], acc[mf][nf], 0, 0, 0);
      }
  }

  int rbase = (lane >> 4) * 4, cn = lane & 15;
  if (EPI == 1){
    #pragma unroll
    for (int mf = 0; mf < 4; mf++)
      #pragma unroll
      for (int nf = 0; nf < 2; nf++){
        int n = n0 + w*32 + nf*16 + cn;
        float bs = bias[n];
        #pragma unroll
        for (int r = 0; r < 4; r++){
          int m = m0 + mf*16 + rbase + r;
          if (m < M){
            float v = fmaxf(acc[mf][nf][r] + bs, 0.f);
            ushort h = f2bf(v);
            Ch[(long)m*DIN + n] = h;
            Cl[(long)m*DIN + n] = f2bf(v - bf2f(h));
          }
        }
      }
  } else {
    __syncthreads();
    float* Dl = (float*)smemc;
    #pragma unroll
    for (int mf = 0; mf < 4; mf++)
      #pragma unroll
      for (int nf = 0; nf < 2; nf++){
        int n = w*32 + nf*16 + cn;
        float bs = bias[n];
        #pragma unroll
        for (int r = 0; r < 4; r++)
          Dl[(mf*16 + rbase + r)*132 + n] = acc[mf][nf][r] + bs;
      }
    __syncthreads();
    for (int rr = 0; rr < 16; rr++){
      int row = w*16 + rr;
      float e0 = Dl[row*132 + lane], e1 = Dl[row*132 + 64 + lane];
      float s = e0 + e1, s2 = e0*e0 + e1*e1;
      #pragma unroll
      for (int m2 = 1; m2 < 64; m2 <<= 1){ s += __shfl_xor(s, m2); s2 += __shfl_xor(s2, m2); }
      float mean = s*(1.f/DD), var = s2*(1.f/DD) - mean*mean;
      float rstd = rsqrtf(var + 1e-5f);
      int m = m0 + row;
      if (m < M){
        Xout[(long)m*DD + lane]      = (e0-mean)*rstd*g2[lane]      + b2[lane];
        Xout[(long)m*DD + 64 + lane] = (e1-mean)*rstd*g2[64 + lane] + b2[64 + lane];
      }
    }
  }
}

// ---------- A_K = x@WKf + c1 ; A_V = x@WVf + c1 ----------
__global__ __launch_bounds__(256) void k2_proj(PP p){
  __shared__ float xt[32][132];
  int tid = threadIdx.x; int g0 = blockIdx.x * 32;
  for (int f = tid; f < 32*32; f += 256){
    int tok = f >> 5, pos = (f & 31) * 4;
    int gt = g0 + tok;
    float4 v = (gt < NTOT) ? *(const float4*)(p.x + (long)gt*DD + pos)
                           : make_float4(0.f,0.f,0.f,0.f);
    *(float4*)&xt[tok][pos] = v;
  }
  __syncthreads();
  int d = tid & 127, grp = tid >> 7;
  float aK[16], aV[16];
  float c1v = p.c1[d];
  #pragma unroll
  for (int t = 0; t < 16; t++){ aK[t] = c1v; aV[t] = c1v; }
  for (int kk = 0; kk < DD; kk += 4){
    float k0 = p.WKf[(kk+0)*DD+d], k1 = p.WKf[(kk+1)*DD+d], k2 = p.WKf[(kk+2)*DD+d], k3 = p.WKf[(kk+3)*DD+d];
    float v0 = p.WVf[(kk+0)*DD+d], v1 = p.WVf[(kk+1)*DD+d], v2 = p.WVf[(kk+2)*DD+d], v3 = p.WVf[(kk+3)*DD+d];
    #pragma unroll
    for (int t = 0; t < 16; t++){
      float4 xv = *(const float4*)&xt[grp*16+t][kk];
      aK[t] = fmaf(xv.x,k0, fmaf(xv.y,k1, fmaf(xv.z,k2, fmaf(xv.w,k3, aK[t]))));
      aV[t] = fmaf(xv.x,v0, fmaf(xv.y,v1, fmaf(xv.z,v2, fmaf(xv.w,v3, aV[t]))));
    }
  }
  #pragma unroll
  for (int t = 0; t < 16; t++){
    int gt = g0 + grp*16 + t;
    if (gt < NTOT){ p.A_K[(long)gt*DD+d] = aK[t]; p.A_V[(long)gt*DD+d] = aV[t]; }
  }
}

// ---------- phase0 (block-local): LN(sl)->q->qW_l, sc[0]=qb, sc[1..4]=spss from spst ----------
__device__ void phase0(const PP& p, int tid, float* scr, const float* sl, const float* spst,
                       float* qw_l, float* sc){
  float* sn   = scr;        // 128
  float* qv   = scr + 128;  // 128
  float* part = scr + 256;  // 256
  float* red  = scr + 512;  // 8
  int o = tid & 127, h = tid >> 7;
  float v = (tid < 128) ? sl[tid] : 0.f;
  float s1 = v, s2 = v*v;
  #pragma unroll
  for (int m = 1; m < 64; m <<= 1){ s1 += __shfl_xor(s1,m); s2 += __shfl_xor(s2,m); }
  if (tid < 128 && (tid & 63) == 0){ red[(tid>>6)*2] = s1; red[(tid>>6)*2+1] = s2; }
  __syncthreads();
  float mean = (red[0]+red[2])*(1.f/128.f);
  float var  = (red[1]+red[3])*(1.f/128.f) - mean*mean;
  float rstd = rsqrtf(var + 1e-5f);
  if (tid < 128) sn[tid] = (v-mean)*rstd*p.ln_g[tid] + p.ln_b[tid];
  __syncthreads();
  float acc = 0.f;
  for (int k = 0; k < 64; k++) acc = fmaf(sn[h*64+k], p.WQ[(h*64+k)*128+o], acc);
  part[h*128+o] = acc;
  __syncthreads();
  if (tid < 128) qv[tid] = part[tid] + part[128+tid];
  __syncthreads();
  float acc2 = 0.f;
  for (int k = 0; k < 64; k++) acc2 = fmaf(qv[h*64+k], p.Wf2T[(h*64+k)*128+o], acc2);
  part[h*128+o] = acc2;
  __syncthreads();
  if (tid < 128) qw_l[tid] = part[tid] + part[128+tid];
  float pb = (tid < 128) ? qv[tid]*p.bf2[tid] : 0.f;
  #pragma unroll
  for (int m = 1; m < 64; m <<= 1) pb += __shfl_xor(pb,m);
  if ((tid & 63) == 0) red[4 + (tid>>6)] = pb;
  __syncthreads();
  if (tid == 0){
    sc[0] = FSCALE*(red[4]+red[5]+red[6]+red[7]);
    sc[1] = spst[0]; sc[2] = spst[1];
    sc[3] = 1.f/(spst[2]*5.0f); sc[4] = 1.f/(spst[3]*5.0f);
  }
  __syncthreads();
}

// ---------- persistent per-(b,s) kernel: 320 blocks x 256, per-b 8-block barriers ----------
__global__ __launch_bounds__(256, 2) void k_pers(PP p){
  __shared__ float smem[5248];
  const int tid = threadIdx.x;
  const int bs = blockIdx.x, bb = bs >> 3, ss = bs & 7;
  float* agx  = smem;          // 448
  float* agy  = smem + 448;    // 448
  float* sl   = smem + 896;    // 128 persistent slots
  float* spst = smem + 1024;   // 4 (+4 pad) persistent Sp/Ss
  float* qw_l = smem + 1032;   // 128
  float* sc   = smem + 1160;   // 8: sc[0]=qb, sc[1..4]=spss
  float* scr  = smem + 1168;   // scratch (phase-dependent)

  // ---- init (fully block-local; no barrier needed before first P1) ----
  for (int f = tid; f < 448; f += 256){
    float g0 = 0.f, g1 = 0.f;
    if (f < NT){ int idx = p.tok_idx[bb*NT+f]; g0 = p.abs_grid[idx*2]; g1 = p.abs_grid[idx*2+1]; }
    agx[f] = g0; agy[f] = g1;
  }
  if (tid < 128) sl[tid] = p.slots_init[ss*128+tid];
  if (tid < 4)   spst[tid] = (tid < 2) ? p.Sp_init[ss*2+tid] : p.Ss_init[ss*2+(tid-2)];
  __syncthreads();
  phase0(p, tid, scr, sl, spst, qw_l, sc);

  int* bbar = p.bar + bb*32;

  for (int t = 0; t < 4; t++){
    // ===== P1: own-slot dots over all 441 tokens =====
    {
      int dg = tid & 7, jl = tid >> 3;
      float w0[16], w1[16], qw[16];
      #pragma unroll
      for (int i = 0; i < 16; i++){
        w0[i] = p.Wg1[dg*16+i];
        w1[i] = p.Wg1[128 + dg*16+i];
        qw[i] = qw_l[dg*16+i];
      }
      float sp0 = sc[1], sp1 = sc[2], si0 = sc[3], si1 = sc[4], qb = sc[0];
      float* drow = p.dots_g + (long)bs*448;
      for (int pass = 0; pass < 14; pass++){
        int j = pass*32 + jl;
        bool valid = j < NT;
        int jc = valid ? j : 0;
        float rel0 = (agx[jc]-sp0)*si0, rel1 = (agy[jc]-sp1)*si1;
        const float4* src = (const float4*)(p.A_K + ((long)(bb*NT+jc))*DD + dg*16);
        float acc = 0.f;
        #pragma unroll
        for (int i4 = 0; i4 < 4; i4++){
          float4 a4 = src[i4];
          float hk;
          hk = fmaxf(fmaf(rel0, w0[i4*4+0], fmaf(rel1, w1[i4*4+0], a4.x)), 0.f); acc = fmaf(hk, qw[i4*4+0], acc);
          hk = fmaxf(fmaf(rel0, w0[i4*4+1], fmaf(rel1, w1[i4*4+1], a4.y)), 0.f); acc = fmaf(hk, qw[i4*4+1], acc);
          hk = fmaxf(fmaf(rel0, w0[i4*4+2], fmaf(rel1, w1[i4*4+2], a4.z)), 0.f); acc = fmaf(hk, qw[i4*4+2], acc);
          hk = fmaxf(fmaf(rel0, w0[i4*4+3], fmaf(rel1, w1[i4*4+3], a4.w)), 0.f); acc = fmaf(hk, qw[i4*4+3], acc);
        }
        acc += __shfl_xor(acc, 1); acc += __shfl_xor(acc, 2); acc += __shfl_xor(acc, 4);
        if (dg == 0 && valid) drow[j] = acc*FSCALE + qb;
      }
    }
    gsync(bbar, 2*t, 8);

    // ===== P234: softmax-over-s (redundant per block), own attn row, Sp/Ss, hbar, GRU, MLP =====
    {
      float* d_l = scr;            // 8*449 = 3592
      float* a_l = scr + 3592;     // 448
      float* red = scr + 4040;     // 16
      float* bc  = scr + 4056;     // 4
      const float* dsrc = p.dots_g + (long)bb*8*448;
      for (int f = tid; f < 8*448; f += 256){
        int s = f / 448, j = f - s*448;
        d_l[s*449 + j] = dsrc[f];
      }
      __syncthreads();
      float rsum = 0.f, sx = 0.f, sy = 0.f;
      for (int j = tid; j < 448; j += 256){
        float a = 0.f;
        if (j < NT){
          float m = -1e30f;
          #pragma unroll
          for (int s = 0; s < 8; s++) m = fmaxf(m, d_l[s*449+j]);
          float tot = 0.f;
          #pragma unroll
          for (int s = 0; s < 8; s++) tot += expf(d_l[s*449+j] - m);
          a = expf(d_l[ss*449+j] - m)/tot + 1e-8f;
        }
        a_l[j] = a;
        rsum += a; sx = fmaf(a, agx[j], sx); sy = fmaf(a, agy[j], sy);
      }
      int wid = tid >> 6, lane = tid & 63;
      #pragma unroll
      for (int m = 1; m < 64; m <<= 1){
        rsum += __shfl_xor(rsum,m); sx += __shfl_xor(sx,m); sy += __shfl_xor(sy,m);
      }
      if (lane == 0){ red[wid] = rsum; red[4+wid] = sx; red[8+wid] = sy; }
      __syncthreads();
      if (tid == 0){
        float SA = red[0]+red[1]+red[2]+red[3];
        float SX = red[4]+red[5]+red[6]+red[7];
        float SY = red[8]+red[9]+red[10]+red[11];
        bc[0] = SX/SA; bc[1] = SY/SA; bc[2] = 1.f/SA;
      }
      __syncthreads();

      if (t == 3){
        if ((bb % 5) == 2){
          float inv = bc[2];
          long base = (long)NB*NS*DD + (long)(bb/5)*(NS*NT) + (long)ss*NT;
          for (int j = tid; j < NT; j += 256) p.out[base+j] = a_l[j]*inv;
        }
      } else {
        float Sp0 = bc[0], Sp1 = bc[1];
        float q0 = 0.f, q1 = 0.f;
        for (int j = tid; j < 448; j += 256){
          float a = a_l[j];
          float e0 = agx[j]-Sp0, e1 = agy[j]-Sp1;
          q0 = fmaf(a, e0*e0, q0); q1 = fmaf(a, e1*e1, q1);
        }
        #pragma unroll
        for (int m = 1; m < 64; m <<= 1){ q0 += __shfl_xor(q0,m); q1 += __shfl_xor(q1,m); }
        if (lane == 0){ red[wid] = q0; red[4+wid] = q1; }
        __syncthreads();
        if (tid == 0){
          float Q0 = red[0]+red[1]+red[2]+red[3];
          float Q1 = red[4]+red[5]+red[6]+red[7];
          spst[0] = Sp0; spst[1] = Sp1;
          spst[2] = sqrtf(Q0*bc[2]); spst[3] = sqrtf(Q1*bc[2]);
        }
        __syncthreads();
        // ---- hbar with OLD spss (sc) ----
        int d = tid & 127, jp = tid >> 7;
        float sp0o = sc[1], sp1o = sc[2], si0o = sc[3], si1o = sc[4];
        float wgd0 = p.Wg1[d], wgd1 = p.Wg1[DD+d];
        float acc = 0.f;
        for (int j = jp; j < NT; j += 2){
          float av = p.A_V[((long)(bb*NT+j))*DD + d];
          float r0 = (agx[j]-sp0o)*si0o, r1 = (agy[j]-sp1o)*si1o;
          float hv = fmaxf(fmaf(r0, wgd0, fmaf(r1, wgd1, av)), 0.f);
          acc = fmaf(a_l[j], hv, acc);
        }
        float* hpart = scr;          // 256 (d_l region, dead now)
        float* hb    = scr + 256;    // 128
        hpart[jp*128+d] = acc;
        __syncthreads();
        if (tid < 128) hb[tid] = (hpart[tid] + hpart[128+tid]) * bc[2];
        __syncthreads();
        // ---- upd = hb@Wf2 + bf2 ----
        float* part = scr + 384;     // 256
        int o = tid & 127, h = tid >> 7;
        float acc2 = 0.f;
        for (int k = 0; k < 64; k++) acc2 = fmaf(hb[h*64+k], p.Wf2[(h*64+k)*128+o], acc2);
        part[h*128+o] = acc2;
        __syncthreads();
        float* upd = scr + 640;      // 128
        if (tid < 128) upd[tid] = part[tid] + part[128+tid] + p.bf2[tid];
        __syncthreads();
        // ---- GRU ----
        float* gil = scr + 768;      // 384
        float* ghl = scr + 1152;     // 384
        int oA = tid, oB = tid + 256;
        float giA = p.gru_b_ih[oA], ghA = p.gru_b_hh[oA];
        float giB = 0.f, ghB = 0.f;
        if (tid < 128){ giB = p.gru_b_ih[oB]; ghB = p.gru_b_hh[oB]; }
        for (int k = 0; k < 128; k++){
          float uk = upd[k], sk = sl[k];
          giA = fmaf(uk, p.gru_w_ih[k*384+oA], giA);
          ghA = fmaf(sk, p.gru_w_hh[k*384+oA], ghA);
          if (tid < 128){
            giB = fmaf(uk, p.gru_w_ih[k*384+oB], giB);
            ghB = fmaf(sk, p.gru_w_hh[k*384+oB], ghB);
          }
        }
        gil[oA] = giA; ghl[oA] = ghA;
        if (tid < 128){ gil[oB] = giB; ghl[oB] = ghB; }
        __syncthreads();
        float* hnl = scr + 1536;     // 128
        float* yv  = scr + 1664;     // 128
        float hnv = 0.f;
        if (tid < 128){
          float r = 1.f/(1.f+expf(-(gil[tid]+ghl[tid])));
          float z = 1.f/(1.f+expf(-(gil[128+tid]+ghl[128+tid])));
          float n = tanhf(gil[256+tid] + r*ghl[256+tid]);
          hnv = (1.f-z)*n + z*sl[tid];
        }
        float t1 = hnv, t2 = hnv*hnv;
        #pragma unroll
        for (int m = 1; m < 64; m <<= 1){ t1 += __shfl_xor(t1,m); t2 += __shfl_xor(t2,m); }
        if (tid < 128 && (tid & 63) == 0){ red[(tid>>6)*2] = t1; red[(tid>>6)*2+1] = t2; }
        __syncthreads();
        float mean = (red[0]+red[2])*(1.f/128.f);
        float var  = (red[1]+red[3])*(1.f/128.f) - mean*mean;
        float rstd = rsqrtf(var + 1e-5f);
        if (tid < 128){
          hnl[tid] = hnv;
          yv[tid] = (hnv-mean)*rstd*p.mlp_ln_g[tid] + p.mlp_ln_b[tid];
        }
        __syncthreads();
        float* h1 = scr + 1792;      // 512
        float m1A = p.mlp_b1[tid], m1B = p.mlp_b1[tid+256];
        for (int k = 0; k < 128; k++){
          float y = yv[k];
          m1A = fmaf(y, p.mlp_w1[k*512+tid], m1A);
          m1B = fmaf(y, p.mlp_w1[k*512+tid+256], m1B);
        }
        h1[tid] = fmaxf(m1A, 0.f); h1[tid+256] = fmaxf(m1B, 0.f);
        __syncthreads();
        float a2 = 0.f;
        for (int kk = 0; kk < 256; kk++) a2 = fmaf(h1[h*256+kk], p.mlp_w2[(h*256+kk)*128+o], a2);
        part[h*128+o] = a2;
        __syncthreads();
        if (tid < 128) sl[tid] = hnl[tid] + p.mlp_b2[tid] + part[tid] + part[128+tid];
        __syncthreads();
        phase0(p, tid, scr, sl, spst, qw_l, sc);
      }
    }
    if (t < 3) gsync(bbar, 2*t+1, 8);
  }

  // ===== P5: final slot projection =====
  {
    float* part = scr;
    int o = tid & 127, h = tid >> 7;
    float acc = 0.f;
    for (int k = 0; k < 64; k++) acc = fmaf(sl[h*64+k], p.fin_w[(h*64+k)*128+o], acc);
    part[h*128+o] = acc;
    __syncthreads();
    if (tid < 128) p.out[(long)bs*128+tid] = p.fin_b[tid] + part[tid] + part[128+tid];
  }
}

extern "C" void kernel_launch(void* const* d_in, const int* in_sizes, int n_in,
                              void* d_out, int out_size, void* d_ws, size_t ws_size,
                              hipStream_t stream){
  PP p;
  p.inputs=(const float*)d_in[0]; p.tok_idx=(const int*)d_in[1]; p.abs_grid=(const float*)d_in[2];
  p.slots_init=(const float*)d_in[3]; p.Sp_init=(const float*)d_in[4]; p.Ss_init=(const float*)d_in[5];
  p.WQ=(const float*)d_in[6]; p.ln_g=(const float*)d_in[7]; p.ln_b=(const float*)d_in[8];
  p.gru_w_ih=(const float*)d_in[9]; p.gru_w_hh=(const float*)d_in[10];
  p.gru_b_ih=(const float*)d_in[11]; p.gru_b_hh=(const float*)d_in[12];
  p.mlp_ln_g=(const float*)d_in[13]; p.mlp_ln_b=(const float*)d_in[14];
  p.mlp_w1=(const float*)d_in[15]; p.mlp_b1=(const float*)d_in[16];
  p.mlp_w2=(const float*)d_in[17]; p.mlp_b2=(const float*)d_in[18];
  p.WK=(const float*)d_in[19]; p.WV=(const float*)d_in[20]; p.Wg=(const float*)d_in[21]; p.bg=(const float*)d_in[22];
  p.Wf1=(const float*)d_in[23]; p.bf1=(const float*)d_in[24]; p.Wf2=(const float*)d_in[25]; p.bf2=(const float*)d_in[26];
  p.im_ln1_g=(const float*)d_in[27]; p.im_ln1_b=(const float*)d_in[28];
  p.im_w1=(const float*)d_in[29]; p.im_b1=(const float*)d_in[30];
  p.im_w2=(const float*)d_in[31]; p.im_b2=(const float*)d_in[32];
  p.im_ln2_g=(const float*)d_in[33]; p.im_ln2_b=(const float*)d_in[34];
  p.fin_w=(const float*)d_in[35]; p.fin_b=(const float*)d_in[36];

  float* w = (float*)d_ws;
  size_t need = 0;
  auto alloc = [&](size_t nfl){ nfl = (nfl + 3) & ~(size_t)3; float* r = w + need; need += nfl; return r; };
  p.x    = alloc((size_t)NTOT*DD);
  p.A_K  = alloc((size_t)NTOT*DD);
  p.A_V  = alloc((size_t)NTOT*DD);
  p.WKf  = alloc(DD*DD);
  p.WVf  = alloc(DD*DD);
  p.Wg1  = alloc(2*DD);
  p.c1   = alloc(DD);
  p.Wf2T = alloc(DD*DD);
  p.dots_g = alloc((size_t)NB*NS*448);
  p.bar    = (int*)alloc(NB*32);
  p.xnh  = (ushort*)alloc((size_t)NTOT*DIN/2);
  p.xnl  = (ushort*)alloc((size_t)NTOT*DIN/2);
  p.hh   = (ushort*)alloc((size_t)NTOT*DIN/2);
  p.hl   = (ushort*)alloc((size_t)NTOT*DIN/2);
  p.W1Th = (ushort*)alloc((size_t)DIN*DIN/2);
  p.W1Tl = (ushort*)alloc((size_t)DIN*DIN/2);
  p.W2Th = (ushort*)alloc((size_t)DD*DIN/2);
  p.W2Tl = (ushort*)alloc((size_t)DD*DIN/2);
  p.out = (float*)d_out;
  if (ws_size < need*sizeof(float)){
    fprintf(stderr, "kernel_launch: ws too small (%zu < %zu)\n", ws_size, need*sizeof(float));
    return;
  }

  prep_weights<<<dim3(DD), dim3(128), 0, stream>>>(p);
  transpose_split<<<dim3(DIN/64, DIN/64), dim3(256), 0, stream>>>(p.im_w1, p.W1Th, p.W1Tl, DIN, DIN);
  transpose_split<<<dim3(DIN/64, DD/64), dim3(256), 0, stream>>>(p.im_w2, p.W2Th, p.W2Tl, DIN, DD);
  ln1_split<<<dim3(NTOT/4), dim3(256), 0, stream>>>(p);
  gemm_split<1><<<dim3(DIN/128, (NTOT+63)/64), dim3(256), 0, stream>>>(
      p.xnh, p.xnl, p.W1Th, p.W1Tl, p.im_b1, p.hh, p.hl,
      nullptr, nullptr, nullptr, NTOT);
  gemm_split<2><<<dim3(1, (NTOT+63)/64), dim3(256), 0, stream>>>(
      p.hh, p.hl, p.W2Th, p.W2Tl, p.im_b2, nullptr, nullptr,
      p.x, p.im_ln2_g, p.im_ln2_b, NTOT);
  k2_proj<<<dim3((NTOT+31)/32), dim3(256), 0, stream>>>(p);
  k_pers<<<dim3(NBLK), dim3(256), 0, stream>>>(p);
}

// Round 9
// 1166.343 us; speedup vs baseline: 1.2524x; 1.0179x over previous
//
#include <hip/hip_runtime.h>
#include <cstdio>

#define NB 40
#define NS 8
#define NT 441
#define DIN 768
#define DD 128
#define NTOT (NB*NT)
#define NBLK 320
#define FSCALE 0.08838834764831843f

typedef short s8v __attribute__((ext_vector_type(8)));
typedef float f4v __attribute__((ext_vector_type(4)));

__device__ inline ushort f2bf(float f){
  unsigned u = __float_as_uint(f);
  unsigned r = (u + 0x7fffu + ((u >> 16) & 1u)) >> 16;
  return (ushort)r;
}
__device__ inline float bf2f(ushort h){ return __uint_as_float(((unsigned)h) << 16); }

struct PP {
  const float *inputs; const int *tok_idx; const float *abs_grid;
  const float *slots_init, *Sp_init, *Ss_init;
  const float *WQ, *ln_g, *ln_b;
  const float *gru_w_ih, *gru_w_hh, *gru_b_ih, *gru_b_hh;
  const float *mlp_ln_g, *mlp_ln_b, *mlp_w1, *mlp_b1, *mlp_w2, *mlp_b2;
  const float *WK, *WV, *Wg, *bg, *Wf1, *bf1, *Wf2, *bf2;
  const float *im_ln1_g, *im_ln1_b, *im_w1, *im_b1, *im_w2, *im_b2, *im_ln2_g, *im_ln2_b;
  const float *fin_w, *fin_b;
  float *x, *A_K, *A_V, *WKf, *WVf, *Wg1, *c1, *Wf2T;
  float *dots_g;
  int *bar;
  ushort *xnh, *xnl, *hh, *hl, *W1Th, *W1Tl, *W2Th, *W2Tl;
  float *out;
};

// ---------- per-b barrier: release fence + relaxed polls; NO acquire invalidate.
// Cross-block data (dots_g) is exchanged via agent-scope bypass atomics, so the
// L2 never needs invalidating and cached panels/weights stay resident.
__device__ inline void gsync(int* bar, int idx, int n){
  __syncthreads();
  if (threadIdx.x == 0){
    __threadfence();                                   // flush (bypass stores already at L3)
    atomicAdd(&bar[idx], 1);
    while (__hip_atomic_load(&bar[idx], __ATOMIC_RELAXED, __HIP_MEMORY_SCOPE_AGENT) < n)
      __builtin_amdgcn_s_sleep(2);
    asm volatile("" ::: "memory");                     // compiler barrier only
  }
  __syncthreads();
}

// ---------- weight prep (also zeroes barrier counters: 40*32 ints) ----------
__global__ __launch_bounds__(128) void prep_weights(PP p){
  int r = blockIdx.x, d = threadIdx.x;
  if (r < 10) p.bar[r*128 + d] = 0;
  float accK = 0.f, accV = 0.f;
  for (int kk = 0; kk < DD; kk++){
    float w = p.Wf1[kk*DD + d];
    accK = fmaf(p.WK[r*DD+kk], w, accK);
    accV = fmaf(p.WV[r*DD+kk], w, accV);
  }
  p.WKf[r*DD+d] = accK; p.WVf[r*DD+d] = accV;
  if (r < 2){
    float a = 0.f;
    for (int kk = 0; kk < DD; kk++) a = fmaf(p.Wg[r*DD+kk], p.Wf1[kk*DD+d], a);
    p.Wg1[r*DD+d] = a;
  }
  if (r == 2){
    float a = 0.f;
    for (int kk = 0; kk < DD; kk++) a = fmaf(p.bg[kk], p.Wf1[kk*DD+d], a);
    p.c1[d] = a + p.bf1[d];
  }
  p.Wf2T[d*DD + r] = p.Wf2[r*DD + d];
}

// ---------- transpose + bf16 split ----------
__global__ __launch_bounds__(256) void transpose_split(const float* __restrict__ W,
                                                       ushort* __restrict__ WTh,
                                                       ushort* __restrict__ WTl,
                                                       int K, int N){
  __shared__ float tile[64][65];
  int tid = threadIdx.x;
  int k0 = blockIdx.x * 64, n0 = blockIdx.y * 64;
  #pragma unroll
  for (int i = 0; i < 4; i++){
    int k = i*16 + (tid >> 4);
    int n4 = (tid & 15) * 4;
    float4 v = *(const float4*)(W + (long)(k0+k)*N + n0 + n4);
    tile[k][n4+0] = v.x; tile[k][n4+1] = v.y; tile[k][n4+2] = v.z; tile[k][n4+3] = v.w;
  }
  __syncthreads();
  #pragma unroll
  for (int i = 0; i < 4; i++){
    int n = i*16 + (tid >> 4);
    int k4 = (tid & 15) * 4;
    ushort4 h4, l4;
    float v0 = tile[k4+0][n], v1 = tile[k4+1][n], v2 = tile[k4+2][n], v3 = tile[k4+3][n];
    h4.x = f2bf(v0); l4.x = f2bf(v0 - bf2f(h4.x));
    h4.y = f2bf(v1); l4.y = f2bf(v1 - bf2f(h4.y));
    h4.z = f2bf(v2); l4.z = f2bf(v2 - bf2f(h4.z));
    h4.w = f2bf(v3); l4.w = f2bf(v3 - bf2f(h4.w));
    *(ushort4*)(WTh + (long)(n0+n)*K + k0 + k4) = h4;
    *(ushort4*)(WTl + (long)(n0+n)*K + k0 + k4) = l4;
  }
}

// ---------- LN1 + bf16 hi/lo split ----------
__global__ __launch_bounds__(256) void ln1_split(PP p){
  int tok = blockIdx.x*4 + (threadIdx.x >> 6);
  int l = threadIdx.x & 63;
  const float* src = p.inputs + (long)tok*DIN;
  float4 v[3];
  float s = 0.f, s2 = 0.f;
  #pragma unroll
  for (int pp = 0; pp < 3; pp++){
    v[pp] = *(const float4*)(src + pp*256 + l*4);
    s  += v[pp].x + v[pp].y + v[pp].z + v[pp].w;
    s2 += v[pp].x*v[pp].x + v[pp].y*v[pp].y + v[pp].z*v[pp].z + v[pp].w*v[pp].w;
  }
  #pragma unroll
  for (int m = 1; m < 64; m <<= 1){ s += __shfl_xor(s, m); s2 += __shfl_xor(s2, m); }
  float mean = s*(1.f/DIN), var = s2*(1.f/DIN) - mean*mean;
  float rstd = rsqrtf(var + 1e-5f);
  #pragma unroll
  for (int pp = 0; pp < 3; pp++){
    int idx = pp*256 + l*4;
    float4 g = *(const float4*)(p.im_ln1_g + idx);
    float4 b = *(const float4*)(p.im_ln1_b + idx);
    float y0 = (v[pp].x-mean)*rstd*g.x + b.x;
    float y1 = (v[pp].y-mean)*rstd*g.y + b.y;
    float y2 = (v[pp].z-mean)*rstd*g.z + b.z;
    float y3 = (v[pp].w-mean)*rstd*g.w + b.w;
    ushort4 h4, l4;
    h4.x = f2bf(y0); l4.x = f2bf(y0 - bf2f(h4.x));
    h4.y = f2bf(y1); l4.y = f2bf(y1 - bf2f(h4.y));
    h4.z = f2bf(y2); l4.z = f2bf(y2 - bf2f(h4.z));
    h4.w = f2bf(y3); l4.w = f2bf(y3 - bf2f(h4.w));
    *(ushort4*)(p.xnh + (long)tok*DIN + idx) = h4;
    *(ushort4*)(p.xnl + (long)tok*DIN + idx) = l4;
  }
}

// ---------- split-bf16 MFMA GEMM ----------
template<int EPI>
__global__ __launch_bounds__(256) void gemm_split(
    const ushort* __restrict__ Ah, const ushort* __restrict__ Al,
    const ushort* __restrict__ Bh, const ushort* __restrict__ Bl,
    const float* __restrict__ bias,
    ushort* __restrict__ Ch, ushort* __restrict__ Cl,
    float* __restrict__ Xout, const float* __restrict__ g2, const float* __restrict__ b2,
    int M)
{
  __shared__ __align__(16) char smemc[64*132*4];
  ushort* As = (ushort*)smemc;
  ushort* Bs = (ushort*)(smemc + 10240);
  int tid = threadIdx.x;
  int n0 = blockIdx.x * 128, m0 = blockIdx.y * 64;
  int w = tid >> 6, lane = tid & 63;
  f4v acc[4][2];
  #pragma unroll
  for (int mf = 0; mf < 4; mf++)
    #pragma unroll
    for (int nf = 0; nf < 2; nf++) acc[mf][nf] = (f4v)(0.f);

  for (int kb = 0; kb < DIN; kb += 32){
    __syncthreads();
    #pragma unroll
    for (int i = 0; i < 2; i++){
      int c = tid + i*256;
      int s = c >> 8, r = (c >> 2) & 63, kg = c & 3;
      int gr = min(m0 + r, M-1);
      const float4 va = *(const float4*)((s ? Al : Ah) + (long)gr*DIN + kb + kg*8);
      *(float4*)(As + s*2560 + r*40 + kg*8) = va;
    }
    #pragma unroll
    for (int i = 0; i < 4; i++){
      int c = tid + i*256;
      int s = c >> 9, r = (c >> 2) & 127, kg = c & 3;
      const float4 vb = *(const float4*)((s ? Bl : Bh) + (long)(n0 + r)*DIN + kb + kg*8);
      *(float4*)(Bs + s*5120 + r*40 + kg*8) = vb;
    }
    __syncthreads();
    int kg = lane >> 4, rA = lane & 15;
    s8v a0[4], a1[4], b0[2], b1[2];
    #pragma unroll
    for (int mf = 0; mf < 4; mf++){
      a0[mf] = *(const s8v*)(As +        (mf*16 + rA)*40 + kg*8);
      a1[mf] = *(const s8v*)(As + 2560 + (mf*16 + rA)*40 + kg*8);
    }
    #pragma unroll
    for (int nf = 0; nf < 2; nf++){
      int rb = w*32 + nf*16 + rA;
      b0[nf] = *(const s8v*)(Bs +        rb*40 + kg*8);
      b1[nf] = *(const s8v*)(Bs + 5120 + rb*40 + kg*8);
    }
    #pragma unroll
    for (int mf = 0; mf < 4; mf++)
      #pragma unroll
      for (int nf = 0; nf < 2; nf++){
        acc[mf][nf] = __builtin_amdgcn_mfma_f32_16x16x32_bf16(a0[mf], b0[nf], acc[mf][nf], 0, 0, 0);
        acc[mf][nf] = __builtin_amdgcn_mfma_f32_16x16x32_bf16(a0[mf], b1[nf], acc[mf][nf], 0, 0, 0);
        acc[mf][nf] = __builtin_amdgcn_mfma_f32_16x16x32_bf16(a1[mf], b0[nf], acc[mf][nf], 0, 0, 0);
      }
  }

  int rbase = (lane >> 4) * 4, cn = lane & 15;
  if (EPI == 1){
    #pragma unroll
    for (int mf = 0; mf < 4; mf++)
      #pragma unroll
      for (int nf = 0; nf < 2; nf++){
        int n = n0 + w*32 + nf*16 + cn;
        float bs = bias[n];
        #pragma unroll
        for (int r = 0; r < 4; r++){
          int m = m0 + mf*16 + rbase + r;
          if (m < M){
            float v = fmaxf(acc[mf][nf][r] + bs, 0.f);
            ushort h = f2bf(v);
            Ch[(long)m*DIN + n] = h;
            Cl[(long)m*DIN + n] = f2bf(v - bf2f(h));
          }
        }
      }
  } else {
    __syncthreads();
    float* Dl = (float*)smemc;
    #pragma unroll
    for (int mf = 0; mf < 4; mf++)
      #pragma unroll
      for (int nf = 0; nf < 2; nf++){
        int n = w*32 + nf*16 + cn;
        float bs = bias[n];
        #pragma unroll
        for (int r = 0; r < 4; r++)
          Dl[(mf*16 + rbase + r)*132 + n] = acc[mf][nf][r] + bs;
      }
    __syncthreads();
    for (int rr = 0; rr < 16; rr++){
      int row = w*16 + rr;
      float e0 = Dl[row*132 + lane], e1 = Dl[row*132 + 64 + lane];
      float s = e0 + e1, s2 = e0*e0 + e1*e1;
      #pragma unroll
      for (int m2 = 1; m2 < 64; m2 <<= 1){ s += __shfl_xor(s, m2); s2 += __shfl_xor(s2, m2); }
      float mean = s*(1.f/DD), var = s2*(1.f/DD) - mean*mean;
      float rstd = rsqrtf(var + 1e-5f);
      int m = m0 + row;
      if (m < M){
        Xout[(long)m*DD + lane]      = (e0-mean)*rstd*g2[lane]      + b2[lane];
        Xout[(long)m*DD + 64 + lane] = (e1-mean)*rstd*g2[64 + lane] + b2[64 + lane];
      }
    }
  }
}

// ---------- A_K = x@WKf + c1 ; A_V = x@WVf + c1 ----------
__global__ __launch_bounds__(256) void k2_proj(PP p){
  __shared__ float xt[32][132];
  int tid = threadIdx.x; int g0 = blockIdx.x * 32;
  for (int f = tid; f < 32*32; f += 256){
    int tok = f >> 5, pos = (f & 31) * 4;
    int gt = g0 + tok;
    float4 v = (gt < NTOT) ? *(const float4*)(p.x + (long)gt*DD + pos)
                           : make_float4(0.f,0.f,0.f,0.f);
    *(float4*)&xt[tok][pos] = v;
  }
  __syncthreads();
  int d = tid & 127, grp = tid >> 7;
  float aK[16], aV[16];
  float c1v = p.c1[d];
  #pragma unroll
  for (int t = 0; t < 16; t++){ aK[t] = c1v; aV[t] = c1v; }
  for (int kk = 0; kk < DD; kk += 4){
    float k0 = p.WKf[(kk+0)*DD+d], k1 = p.WKf[(kk+1)*DD+d], k2 = p.WKf[(kk+2)*DD+d], k3 = p.WKf[(kk+3)*DD+d];
    float v0 = p.WVf[(kk+0)*DD+d], v1 = p.WVf[(kk+1)*DD+d], v2 = p.WVf[(kk+2)*DD+d], v3 = p.WVf[(kk+3)*DD+d];
    #pragma unroll
    for (int t = 0; t < 16; t++){
      float4 xv = *(const float4*)&xt[grp*16+t][kk];
      aK[t] = fmaf(xv.x,k0, fmaf(xv.y,k1, fmaf(xv.z,k2, fmaf(xv.w,k3, aK[t]))));
      aV[t] = fmaf(xv.x,v0, fmaf(xv.y,v1, fmaf(xv.z,v2, fmaf(xv.w,v3, aV[t]))));
    }
  }
  #pragma unroll
  for (int t = 0; t < 16; t++){
    int gt = g0 + grp*16 + t;
    if (gt < NTOT){ p.A_K[(long)gt*DD+d] = aK[t]; p.A_V[(long)gt*DD+d] = aV[t]; }
  }
}

// ---------- phase0 (block-local): LN(sl)->q->qW_l, sc[0]=qb, sc[1..4]=spss from spst ----------
__device__ void phase0(const PP& p, int tid, float* scr, const float* sl, const float* spst,
                       float* qw_l, float* sc){
  float* sn   = scr;        // 128
  float* qv   = scr + 128;  // 128
  float* part = scr + 256;  // 256
  float* red  = scr + 512;  // 8
  int o = tid & 127, h = tid >> 7;
  float v = (tid < 128) ? sl[tid] : 0.f;
  float s1 = v, s2 = v*v;
  #pragma unroll
  for (int m = 1; m < 64; m <<= 1){ s1 += __shfl_xor(s1,m); s2 += __shfl_xor(s2,m); }
  if (tid < 128 && (tid & 63) == 0){ red[(tid>>6)*2] = s1; red[(tid>>6)*2+1] = s2; }
  __syncthreads();
  float mean = (red[0]+red[2])*(1.f/128.f);
  float var  = (red[1]+red[3])*(1.f/128.f) - mean*mean;
  float rstd = rsqrtf(var + 1e-5f);
  if (tid < 128) sn[tid] = (v-mean)*rstd*p.ln_g[tid] + p.ln_b[tid];
  __syncthreads();
  float acc = 0.f;
  for (int k = 0; k < 64; k++) acc = fmaf(sn[h*64+k], p.WQ[(h*64+k)*128+o], acc);
  part[h*128+o] = acc;
  __syncthreads();
  if (tid < 128) qv[tid] = part[tid] + part[128+tid];
  __syncthreads();
  float acc2 = 0.f;
  for (int k = 0; k < 64; k++) acc2 = fmaf(qv[h*64+k], p.Wf2T[(h*64+k)*128+o], acc2);
  part[h*128+o] = acc2;
  __syncthreads();
  if (tid < 128) qw_l[tid] = part[tid] + part[128+tid];
  float pb = (tid < 128) ? qv[tid]*p.bf2[tid] : 0.f;
  #pragma unroll
  for (int m = 1; m < 64; m <<= 1) pb += __shfl_xor(pb,m);
  if ((tid & 63) == 0) red[4 + (tid>>6)] = pb;
  __syncthreads();
  if (tid == 0){
    sc[0] = FSCALE*(red[4]+red[5]+red[6]+red[7]);
    sc[1] = spst[0]; sc[2] = spst[1];
    sc[3] = 1.f/(spst[2]*5.0f); sc[4] = 1.f/(spst[3]*5.0f);
  }
  __syncthreads();
}

// ---------- persistent per-(b,s) kernel: 320 blocks, XCD-swizzled, per-b barriers ----------
__global__ __launch_bounds__(256, 2) void k_pers(PP p){
  __shared__ float smem[5248];
  const int tid = threadIdx.x;
  // XCD swizzle: assume consecutive blockIdx round-robin across 8 XCDs.
  // Put all 8 slots of a b on ONE XCD; 5 b's per XCD -> ~3.4 MB L2-resident working set.
  const int xcd = blockIdx.x & 7, slot = blockIdx.x >> 3;
  const int bb = xcd*5 + (slot >> 3), ss = slot & 7;
  const int bs = bb*8 + ss;
  float* agx  = smem;          // 448
  float* agy  = smem + 448;    // 448
  float* sl   = smem + 896;    // 128 persistent slots
  float* spst = smem + 1024;   // 4 (+4 pad) persistent Sp/Ss
  float* qw_l = smem + 1032;   // 128
  float* sc   = smem + 1160;   // 8: sc[0]=qb, sc[1..4]=spss
  float* scr  = smem + 1168;   // scratch (phase-dependent)

  // ---- init (fully block-local) ----
  for (int f = tid; f < 448; f += 256){
    float g0 = 0.f, g1 = 0.f;
    if (f < NT){ int idx = p.tok_idx[bb*NT+f]; g0 = p.abs_grid[idx*2]; g1 = p.abs_grid[idx*2+1]; }
    agx[f] = g0; agy[f] = g1;
  }
  if (tid < 128) sl[tid] = p.slots_init[ss*128+tid];
  if (tid < 4)   spst[tid] = (tid < 2) ? p.Sp_init[ss*2+tid] : p.Ss_init[ss*2+(tid-2)];
  __syncthreads();
  phase0(p, tid, scr, sl, spst, qw_l, sc);

  int* bbar = p.bar + bb*32;

  for (int t = 0; t < 4; t++){
    // ===== P1: own-slot dots over all 441 tokens (A_K reads L2-cached; dots bypass-stored) =====
    {
      int dg = tid & 7, jl = tid >> 3;
      float w0[16], w1[16], qw[16];
      #pragma unroll
      for (int i = 0; i < 16; i++){
        w0[i] = p.Wg1[dg*16+i];
        w1[i] = p.Wg1[128 + dg*16+i];
        qw[i] = qw_l[dg*16+i];
      }
      float sp0 = sc[1], sp1 = sc[2], si0 = sc[3], si1 = sc[4], qb = sc[0];
      float* drow = p.dots_g + (long)bs*448;
      for (int pass = 0; pass < 14; pass++){
        int j = pass*32 + jl;
        bool valid = j < NT;
        int jc = valid ? j : 0;
        float rel0 = (agx[jc]-sp0)*si0, rel1 = (agy[jc]-sp1)*si1;
        const float4* src = (const float4*)(p.A_K + ((long)(bb*NT+jc))*DD + dg*16);
        float acc = 0.f;
        #pragma unroll
        for (int i4 = 0; i4 < 4; i4++){
          float4 a4 = src[i4];
          float hk;
          hk = fmaxf(fmaf(rel0, w0[i4*4+0], fmaf(rel1, w1[i4*4+0], a4.x)), 0.f); acc = fmaf(hk, qw[i4*4+0], acc);
          hk = fmaxf(fmaf(rel0, w0[i4*4+1], fmaf(rel1, w1[i4*4+1], a4.y)), 0.f); acc = fmaf(hk, qw[i4*4+1], acc);
          hk = fmaxf(fmaf(rel0, w0[i4*4+2], fmaf(rel1, w1[i4*4+2], a4.z)), 0.f); acc = fmaf(hk, qw[i4*4+2], acc);
          hk = fmaxf(fmaf(rel0, w0[i4*4+3], fmaf(rel1, w1[i4*4+3], a4.w)), 0.f); acc = fmaf(hk, qw[i4*4+3], acc);
        }
        acc += __shfl_xor(acc, 1); acc += __shfl_xor(acc, 2); acc += __shfl_xor(acc, 4);
        if (dg == 0 && valid)
          __hip_atomic_store(&drow[j], acc*FSCALE + qb, __ATOMIC_RELAXED, __HIP_MEMORY_SCOPE_AGENT);
      }
    }
    gsync(bbar, 2*t, 8);

    // ===== P234: softmax-over-s (redundant per block), Sp/Ss, hbar, GRU, MLP =====
    {
      float* d_l = scr;            // 8*449 = 3592
      float* a_l = scr + 3592;     // 448
      float* red = scr + 4040;     // 16
      float* bc  = scr + 4056;     // 4
      const float* dsrc = p.dots_g + (long)bb*8*448;
      for (int f = tid; f < 8*448; f += 256){
        int s = f / 448, j = f - s*448;
        d_l[s*449 + j] = __hip_atomic_load(&dsrc[f], __ATOMIC_RELAXED, __HIP_MEMORY_SCOPE_AGENT);
      }
      __syncthreads();
      float rsum = 0.f, sx = 0.f, sy = 0.f;
      for (int j = tid; j < 448; j += 256){
        float a = 0.f;
        if (j < NT){
          float m = -1e30f;
          #pragma unroll
          for (int s = 0; s < 8; s++) m = fmaxf(m, d_l[s*449+j]);
          float tot = 0.f;
          #pragma unroll
          for (int s = 0; s < 8; s++) tot += expf(d_l[s*449+j] - m);
          a = expf(d_l[ss*449+j] - m)/tot + 1e-8f;
        }
        a_l[j] = a;
        rsum += a; sx = fmaf(a, agx[j], sx); sy = fmaf(a, agy[j], sy);
      }
      int wid = tid >> 6, lane = tid & 63;
      #pragma unroll
      for (int m = 1; m < 64; m <<= 1){
        rsum += __shfl_xor(rsum,m); sx += __shfl_xor(sx,m); sy += __shfl_xor(sy,m);
      }
      if (lane == 0){ red[wid] = rsum; red[4+wid] = sx; red[8+wid] = sy; }
      __syncthreads();
      if (tid == 0){
        float SA = red[0]+red[1]+red[2]+red[3];
        float SX = red[4]+red[5]+red[6]+red[7];
        float SY = red[8]+red[9]+red[10]+red[11];
        bc[0] = SX/SA; bc[1] = SY/SA; bc[2] = 1.f/SA;
      }
      __syncthreads();

      if (t == 3){
        if ((bb % 5) == 2){
          float inv = bc[2];
          long base = (long)NB*NS*DD + (long)(bb/5)*(NS*NT) + (long)ss*NT;
          for (int j = tid; j < NT; j += 256) p.out[base+j] = a_l[j]*inv;
        }
      } else {
        float Sp0 = bc[0], Sp1 = bc[1];
        float q0 = 0.f, q1 = 0.f;
        for (int j = tid; j < 448; j += 256){
          float a = a_l[j];
          float e0 = agx[j]-Sp0, e1 = agy[j]-Sp1;
          q0 = fmaf(a, e0*e0, q0); q1 = fmaf(a, e1*e1, q1);
        }
        #pragma unroll
        for (int m = 1; m < 64; m <<= 1){ q0 += __shfl_xor(q0,m); q1 += __shfl_xor(q1,m); }
        if (lane == 0){ red[wid] = q0; red[4+wid] = q1; }
        __syncthreads();
        if (tid == 0){
          float Q0 = red[0]+red[1]+red[2]+red[3];
          float Q1 = red[4]+red[5]+red[6]+red[7];
          spst[0] = Sp0; spst[1] = Sp1;
          spst[2] = sqrtf(Q0*bc[2]); spst[3] = sqrtf(Q1*bc[2]);
        }
        __syncthreads();
        // ---- hbar with OLD spss (sc); A_V reads L2-cached ----
        int d = tid & 127, jp = tid >> 7;
        float sp0o = sc[1], sp1o = sc[2], si0o = sc[3], si1o = sc[4];
        float wgd0 = p.Wg1[d], wgd1 = p.Wg1[DD+d];
        float acc = 0.f;
        for (int j = jp; j < NT; j += 2){
          float av = p.A_V[((long)(bb*NT+j))*DD + d];
          float r0 = (agx[j]-sp0o)*si0o, r1 = (agy[j]-sp1o)*si1o;
          float hv = fmaxf(fmaf(r0, wgd0, fmaf(r1, wgd1, av)), 0.f);
          acc = fmaf(a_l[j], hv, acc);
        }
        float* hpart = scr;          // 256 (d_l region, dead now)
        float* hb    = scr + 256;    // 128
        hpart[jp*128+d] = acc;
        __syncthreads();
        if (tid < 128) hb[tid] = (hpart[tid] + hpart[128+tid]) * bc[2];
        __syncthreads();
        // ---- upd = hb@Wf2 + bf2 ----
        float* part = scr + 384;     // 256
        int o = tid & 127, h = tid >> 7;
        float acc2 = 0.f;
        for (int k = 0; k < 64; k++) acc2 = fmaf(hb[h*64+k], p.Wf2[(h*64+k)*128+o], acc2);
        part[h*128+o] = acc2;
        __syncthreads();
        float* upd = scr + 640;      // 128
        if (tid < 128) upd[tid] = part[tid] + part[128+tid] + p.bf2[tid];
        __syncthreads();
        // ---- GRU ----
        float* gil = scr + 768;      // 384
        float* ghl = scr + 1152;     // 384
        int oA = tid, oB = tid + 256;
        float giA = p.gru_b_ih[oA], ghA = p.gru_b_hh[oA];
        float giB = 0.f, ghB = 0.f;
        if (tid < 128){ giB = p.gru_b_ih[oB]; ghB = p.gru_b_hh[oB]; }
        for (int k = 0; k < 128; k++){
          float uk = upd[k], sk = sl[k];
          giA = fmaf(uk, p.gru_w_ih[k*384+oA], giA);
          ghA = fmaf(sk, p.gru_w_hh[k*384+oA], ghA);
          if (tid < 128){
            giB = fmaf(uk, p.gru_w_ih[k*384+oB], giB);
            ghB = fmaf(sk, p.gru_w_hh[k*384+oB], ghB);
          }
        }
        gil[oA] = giA; ghl[oA] = ghA;
        if (tid < 128){ gil[oB] = giB; ghl[oB] = ghB; }
        __syncthreads();
        float* hnl = scr + 1536;     // 128
        float* yv  = scr + 1664;     // 128
        float hnv = 0.f;
        if (tid < 128){
          float r = 1.f/(1.f+expf(-(gil[tid]+ghl[tid])));
          float z = 1.f/(1.f+expf(-(gil[128+tid]+ghl[128+tid])));
          float n = tanhf(gil[256+tid] + r*ghl[256+tid]);
          hnv = (1.f-z)*n + z*sl[tid];
        }
        float t1 = hnv, t2 = hnv*hnv;
        #pragma unroll
        for (int m = 1; m < 64; m <<= 1){ t1 += __shfl_xor(t1,m); t2 += __shfl_xor(t2,m); }
        if (tid < 128 && (tid & 63) == 0){ red[(tid>>6)*2] = t1; red[(tid>>6)*2+1] = t2; }
        __syncthreads();
        float mean = (red[0]+red[2])*(1.f/128.f);
        float var  = (red[1]+red[3])*(1.f/128.f) - mean*mean;
        float rstd = rsqrtf(var + 1e-5f);
        if (tid < 128){
          hnl[tid] = hnv;
          yv[tid] = (hnv-mean)*rstd*p.mlp_ln_g[tid] + p.mlp_ln_b[tid];
        }
        __syncthreads();
        float* h1 = scr + 1792;      // 512
        float m1A = p.mlp_b1[tid], m1B = p.mlp_b1[tid+256];
        for (int k = 0; k < 128; k++){
          float y = yv[k];
          m1A = fmaf(y, p.mlp_w1[k*512+tid], m1A);
          m1B = fmaf(y, p.mlp_w1[k*512+tid+256], m1B);
        }
        h1[tid] = fmaxf(m1A, 0.f); h1[tid+256] = fmaxf(m1B, 0.f);
        __syncthreads();
        float a2 = 0.f;
        for (int kk = 0; kk < 256; kk++) a2 = fmaf(h1[h*256+kk], p.mlp_w2[(h*256+kk)*128+o], a2);
        part[h*128+o] = a2;
        __syncthreads();
        if (tid < 128) sl[tid] = hnl[tid] + p.mlp_b2[tid] + part[tid] + part[128+tid];
        __syncthreads();
        phase0(p, tid, scr, sl, spst, qw_l, sc);
      }
    }
    if (t < 3) gsync(bbar, 2*t+1, 8);
  }

  // ===== P5: final slot projection =====
  {
    float* part = scr;
    int o = tid & 127, h = tid >> 7;
    float acc = 0.f;
    for (int k = 0; k < 64; k++) acc = fmaf(sl[h*64+k], p.fin_w[(h*64+k)*128+o], acc);
    part[h*128+o] = acc;
    __syncthreads();
    if (tid < 128) p.out[(long)bs*128+tid] = p.fin_b[tid] + part[tid] + part[128+tid];
  }
}

extern "C" void kernel_launch(void* const* d_in, const int* in_sizes, int n_in,
                              void* d_out, int out_size, void* d_ws, size_t ws_size,
                              hipStream_t stream){
  PP p;
  p.inputs=(const float*)d_in[0]; p.tok_idx=(const int*)d_in[1]; p.abs_grid=(const float*)d_in[2];
  p.slots_init=(const float*)d_in[3]; p.Sp_init=(const float*)d_in[4]; p.Ss_init=(const float*)d_in[5];
  p.WQ=(const float*)d_in[6]; p.ln_g=(const float*)d_in[7]; p.ln_b=(const float*)d_in[8];
  p.gru_w_ih=(const float*)d_in[9]; p.gru_w_hh=(const float*)d_in[10];
  p.gru_b_ih=(const float*)d_in[11]; p.gru_b_hh=(const float*)d_in[12];
  p.mlp_ln_g=(const float*)d_in[13]; p.mlp_ln_b=(const float*)d_in[14];
  p.mlp_w1=(const float*)d_in[15]; p.mlp_b1=(const float*)d_in[16];
  p.mlp_w2=(const float*)d_in[17]; p.mlp_b2=(const float*)d_in[18];
  p.WK=(const float*)d_in[19]; p.WV=(const float*)d_in[20]; p.Wg=(const float*)d_in[21]; p.bg=(const float*)d_in[22];
  p.Wf1=(const float*)d_in[23]; p.bf1=(const float*)d_in[24]; p.Wf2=(const float*)d_in[25]; p.bf2=(const float*)d_in[26];
  p.im_ln1_g=(const float*)d_in[27]; p.im_ln1_b=(const float*)d_in[28];
  p.im_w1=(const float*)d_in[29]; p.im_b1=(const float*)d_in[30];
  p.im_w2=(const float*)d_in[31]; p.im_b2=(const float*)d_in[32];
  p.im_ln2_g=(const float*)d_in[33]; p.im_ln2_b=(const float*)d_in[34];
  p.fin_w=(const float*)d_in[35]; p.fin_b=(const float*)d_in[36];

  float* w = (float*)d_ws;
  size_t need = 0;
  auto alloc = [&](size_t nfl){ nfl = (nfl + 3) & ~(size_t)3; float* r = w + need; need += nfl; return r; };
  p.x    = alloc((size_t)NTOT*DD);
  p.A_K  = alloc((size_t)NTOT*DD);
  p.A_V  = alloc((size_t)NTOT*DD);
  p.WKf  = alloc(DD*DD);
  p.WVf  = alloc(DD*DD);
  p.Wg1  = alloc(2*DD);
  p.c1   = alloc(DD);
  p.Wf2T = alloc(DD*DD);
  p.dots_g = alloc((size_t)NB*NS*448);
  p.bar    = (int*)alloc(NB*32);
  p.xnh  = (ushort*)alloc((size_t)NTOT*DIN/2);
  p.xnl  = (ushort*)alloc((size_t)NTOT*DIN/2);
  p.hh   = (ushort*)alloc((size_t)NTOT*DIN/2);
  p.hl   = (ushort*)alloc((size_t)NTOT*DIN/2);
  p.W1Th = (ushort*)alloc((size_t)DIN*DIN/2);
  p.W1Tl = (ushort*)alloc((size_t)DIN*DIN/2);
  p.W2Th = (ushort*)alloc((size_t)DD*DIN/2);
  p.W2Tl = (ushort*)alloc((size_t)DD*DIN/2);
  p.out = (float*)d_out;
  if (ws_size < need*sizeof(float)){
    fprintf(stderr, "kernel_launch: ws too small (%zu < %zu)\n", ws_size, need*sizeof(float));
    return;
  }

  prep_weights<<<dim3(DD), dim3(128), 0, stream>>>(p);
  transpose_split<<<dim3(DIN/64, DIN/64), dim3(256), 0, stream>>>(p.im_w1, p.W1Th, p.W1Tl, DIN, DIN);
  transpose_split<<<dim3(DIN/64, DD/64), dim3(256), 0, stream>>>(p.im_w2, p.W2Th, p.W2Tl, DIN, DD);
  ln1_split<<<dim3(NTOT/4), dim3(256), 0, stream>>>(p);
  gemm_split<1><<<dim3(DIN/128, (NTOT+63)/64), dim3(256), 0, stream>>>(
      p.xnh, p.xnl, p.W1Th, p.W1Tl, p.im_b1, p.hh, p.hl,
      nullptr, nullptr, nullptr, NTOT);
  gemm_split<2><<<dim3(1, (NTOT+63)/64), dim3(256), 0, stream>>>(
      p.hh, p.hl, p.W2Th, p.W2Tl, p.im_b2, nullptr, nullptr,
      p.x, p.im_ln2_g, p.im_ln2_b, NTOT);
  k2_proj<<<dim3((NTOT+31)/32), dim3(256), 0, stream>>>(p);
  k_pers<<<dim3(NBLK), dim3(256), 0, stream>>>(p);
}

// Round 10
// 473.432 us; speedup vs baseline: 3.0855x; 2.4636x over previous
//
#include <hip/hip_runtime.h>
#include <cstdio>

#define NB 40
#define NS 8
#define NT 441
#define DIN 768
#define DD 128
#define NTOT (NB*NT)
#define FSCALE 0.08838834764831843f

typedef short s8v __attribute__((ext_vector_type(8)));
typedef float f4v __attribute__((ext_vector_type(4)));

__device__ inline ushort f2bf(float f){
  unsigned u = __float_as_uint(f);
  unsigned r = (u + 0x7fffu + ((u >> 16) & 1u)) >> 16;
  return (ushort)r;
}
__device__ inline float bf2f(ushort h){ return __uint_as_float(((unsigned)h) << 16); }

struct PP {
  const float *inputs; const int *tok_idx; const float *abs_grid;
  const float *slots_init, *Sp_init, *Ss_init;
  const float *WQ, *ln_g, *ln_b;
  const float *gru_w_ih, *gru_w_hh, *gru_b_ih, *gru_b_hh;
  const float *mlp_ln_g, *mlp_ln_b, *mlp_w1, *mlp_b1, *mlp_w2, *mlp_b2;
  const float *WK, *WV, *Wg, *bg, *Wf1, *bf1, *Wf2, *bf2;
  const float *im_ln1_g, *im_ln1_b, *im_w1, *im_b1, *im_w2, *im_b2, *im_ln2_g, *im_ln2_b;
  const float *fin_w, *fin_b;
  float *x, *A_K, *A_V, *WKf, *WVf, *Wg1, *c1, *Wf2T;
  float *slots_g, *qw_g, *qb_g, *spss_g, *hpart_g, *a_g;
  ushort *xnh, *xnl, *hh, *hl, *W1Th, *W1Tl, *W2Th, *W2Tl;
  float *out;
};

// ---------- weight prep ----------
__global__ __launch_bounds__(128) void prep_weights(PP p){
  int r = blockIdx.x, d = threadIdx.x;
  float accK = 0.f, accV = 0.f;
  for (int kk = 0; kk < DD; kk++){
    float w = p.Wf1[kk*DD + d];
    accK = fmaf(p.WK[r*DD+kk], w, accK);
    accV = fmaf(p.WV[r*DD+kk], w, accV);
  }
  p.WKf[r*DD+d] = accK; p.WVf[r*DD+d] = accV;
  if (r < 2){
    float a = 0.f;
    for (int kk = 0; kk < DD; kk++) a = fmaf(p.Wg[r*DD+kk], p.Wf1[kk*DD+d], a);
    p.Wg1[r*DD+d] = a;
  }
  if (r == 2){
    float a = 0.f;
    for (int kk = 0; kk < DD; kk++) a = fmaf(p.bg[kk], p.Wf1[kk*DD+d], a);
    p.c1[d] = a + p.bf1[d];
  }
  p.Wf2T[d*DD + r] = p.Wf2[r*DD + d];
}

// ---------- transpose + bf16 split ----------
__global__ __launch_bounds__(256) void transpose_split(const float* __restrict__ W,
                                                       ushort* __restrict__ WTh,
                                                       ushort* __restrict__ WTl,
                                                       int K, int N){
  __shared__ float tile[64][65];
  int tid = threadIdx.x;
  int k0 = blockIdx.x * 64, n0 = blockIdx.y * 64;
  #pragma unroll
  for (int i = 0; i < 4; i++){
    int k = i*16 + (tid >> 4);
    int n4 = (tid & 15) * 4;
    float4 v = *(const float4*)(W + (long)(k0+k)*N + n0 + n4);
    tile[k][n4+0] = v.x; tile[k][n4+1] = v.y; tile[k][n4+2] = v.z; tile[k][n4+3] = v.w;
  }
  __syncthreads();
  #pragma unroll
  for (int i = 0; i < 4; i++){
    int n = i*16 + (tid >> 4);
    int k4 = (tid & 15) * 4;
    ushort4 h4, l4;
    float v0 = tile[k4+0][n], v1 = tile[k4+1][n], v2 = tile[k4+2][n], v3 = tile[k4+3][n];
    h4.x = f2bf(v0); l4.x = f2bf(v0 - bf2f(h4.x));
    h4.y = f2bf(v1); l4.y = f2bf(v1 - bf2f(h4.y));
    h4.z = f2bf(v2); l4.z = f2bf(v2 - bf2f(h4.z));
    h4.w = f2bf(v3); l4.w = f2bf(v3 - bf2f(h4.w));
    *(ushort4*)(WTh + (long)(n0+n)*K + k0 + k4) = h4;
    *(ushort4*)(WTl + (long)(n0+n)*K + k0 + k4) = l4;
  }
}

// ---------- LN1 + bf16 hi/lo split ----------
__global__ __launch_bounds__(256) void ln1_split(PP p){
  int tok = blockIdx.x*4 + (threadIdx.x >> 6);
  int l = threadIdx.x & 63;
  const float* src = p.inputs + (long)tok*DIN;
  float4 v[3];
  float s = 0.f, s2 = 0.f;
  #pragma unroll
  for (int pp = 0; pp < 3; pp++){
    v[pp] = *(const float4*)(src + pp*256 + l*4);
    s  += v[pp].x + v[pp].y + v[pp].z + v[pp].w;
    s2 += v[pp].x*v[pp].x + v[pp].y*v[pp].y + v[pp].z*v[pp].z + v[pp].w*v[pp].w;
  }
  #pragma unroll
  for (int m = 1; m < 64; m <<= 1){ s += __shfl_xor(s, m); s2 += __shfl_xor(s2, m); }
  float mean = s*(1.f/DIN), var = s2*(1.f/DIN) - mean*mean;
  float rstd = rsqrtf(var + 1e-5f);
  #pragma unroll
  for (int pp = 0; pp < 3; pp++){
    int idx = pp*256 + l*4;
    float4 g = *(const float4*)(p.im_ln1_g + idx);
    float4 b = *(const float4*)(p.im_ln1_b + idx);
    float y0 = (v[pp].x-mean)*rstd*g.x + b.x;
    float y1 = (v[pp].y-mean)*rstd*g.y + b.y;
    float y2 = (v[pp].z-mean)*rstd*g.z + b.z;
    float y3 = (v[pp].w-mean)*rstd*g.w + b.w;
    ushort4 h4, l4;
    h4.x = f2bf(y0); l4.x = f2bf(y0 - bf2f(h4.x));
    h4.y = f2bf(y1); l4.y = f2bf(y1 - bf2f(h4.y));
    h4.z = f2bf(y2); l4.z = f2bf(y2 - bf2f(h4.z));
    h4.w = f2bf(y3); l4.w = f2bf(y3 - bf2f(h4.w));
    *(ushort4*)(p.xnh + (long)tok*DIN + idx) = h4;
    *(ushort4*)(p.xnl + (long)tok*DIN + idx) = l4;
  }
}

// ---------- split-bf16 MFMA GEMM ----------
template<int EPI>
__global__ __launch_bounds__(256) void gemm_split(
    const ushort* __restrict__ Ah, const ushort* __restrict__ Al,
    const ushort* __restrict__ Bh, const ushort* __restrict__ Bl,
    const float* __restrict__ bias,
    ushort* __restrict__ Ch, ushort* __restrict__ Cl,
    float* __restrict__ Xout, const float* __restrict__ g2, const float* __restrict__ b2,
    int M)
{
  __shared__ __align__(16) char smemc[64*132*4];
  ushort* As = (ushort*)smemc;
  ushort* Bs = (ushort*)(smemc + 10240);
  int tid = threadIdx.x;
  int n0 = blockIdx.x * 128, m0 = blockIdx.y * 64;
  int w = tid >> 6, lane = tid & 63;
  f4v acc[4][2];
  #pragma unroll
  for (int mf = 0; mf < 4; mf++)
    #pragma unroll
    for (int nf = 0; nf < 2; nf++) acc[mf][nf] = (f4v)(0.f);

  for (int kb = 0; kb < DIN; kb += 32){
    __syncthreads();
    #pragma unroll
    for (int i = 0; i < 2; i++){
      int c = tid + i*256;
      int s = c >> 8, r = (c >> 2) & 63, kg = c & 3;
      int gr = min(m0 + r, M-1);
      const float4 va = *(const float4*)((s ? Al : Ah) + (long)gr*DIN + kb + kg*8);
      *(float4*)(As + s*2560 + r*40 + kg*8) = va;
    }
    #pragma unroll
    for (int i = 0; i < 4; i++){
      int c = tid + i*256;
      int s = c >> 9, r = (c >> 2) & 127, kg = c & 3;
      const float4 vb = *(const float4*)((s ? Bl : Bh) + (long)(n0 + r)*DIN + kb + kg*8);
      *(float4*)(Bs + s*5120 + r*40 + kg*8) = vb;
    }
    __syncthreads();
    int kg = lane >> 4, rA = lane & 15;
    s8v a0[4], a1[4], b0[2], b1[2];
    #pragma unroll
    for (int mf = 0; mf < 4; mf++){
      a0[mf] = *(const s8v*)(As +        (mf*16 + rA)*40 + kg*8);
      a1[mf] = *(const s8v*)(As + 2560 + (mf*16 + rA)*40 + kg*8);
    }
    #pragma unroll
    for (int nf = 0; nf < 2; nf++){
      int rb = w*32 + nf*16 + rA;
      b0[nf] = *(const s8v*)(Bs +        rb*40 + kg*8);
      b1[nf] = *(const s8v*)(Bs + 5120 + rb*40 + kg*8);
    }
    #pragma unroll
    for (int mf = 0; mf < 4; mf++)
      #pragma unroll
      for (int nf = 0; nf < 2; nf++){
        acc[mf][nf] = __builtin_amdgcn_mfma_f32_16x16x32_bf16(a0[mf], b0[nf], acc[mf][nf], 0, 0, 0);
        acc[mf][nf] = __builtin_amdgcn_mfma_f32_16x16x32_bf16(a0[mf], b1[nf], acc[mf][nf], 0, 0, 0);
        acc[mf][nf] = __builtin_amdgcn_mfma_f32_16x16x32_bf16(a1[mf], b0[nf], acc[mf][nf], 0, 0, 0);
      }
  }

  int rbase = (lane >> 4) * 4, cn = lane & 15;
  if (EPI == 1){
    #pragma unroll
    for (int mf = 0; mf < 4; mf++)
      #pragma unroll
      for (int nf = 0; nf < 2; nf++){
        int n = n0 + w*32 + nf*16 + cn;
        float bs = bias[n];
        #pragma unroll
        for (int r = 0; r < 4; r++){
          int m = m0 + mf*16 + rbase + r;
          if (m < M){
            float v = fmaxf(acc[mf][nf][r] + bs, 0.f);
            ushort h = f2bf(v);
            Ch[(long)m*DIN + n] = h;
            Cl[(long)m*DIN + n] = f2bf(v - bf2f(h));
          }
        }
      }
  } else {
    __syncthreads();
    float* Dl = (float*)smemc;
    #pragma unroll
    for (int mf = 0; mf < 4; mf++)
      #pragma unroll
      for (int nf = 0; nf < 2; nf++){
        int n = w*32 + nf*16 + cn;
        float bs = bias[n];
        #pragma unroll
        for (int r = 0; r < 4; r++)
          Dl[(mf*16 + rbase + r)*132 + n] = acc[mf][nf][r] + bs;
      }
    __syncthreads();
    for (int rr = 0; rr < 16; rr++){
      int row = w*16 + rr;
      float e0 = Dl[row*132 + lane], e1 = Dl[row*132 + 64 + lane];
      float s = e0 + e1, s2 = e0*e0 + e1*e1;
      #pragma unroll
      for (int m2 = 1; m2 < 64; m2 <<= 1){ s += __shfl_xor(s, m2); s2 += __shfl_xor(s2, m2); }
      float mean = s*(1.f/DD), var = s2*(1.f/DD) - mean*mean;
      float rstd = rsqrtf(var + 1e-5f);
      int m = m0 + row;
      if (m < M){
        Xout[(long)m*DD + lane]      = (e0-mean)*rstd*g2[lane]      + b2[lane];
        Xout[(long)m*DD + 64 + lane] = (e1-mean)*rstd*g2[64 + lane] + b2[64 + lane];
      }
    }
  }
}

// ---------- A_K = x@WKf + c1 ; A_V = x@WVf + c1 ----------
__global__ __launch_bounds__(256) void k2_proj(PP p){
  __shared__ float xt[32][132];
  int tid = threadIdx.x; int g0 = blockIdx.x * 32;
  for (int f = tid; f < 32*32; f += 256){
    int tok = f >> 5, pos = (f & 31) * 4;
    int gt = g0 + tok;
    float4 v = (gt < NTOT) ? *(const float4*)(p.x + (long)gt*DD + pos)
                           : make_float4(0.f,0.f,0.f,0.f);
    *(float4*)&xt[tok][pos] = v;
  }
  __syncthreads();
  int d = tid & 127, grp = tid >> 7;
  float aK[16], aV[16];
  float c1v = p.c1[d];
  #pragma unroll
  for (int t = 0; t < 16; t++){ aK[t] = c1v; aV[t] = c1v; }
  for (int kk = 0; kk < DD; kk += 4){
    float k0 = p.WKf[(kk+0)*DD+d], k1 = p.WKf[(kk+1)*DD+d], k2 = p.WKf[(kk+2)*DD+d], k3 = p.WKf[(kk+3)*DD+d];
    float v0 = p.WVf[(kk+0)*DD+d], v1 = p.WVf[(kk+1)*DD+d], v2 = p.WVf[(kk+2)*DD+d], v3 = p.WVf[(kk+3)*DD+d];
    #pragma unroll
    for (int t = 0; t < 16; t++){
      float4 xv = *(const float4*)&xt[grp*16+t][kk];
      aK[t] = fmaf(xv.x,k0, fmaf(xv.y,k1, fmaf(xv.z,k2, fmaf(xv.w,k3, aK[t]))));
      aV[t] = fmaf(xv.x,v0, fmaf(xv.y,v1, fmaf(xv.z,v2, fmaf(xv.w,v3, aV[t]))));
    }
  }
  #pragma unroll
  for (int t = 0; t < 16; t++){
    int gt = g0 + grp*16 + t;
    if (gt < NTOT){ p.A_K[(long)gt*DD+d] = aK[t]; p.A_V[(long)gt*DD+d] = aV[t]; }
  }
}

// ---------- phase0: LN(sl)->q; publish qw_g/qb_g/spss_g for (b,s)=bs ----------
// scr >= 520 floats; sl outside scr; Sp/Ss are uniform scalars
__device__ void phase0g(const PP& p, int bs, int tid, float* scr, const float* sl,
                        float Sp0, float Sp1, float Ss0, float Ss1){
  float* sn   = scr;        // 128
  float* qv   = scr + 128;  // 128
  float* part = scr + 256;  // 256
  float* red  = scr + 512;  // 8
  int o = tid & 127, h = tid >> 7;
  float v = (tid < 128) ? sl[tid] : 0.f;
  float s1 = v, s2 = v*v;
  #pragma unroll
  for (int m = 1; m < 64; m <<= 1){ s1 += __shfl_xor(s1,m); s2 += __shfl_xor(s2,m); }
  if (tid < 128 && (tid & 63) == 0){ red[(tid>>6)*2] = s1; red[(tid>>6)*2+1] = s2; }
  __syncthreads();
  float mean = (red[0]+red[2])*(1.f/128.f);
  float var  = (red[1]+red[3])*(1.f/128.f) - mean*mean;
  float rstd = rsqrtf(var + 1e-5f);
  if (tid < 128) sn[tid] = (v-mean)*rstd*p.ln_g[tid] + p.ln_b[tid];
  __syncthreads();
  float acc = 0.f;
  for (int k = 0; k < 64; k++) acc = fmaf(sn[h*64+k], p.WQ[(h*64+k)*128+o], acc);
  part[h*128+o] = acc;
  __syncthreads();
  if (tid < 128) qv[tid] = part[tid] + part[128+tid];
  __syncthreads();
  float acc2 = 0.f;
  for (int k = 0; k < 64; k++) acc2 = fmaf(qv[h*64+k], p.Wf2T[(h*64+k)*128+o], acc2);
  part[h*128+o] = acc2;
  __syncthreads();
  if (tid < 128) p.qw_g[(long)bs*128+tid] = part[tid] + part[128+tid];
  float pb = (tid < 128) ? qv[tid]*p.bf2[tid] : 0.f;
  #pragma unroll
  for (int m = 1; m < 64; m <<= 1) pb += __shfl_xor(pb,m);
  if ((tid & 63) == 0) red[4 + (tid>>6)] = pb;
  __syncthreads();
  if (tid == 0){
    p.qb_g[bs] = FSCALE*(red[4]+red[5]+red[6]+red[7]);
    p.spss_g[bs*4+0] = Sp0; p.spss_g[bs*4+1] = Sp1;
    p.spss_g[bs*4+2] = 1.f/(Ss0*5.0f); p.spss_g[bs*4+3] = 1.f/(Ss1*5.0f);
  }
}

// ---------- init: slots_g + first phase0 ----------
__global__ __launch_bounds__(256) void k_init(PP p){
  __shared__ float sl[128];
  __shared__ float scr[520];
  int bs = blockIdx.x, ss = bs & 7, tid = threadIdx.x;
  if (tid < 128){
    float v = p.slots_init[ss*128+tid];
    sl[tid] = v;
    p.slots_g[(long)bs*128+tid] = v;
  }
  __syncthreads();
  phase0g(p, bs, tid, scr, sl,
          p.Sp_init[ss*2], p.Sp_init[ss*2+1], p.Ss_init[ss*2], p.Ss_init[ss*2+1]);
}

// ---------- kA: per (b, jtile): dots (8 slots x 64 tokens) + softmax + stats + hpart ----------
// hpart_g row layout: [(b*7+tile)][s][136]: h[0..127], stats[128..132]=SA,Sag0,Sag1,Sag20,Sag21
template<int LAST>
__global__ __launch_bounds__(256) void kA(PP p){
  int b = blockIdx.x / 7, tile = blockIdx.x % 7;
  int tid = threadIdx.x, wid = tid >> 6, lane = tid & 63;
  __shared__ float qws[8][132];
  __shared__ float qbs[8];
  __shared__ float spssL[32];
  __shared__ float agt[64][2];
  __shared__ float a_tile[8][64];
  __shared__ float hpartL[4][8][128];
  for (int f = tid; f < 8*128; f += 256){
    int s = f >> 7, d = f & 127;
    qws[s][(d&31)*4 + (d>>5)] = p.qw_g[((long)b*8+s)*128 + d];
  }
  if (tid < 8)  qbs[tid] = p.qb_g[b*8+tid];
  if (tid < 32) spssL[tid] = p.spss_g[b*32+tid];
  if (tid < 64){
    int j = tile*64 + tid;
    float g0 = 0.f, g1 = 0.f;
    if (j < NT){ int idx = p.tok_idx[b*NT+j]; g0 = p.abs_grid[idx*2]; g1 = p.abs_grid[idx*2+1]; }
    agt[tid][0] = g0; agt[tid][1] = g1;
  }
  __syncthreads();

  // ---- dots (R2 k4 scheme: 4 lanes x 16 tokens per wave) + per-token softmax ----
  {
    int tl = lane >> 2, dg = lane & 3;
    int jtok = wid*16 + tl, j = tile*64 + jtok;
    bool valid = j < NT;
    int jc = valid ? j : 0;
    float aa[32], w0[32], w1[32];
    const float* src = p.A_K + ((long)(b*NT+jc))*DD + dg*32;
    #pragma unroll
    for (int i4 = 0; i4 < 8; i4++){
      float4 t = *(const float4*)(src + i4*4);
      aa[i4*4+0]=t.x; aa[i4*4+1]=t.y; aa[i4*4+2]=t.z; aa[i4*4+3]=t.w;
    }
    #pragma unroll
    for (int i4 = 0; i4 < 8; i4++){
      float4 t0 = *(const float4*)(p.Wg1 + dg*32 + i4*4);
      float4 t1 = *(const float4*)(p.Wg1 + DD + dg*32 + i4*4);
      w0[i4*4+0]=t0.x; w0[i4*4+1]=t0.y; w0[i4*4+2]=t0.z; w0[i4*4+3]=t0.w;
      w1[i4*4+0]=t1.x; w1[i4*4+1]=t1.y; w1[i4*4+2]=t1.z; w1[i4*4+3]=t1.w;
    }
    float ag0 = agt[jtok][0], ag1 = agt[jtok][1];
    float dv[8];
    #pragma unroll
    for (int s = 0; s < 8; s++){
      float rel0 = (ag0 - spssL[s*4+0])*spssL[s*4+2];
      float rel1 = (ag1 - spssL[s*4+1])*spssL[s*4+3];
      float acc = 0.f;
      #pragma unroll
      for (int i = 0; i < 32; i++){
        float hk = fmaxf(fmaf(rel0, w0[i], fmaf(rel1, w1[i], aa[i])), 0.f);
        acc = fmaf(hk, qws[s][i*4+dg], acc);
      }
      acc += __shfl_xor(acc, 1); acc += __shfl_xor(acc, 2);
      dv[s] = acc*FSCALE + qbs[s];
    }
    if (dg == 0){
      float m = -1e30f;
      #pragma unroll
      for (int s = 0; s < 8; s++) m = fmaxf(m, dv[s]);
      float tot = 0.f;
      #pragma unroll
      for (int s = 0; s < 8; s++){ dv[s] = expf(dv[s]-m); tot += dv[s]; }
      float inv = 1.f/tot;
      #pragma unroll
      for (int s = 0; s < 8; s++)
        a_tile[s][jtok] = valid ? (dv[s]*inv + 1e-8f) : 0.f;
    }
  }
  __syncthreads();

  // ---- stats: wave handles 2 slots; lane = token ----
  #pragma unroll
  for (int si = 0; si < 2; si++){
    int s = wid*2 + si;
    float a = a_tile[s][lane];
    float g0 = agt[lane][0], g1 = agt[lane][1];
    float v0 = a, v1 = a*g0, v2 = a*g1, v3 = a*g0*g0, v4 = a*g1*g1;
    #pragma unroll
    for (int m = 1; m < 64; m <<= 1){
      v0 += __shfl_xor(v0,m); v1 += __shfl_xor(v1,m); v2 += __shfl_xor(v2,m);
      v3 += __shfl_xor(v3,m); v4 += __shfl_xor(v4,m);
    }
    if (lane == 0){
      float* st = p.hpart_g + ((long)(b*7+tile)*8 + s)*136 + 128;
      st[0]=v0; st[1]=v1; st[2]=v2; st[3]=v3; st[4]=v4;
    }
  }

  if (LAST){
    // store raw attn for center-frame b's (renormalized later in kB)
    if ((b % 5) == 2){
      int clip = b/5;
      for (int f = tid; f < 8*64; f += 256){
        int s = f >> 6, jt = f & 63;
        int j = tile*64 + jt;
        if (j < NT) p.a_g[((long)clip*8 + s)*NT + j] = a_tile[s][jt];
      }
    }
    return;
  }

  // ---- hpart: wid strides tokens; lane covers d0/d1 ----
  {
    float sp0[8], sp1[8], si0[8], si1[8];
    #pragma unroll
    for (int s = 0; s < 8; s++){
      sp0[s]=spssL[s*4+0]; sp1[s]=spssL[s*4+1]; si0[s]=spssL[s*4+2]; si1[s]=spssL[s*4+3];
    }
    int d0 = lane, d1 = lane + 64;
    float wg0a = p.Wg1[d0], wg1a = p.Wg1[DD+d0];
    float wg0b = p.Wg1[d1], wg1b = p.Wg1[DD+d1];
    float acc0[8], acc1[8];
    #pragma unroll
    for (int s = 0; s < 8; s++){ acc0[s]=0.f; acc1[s]=0.f; }
    for (int jj = wid; jj < 64; jj += 4){
      int j = tile*64 + jj;
      if (j >= NT) continue;
      float av0 = p.A_V[((long)(b*NT+j))*DD + d0];
      float av1 = p.A_V[((long)(b*NT+j))*DD + d1];
      float g0 = agt[jj][0], g1 = agt[jj][1];
      #pragma unroll
      for (int s = 0; s < 8; s++){
        float rel0 = (g0 - sp0[s])*si0[s];
        float rel1 = (g1 - sp1[s])*si1[s];
        float a = a_tile[s][jj];
        float hv0 = fmaxf(fmaf(rel0, wg0a, fmaf(rel1, wg1a, av0)), 0.f);
        float hv1 = fmaxf(fmaf(rel0, wg0b, fmaf(rel1, wg1b, av1)), 0.f);
        acc0[s] = fmaf(a, hv0, acc0[s]);
        acc1[s] = fmaf(a, hv1, acc1[s]);
      }
    }
    #pragma unroll
    for (int s = 0; s < 8; s++){ hpartL[wid][s][d0] = acc0[s]; hpartL[wid][s][d1] = acc1[s]; }
    __syncthreads();
    for (int f = tid; f < 1024; f += 256){
      int s = f >> 7, d = f & 127;
      p.hpart_g[((long)(b*7+tile)*8 + s)*136 + d] =
        hpartL[0][s][d] + hpartL[1][s][d] + hpartL[2][s][d] + hpartL[3][s][d];
    }
  }
}

// ---------- kB: per (b,s): reduce stats+hpart -> Sp/Ss/hbar -> GRU -> MLP -> phase0 ----------
template<int LAST>
__global__ __launch_bounds__(256) void kB(PP p){
  __shared__ float red[8];
  __shared__ float sl[128];
  __shared__ float hb[128];
  __shared__ float scr[2304];
  int bs = blockIdx.x, b = bs >> 3, ss = bs & 7, tid = threadIdx.x;
  if (tid < 5){
    float v = 0.f;
    #pragma unroll
    for (int t7 = 0; t7 < 7; t7++) v += p.hpart_g[((long)(b*7+t7)*8 + ss)*136 + 128 + tid];
    red[tid] = v;
  }
  __syncthreads();
  float SA = red[0], inv = 1.f/SA;
  float Sp0 = red[1]*inv, Sp1 = red[2]*inv;
  float Ss0 = sqrtf(fmaxf(red[3]*inv - Sp0*Sp0, 0.f));
  float Ss1 = sqrtf(fmaxf(red[4]*inv - Sp1*Sp1, 0.f));

  if (LAST){
    if ((b % 5) == 2){
      int clip = b/5;
      long base = (long)NB*NS*DD + ((long)clip*8 + ss)*NT;
      const float* arow = p.a_g + ((long)clip*8 + ss)*NT;
      for (int j = tid; j < NT; j += 256) p.out[base+j] = arow[j]*inv;
    }
    // final projection
    if (tid < 128) sl[tid] = p.slots_g[(long)bs*128+tid];
    __syncthreads();
    int o = tid & 127, h = tid >> 7;
    float acc = 0.f;
    for (int k = 0; k < 64; k++) acc = fmaf(sl[h*64+k], p.fin_w[(h*64+k)*128+o], acc);
    scr[h*128+o] = acc;
    __syncthreads();
    if (tid < 128) p.out[(long)bs*128+tid] = p.fin_b[tid] + scr[tid] + scr[128+tid];
    return;
  }

  if (tid < 128){
    float v = 0.f;
    #pragma unroll
    for (int t7 = 0; t7 < 7; t7++) v += p.hpart_g[((long)(b*7+t7)*8 + ss)*136 + tid];
    hb[tid] = v * inv;
    sl[tid] = p.slots_g[(long)bs*128+tid];
  }
  __syncthreads();
  // upd = hb@Wf2 + bf2
  float* part = scr;           // 256
  float* upd  = scr + 256;     // 128
  float* gil  = scr + 384;     // 384
  float* ghl  = scr + 768;     // 384
  float* hnl  = scr + 1152;    // 128
  float* yv   = scr + 1280;    // 128
  float* h1   = scr + 1408;    // 512
  int o = tid & 127, h = tid >> 7;
  float acc2 = 0.f;
  for (int k = 0; k < 64; k++) acc2 = fmaf(hb[h*64+k], p.Wf2[(h*64+k)*128+o], acc2);
  part[h*128+o] = acc2;
  __syncthreads();
  if (tid < 128) upd[tid] = part[tid] + part[128+tid] + p.bf2[tid];
  __syncthreads();
  // GRU
  int oA = tid, oB = tid + 256;
  float giA = p.gru_b_ih[oA], ghA = p.gru_b_hh[oA];
  float giB = 0.f, ghB = 0.f;
  if (tid < 128){ giB = p.gru_b_ih[oB]; ghB = p.gru_b_hh[oB]; }
  for (int k = 0; k < 128; k++){
    float uk = upd[k], sk = sl[k];
    giA = fmaf(uk, p.gru_w_ih[k*384+oA], giA);
    ghA = fmaf(sk, p.gru_w_hh[k*384+oA], ghA);
    if (tid < 128){
      giB = fmaf(uk, p.gru_w_ih[k*384+oB], giB);
      ghB = fmaf(sk, p.gru_w_hh[k*384+oB], ghB);
    }
  }
  gil[oA] = giA; ghl[oA] = ghA;
  if (tid < 128){ gil[oB] = giB; ghl[oB] = ghB; }
  __syncthreads();
  float hnv = 0.f;
  if (tid < 128){
    float r = 1.f/(1.f+expf(-(gil[tid]+ghl[tid])));
    float z = 1.f/(1.f+expf(-(gil[128+tid]+ghl[128+tid])));
    float n = tanhf(gil[256+tid] + r*ghl[256+tid]);
    hnv = (1.f-z)*n + z*sl[tid];
  }
  float t1 = hnv, t2 = hnv*hnv;
  #pragma unroll
  for (int m = 1; m < 64; m <<= 1){ t1 += __shfl_xor(t1,m); t2 += __shfl_xor(t2,m); }
  if (tid < 128 && (tid & 63) == 0){ red[(tid>>6)*2] = t1; red[(tid>>6)*2+1] = t2; }
  __syncthreads();
  float mean = (red[0]+red[2])*(1.f/128.f);
  float var  = (red[1]+red[3])*(1.f/128.f) - mean*mean;
  float rstd = rsqrtf(var + 1e-5f);
  if (tid < 128){
    hnl[tid] = hnv;
    yv[tid] = (hnv-mean)*rstd*p.mlp_ln_g[tid] + p.mlp_ln_b[tid];
  }
  __syncthreads();
  float m1A = p.mlp_b1[tid], m1B = p.mlp_b1[tid+256];
  for (int k = 0; k < 128; k++){
    float y = yv[k];
    m1A = fmaf(y, p.mlp_w1[k*512+tid], m1A);
    m1B = fmaf(y, p.mlp_w1[k*512+tid+256], m1B);
  }
  h1[tid] = fmaxf(m1A, 0.f); h1[tid+256] = fmaxf(m1B, 0.f);
  __syncthreads();
  float a2 = 0.f;
  for (int kk = 0; kk < 256; kk++) a2 = fmaf(h1[h*256+kk], p.mlp_w2[(h*256+kk)*128+o], a2);
  part[h*128+o] = a2;
  __syncthreads();
  if (tid < 128){
    float sln = hnl[tid] + p.mlp_b2[tid] + part[tid] + part[128+tid];
    sl[tid] = sln;
    p.slots_g[(long)bs*128+tid] = sln;
  }
  __syncthreads();
  phase0g(p, bs, tid, scr, sl, Sp0, Sp1, Ss0, Ss1);
}

extern "C" void kernel_launch(void* const* d_in, const int* in_sizes, int n_in,
                              void* d_out, int out_size, void* d_ws, size_t ws_size,
                              hipStream_t stream){
  PP p;
  p.inputs=(const float*)d_in[0]; p.tok_idx=(const int*)d_in[1]; p.abs_grid=(const float*)d_in[2];
  p.slots_init=(const float*)d_in[3]; p.Sp_init=(const float*)d_in[4]; p.Ss_init=(const float*)d_in[5];
  p.WQ=(const float*)d_in[6]; p.ln_g=(const float*)d_in[7]; p.ln_b=(const float*)d_in[8];
  p.gru_w_ih=(const float*)d_in[9]; p.gru_w_hh=(const float*)d_in[10];
  p.gru_b_ih=(const float*)d_in[11]; p.gru_b_hh=(const float*)d_in[12];
  p.mlp_ln_g=(const float*)d_in[13]; p.mlp_ln_b=(const float*)d_in[14];
  p.mlp_w1=(const float*)d_in[15]; p.mlp_b1=(const float*)d_in[16];
  p.mlp_w2=(const float*)d_in[17]; p.mlp_b2=(const float*)d_in[18];
  p.WK=(const float*)d_in[19]; p.WV=(const float*)d_in[20]; p.Wg=(const float*)d_in[21]; p.bg=(const float*)d_in[22];
  p.Wf1=(const float*)d_in[23]; p.bf1=(const float*)d_in[24]; p.Wf2=(const float*)d_in[25]; p.bf2=(const float*)d_in[26];
  p.im_ln1_g=(const float*)d_in[27]; p.im_ln1_b=(const float*)d_in[28];
  p.im_w1=(const float*)d_in[29]; p.im_b1=(const float*)d_in[30];
  p.im_w2=(const float*)d_in[31]; p.im_b2=(const float*)d_in[32];
  p.im_ln2_g=(const float*)d_in[33]; p.im_ln2_b=(const float*)d_in[34];
  p.fin_w=(const float*)d_in[35]; p.fin_b=(const float*)d_in[36];

  float* w = (float*)d_ws;
  size_t need = 0;
  auto alloc = [&](size_t nfl){ nfl = (nfl + 3) & ~(size_t)3; float* r = w + need; need += nfl; return r; };
  p.x    = alloc((size_t)NTOT*DD);
  p.A_K  = alloc((size_t)NTOT*DD);
  p.A_V  = alloc((size_t)NTOT*DD);
  p.WKf  = alloc(DD*DD);
  p.WVf  = alloc(DD*DD);
  p.Wg1  = alloc(2*DD);
  p.c1   = alloc(DD);
  p.Wf2T = alloc(DD*DD);
  p.slots_g = alloc(320*128);
  p.qw_g    = alloc(320*128);
  p.qb_g    = alloc(320);
  p.spss_g  = alloc(320*4);
  p.hpart_g = alloc((size_t)280*8*136);
  p.a_g     = alloc((size_t)8*8*NT);
  p.xnh  = (ushort*)alloc((size_t)NTOT*DIN/2);
  p.xnl  = (ushort*)alloc((size_t)NTOT*DIN/2);
  p.hh   = (ushort*)alloc((size_t)NTOT*DIN/2);
  p.hl   = (ushort*)alloc((size_t)NTOT*DIN/2);
  p.W1Th = (ushort*)alloc((size_t)DIN*DIN/2);
  p.W1Tl = (ushort*)alloc((size_t)DIN*DIN/2);
  p.W2Th = (ushort*)alloc((size_t)DD*DIN/2);
  p.W2Tl = (ushort*)alloc((size_t)DD*DIN/2);
  p.out = (float*)d_out;
  if (ws_size < need*sizeof(float)){
    fprintf(stderr, "kernel_launch: ws too small (%zu < %zu)\n", ws_size, need*sizeof(float));
    return;
  }

  prep_weights<<<dim3(DD), dim3(128), 0, stream>>>(p);
  transpose_split<<<dim3(DIN/64, DIN/64), dim3(256), 0, stream>>>(p.im_w1, p.W1Th, p.W1Tl, DIN, DIN);
  transpose_split<<<dim3(DIN/64, DD/64), dim3(256), 0, stream>>>(p.im_w2, p.W2Th, p.W2Tl, DIN, DD);
  ln1_split<<<dim3(NTOT/4), dim3(256), 0, stream>>>(p);
  gemm_split<1><<<dim3(DIN/128, (NTOT+63)/64), dim3(256), 0, stream>>>(
      p.xnh, p.xnl, p.W1Th, p.W1Tl, p.im_b1, p.hh, p.hl,
      nullptr, nullptr, nullptr, NTOT);
  gemm_split<2><<<dim3(1, (NTOT+63)/64), dim3(256), 0, stream>>>(
      p.hh, p.hl, p.W2Th, p.W2Tl, p.im_b2, nullptr, nullptr,
      p.x, p.im_ln2_g, p.im_ln2_b, NTOT);
  k2_proj<<<dim3((NTOT+31)/32), dim3(256), 0, stream>>>(p);
  k_init<<<dim3(320), dim3(256), 0, stream>>>(p);

  for (int t = 0; t < 3; t++){
    kA<0><<<dim3(NB*7), dim3(256), 0, stream>>>(p);
    kB<0><<<dim3(320), dim3(256), 0, stream>>>(p);
  }
  kA<1><<<dim3(NB*7), dim3(256), 0, stream>>>(p);
  kB<1><<<dim3(320), dim3(256), 0, stream>>>(p);
}

// Round 11
// 461.646 us; speedup vs baseline: 3.1643x; 1.0255x over previous
//
#include <hip/hip_runtime.h>
#include <cstdio>

#define NB 40
#define NS 8
#define NT 441
#define DIN 768
#define DD 128
#define NTOT (NB*NT)
#define FSCALE 0.08838834764831843f

typedef short s8v __attribute__((ext_vector_type(8)));
typedef float f4v __attribute__((ext_vector_type(4)));

__device__ inline ushort f2bf(float f){
  unsigned u = __float_as_uint(f);
  unsigned r = (u + 0x7fffu + ((u >> 16) & 1u)) >> 16;
  return (ushort)r;
}
__device__ inline float bf2f(ushort h){ return __uint_as_float(((unsigned)h) << 16); }

struct PP {
  const float *inputs; const int *tok_idx; const float *abs_grid;
  const float *slots_init, *Sp_init, *Ss_init;
  const float *WQ, *ln_g, *ln_b;
  const float *gru_w_ih, *gru_w_hh, *gru_b_ih, *gru_b_hh;
  const float *mlp_ln_g, *mlp_ln_b, *mlp_w1, *mlp_b1, *mlp_w2, *mlp_b2;
  const float *WK, *WV, *Wg, *bg, *Wf1, *bf1, *Wf2, *bf2;
  const float *im_ln1_g, *im_ln1_b, *im_w1, *im_b1, *im_w2, *im_b2, *im_ln2_g, *im_ln2_b;
  const float *fin_w, *fin_b;
  float *x, *A_K, *A_V, *WKf, *WVf, *Wg1, *c1, *Wf2T;
  float *slots_g, *qw_g, *qb_g, *spss_g, *hpart_g, *a_g;
  ushort *xnh, *xnl, *hh, *hl, *W1Th, *W1Tl, *W2Th, *W2Tl;
  float *out;
};

// ---------- weight prep ----------
__global__ __launch_bounds__(128) void prep_weights(PP p){
  int r = blockIdx.x, d = threadIdx.x;
  float accK = 0.f, accV = 0.f;
  for (int kk = 0; kk < DD; kk++){
    float w = p.Wf1[kk*DD + d];
    accK = fmaf(p.WK[r*DD+kk], w, accK);
    accV = fmaf(p.WV[r*DD+kk], w, accV);
  }
  p.WKf[r*DD+d] = accK; p.WVf[r*DD+d] = accV;
  if (r < 2){
    float a = 0.f;
    for (int kk = 0; kk < DD; kk++) a = fmaf(p.Wg[r*DD+kk], p.Wf1[kk*DD+d], a);
    p.Wg1[r*DD+d] = a;
  }
  if (r == 2){
    float a = 0.f;
    for (int kk = 0; kk < DD; kk++) a = fmaf(p.bg[kk], p.Wf1[kk*DD+d], a);
    p.c1[d] = a + p.bf1[d];
  }
  p.Wf2T[d*DD + r] = p.Wf2[r*DD + d];
}

// ---------- transpose + bf16 split ----------
__global__ __launch_bounds__(256) void transpose_split(const float* __restrict__ W,
                                                       ushort* __restrict__ WTh,
                                                       ushort* __restrict__ WTl,
                                                       int K, int N){
  __shared__ float tile[64][65];
  int tid = threadIdx.x;
  int k0 = blockIdx.x * 64, n0 = blockIdx.y * 64;
  #pragma unroll
  for (int i = 0; i < 4; i++){
    int k = i*16 + (tid >> 4);
    int n4 = (tid & 15) * 4;
    float4 v = *(const float4*)(W + (long)(k0+k)*N + n0 + n4);
    tile[k][n4+0] = v.x; tile[k][n4+1] = v.y; tile[k][n4+2] = v.z; tile[k][n4+3] = v.w;
  }
  __syncthreads();
  #pragma unroll
  for (int i = 0; i < 4; i++){
    int n = i*16 + (tid >> 4);
    int k4 = (tid & 15) * 4;
    ushort4 h4, l4;
    float v0 = tile[k4+0][n], v1 = tile[k4+1][n], v2 = tile[k4+2][n], v3 = tile[k4+3][n];
    h4.x = f2bf(v0); l4.x = f2bf(v0 - bf2f(h4.x));
    h4.y = f2bf(v1); l4.y = f2bf(v1 - bf2f(h4.y));
    h4.z = f2bf(v2); l4.z = f2bf(v2 - bf2f(h4.z));
    h4.w = f2bf(v3); l4.w = f2bf(v3 - bf2f(h4.w));
    *(ushort4*)(WTh + (long)(n0+n)*K + k0 + k4) = h4;
    *(ushort4*)(WTl + (long)(n0+n)*K + k0 + k4) = l4;
  }
}

// ---------- LN1 + bf16 hi/lo split ----------
__global__ __launch_bounds__(256) void ln1_split(PP p){
  int tok = blockIdx.x*4 + (threadIdx.x >> 6);
  int l = threadIdx.x & 63;
  const float* src = p.inputs + (long)tok*DIN;
  float4 v[3];
  float s = 0.f, s2 = 0.f;
  #pragma unroll
  for (int pp = 0; pp < 3; pp++){
    v[pp] = *(const float4*)(src + pp*256 + l*4);
    s  += v[pp].x + v[pp].y + v[pp].z + v[pp].w;
    s2 += v[pp].x*v[pp].x + v[pp].y*v[pp].y + v[pp].z*v[pp].z + v[pp].w*v[pp].w;
  }
  #pragma unroll
  for (int m = 1; m < 64; m <<= 1){ s += __shfl_xor(s, m); s2 += __shfl_xor(s2, m); }
  float mean = s*(1.f/DIN), var = s2*(1.f/DIN) - mean*mean;
  float rstd = rsqrtf(var + 1e-5f);
  #pragma unroll
  for (int pp = 0; pp < 3; pp++){
    int idx = pp*256 + l*4;
    float4 g = *(const float4*)(p.im_ln1_g + idx);
    float4 b = *(const float4*)(p.im_ln1_b + idx);
    float y0 = (v[pp].x-mean)*rstd*g.x + b.x;
    float y1 = (v[pp].y-mean)*rstd*g.y + b.y;
    float y2 = (v[pp].z-mean)*rstd*g.z + b.z;
    float y3 = (v[pp].w-mean)*rstd*g.w + b.w;
    ushort4 h4, l4;
    h4.x = f2bf(y0); l4.x = f2bf(y0 - bf2f(h4.x));
    h4.y = f2bf(y1); l4.y = f2bf(y1 - bf2f(h4.y));
    h4.z = f2bf(y2); l4.z = f2bf(y2 - bf2f(h4.z));
    h4.w = f2bf(y3); l4.w = f2bf(y3 - bf2f(h4.w));
    *(ushort4*)(p.xnh + (long)tok*DIN + idx) = h4;
    *(ushort4*)(p.xnl + (long)tok*DIN + idx) = l4;
  }
}

// ---------- GEMM1: 128x128 tile, XCD-aware m-grouping, bias+relu+split epilogue ----------
__global__ __launch_bounds__(256) void gemm1_128(PP p){
  __shared__ __align__(16) ushort As[2][128][40];   // 20480 B
  __shared__ __align__(16) ushort Bs[2][128][40];   // 20480 B
  // bijective XCD swizzle over padded 832 grid: all 6 n-blocks of an m-tile on one XCD
  int id = blockIdx.x;
  int xcd = id & 7, idx = id >> 3;          // idx 0..103
  int m_t = xcd + 8*(idx/6), n_t = idx % 6; // m_t 0..143
  if (m_t >= 138) return;
  int m0 = m_t*128, n0 = n_t*128;
  int tid = threadIdx.x;
  int w = tid >> 6, lane = tid & 63;
  int wm = w >> 1, wn = w & 1;
  f4v acc[4][4];
  #pragma unroll
  for (int mf = 0; mf < 4; mf++)
    #pragma unroll
    for (int nf = 0; nf < 4; nf++) acc[mf][nf] = (f4v)(0.f);

  for (int kb = 0; kb < DIN; kb += 32){
    __syncthreads();
    #pragma unroll
    for (int i = 0; i < 4; i++){
      int c = tid + i*256;                  // 0..1023
      int s = c >> 9, rem = c & 511;
      int r = rem >> 2, kg = rem & 3;
      int gr = min(m0 + r, NTOT-1);
      const float4 va = *(const float4*)((s ? p.xnl : p.xnh) + (long)gr*DIN + kb + kg*8);
      *(float4*)(&As[s][r][kg*8]) = va;
      const float4 vb = *(const float4*)((s ? p.W1Tl : p.W1Th) + (long)(n0 + r)*DIN + kb + kg*8);
      *(float4*)(&Bs[s][r][kg*8]) = vb;
    }
    __syncthreads();
    int kg = lane >> 4, rA = lane & 15;
    s8v a0[4], a1[4], b0[4], b1[4];
    #pragma unroll
    for (int mf = 0; mf < 4; mf++){
      a0[mf] = *(const s8v*)(&As[0][wm*64 + mf*16 + rA][kg*8]);
      a1[mf] = *(const s8v*)(&As[1][wm*64 + mf*16 + rA][kg*8]);
    }
    #pragma unroll
    for (int nf = 0; nf < 4; nf++){
      b0[nf] = *(const s8v*)(&Bs[0][wn*64 + nf*16 + rA][kg*8]);
      b1[nf] = *(const s8v*)(&Bs[1][wn*64 + nf*16 + rA][kg*8]);
    }
    #pragma unroll
    for (int mf = 0; mf < 4; mf++)
      #pragma unroll
      for (int nf = 0; nf < 4; nf++){
        acc[mf][nf] = __builtin_amdgcn_mfma_f32_16x16x32_bf16(a0[mf], b0[nf], acc[mf][nf], 0, 0, 0);
        acc[mf][nf] = __builtin_amdgcn_mfma_f32_16x16x32_bf16(a0[mf], b1[nf], acc[mf][nf], 0, 0, 0);
        acc[mf][nf] = __builtin_amdgcn_mfma_f32_16x16x32_bf16(a1[mf], b0[nf], acc[mf][nf], 0, 0, 0);
      }
  }

  int rbase = (lane >> 4) * 4, cn = lane & 15;
  #pragma unroll
  for (int mf = 0; mf < 4; mf++)
    #pragma unroll
    for (int nf = 0; nf < 4; nf++){
      int n = n0 + wn*64 + nf*16 + cn;
      float bs = p.im_b1[n];
      #pragma unroll
      for (int r = 0; r < 4; r++){
        int m = m0 + wm*64 + mf*16 + rbase + r;
        if (m < NTOT){
          float v = fmaxf(acc[mf][nf][r] + bs, 0.f);
          ushort h = f2bf(v);
          p.hh[(long)m*DIN + n] = h;
          p.hl[(long)m*DIN + n] = f2bf(v - bf2f(h));
        }
      }
    }
}

// ---------- split-bf16 MFMA GEMM (64x128 tile) — used for GEMM2 (bias+LN epilogue) ----------
__global__ __launch_bounds__(256) void gemm_split2(
    const ushort* __restrict__ Ah, const ushort* __restrict__ Al,
    const ushort* __restrict__ Bh, const ushort* __restrict__ Bl,
    const float* __restrict__ bias,
    float* __restrict__ Xout, const float* __restrict__ g2, const float* __restrict__ b2,
    int M)
{
  __shared__ __align__(16) char smemc[64*132*4];
  ushort* As = (ushort*)smemc;
  ushort* Bs = (ushort*)(smemc + 10240);
  int tid = threadIdx.x;
  int n0 = blockIdx.x * 128, m0 = blockIdx.y * 64;
  int w = tid >> 6, lane = tid & 63;
  f4v acc[4][2];
  #pragma unroll
  for (int mf = 0; mf < 4; mf++)
    #pragma unroll
    for (int nf = 0; nf < 2; nf++) acc[mf][nf] = (f4v)(0.f);

  for (int kb = 0; kb < DIN; kb += 32){
    __syncthreads();
    #pragma unroll
    for (int i = 0; i < 2; i++){
      int c = tid + i*256;
      int s = c >> 8, r = (c >> 2) & 63, kg = c & 3;
      int gr = min(m0 + r, M-1);
      const float4 va = *(const float4*)((s ? Al : Ah) + (long)gr*DIN + kb + kg*8);
      *(float4*)(As + s*2560 + r*40 + kg*8) = va;
    }
    #pragma unroll
    for (int i = 0; i < 4; i++){
      int c = tid + i*256;
      int s = c >> 9, r = (c >> 2) & 127, kg = c & 3;
      const float4 vb = *(const float4*)((s ? Bl : Bh) + (long)(n0 + r)*DIN + kb + kg*8);
      *(float4*)(Bs + s*5120 + r*40 + kg*8) = vb;
    }
    __syncthreads();
    int kg = lane >> 4, rA = lane & 15;
    s8v a0[4], a1[4], b0[2], b1[2];
    #pragma unroll
    for (int mf = 0; mf < 4; mf++){
      a0[mf] = *(const s8v*)(As +        (mf*16 + rA)*40 + kg*8);
      a1[mf] = *(const s8v*)(As + 2560 + (mf*16 + rA)*40 + kg*8);
    }
    #pragma unroll
    for (int nf = 0; nf < 2; nf++){
      int rb = w*32 + nf*16 + rA;
      b0[nf] = *(const s8v*)(Bs +        rb*40 + kg*8);
      b1[nf] = *(const s8v*)(Bs + 5120 + rb*40 + kg*8);
    }
    #pragma unroll
    for (int mf = 0; mf < 4; mf++)
      #pragma unroll
      for (int nf = 0; nf < 2; nf++){
        acc[mf][nf] = __builtin_amdgcn_mfma_f32_16x16x32_bf16(a0[mf], b0[nf], acc[mf][nf], 0, 0, 0);
        acc[mf][nf] = __builtin_amdgcn_mfma_f32_16x16x32_bf16(a0[mf], b1[nf], acc[mf][nf], 0, 0, 0);
        acc[mf][nf] = __builtin_amdgcn_mfma_f32_16x16x32_bf16(a1[mf], b0[nf], acc[mf][nf], 0, 0, 0);
      }
  }

  int rbase = (lane >> 4) * 4, cn = lane & 15;
  __syncthreads();
  float* Dl = (float*)smemc;
  #pragma unroll
  for (int mf = 0; mf < 4; mf++)
    #pragma unroll
    for (int nf = 0; nf < 2; nf++){
      int n = w*32 + nf*16 + cn;
      float bs = bias[n];
      #pragma unroll
      for (int r = 0; r < 4; r++)
        Dl[(mf*16 + rbase + r)*132 + n] = acc[mf][nf][r] + bs;
    }
  __syncthreads();
  for (int rr = 0; rr < 16; rr++){
    int row = w*16 + rr;
    float e0 = Dl[row*132 + lane], e1 = Dl[row*132 + 64 + lane];
    float s = e0 + e1, s2 = e0*e0 + e1*e1;
    #pragma unroll
    for (int m2 = 1; m2 < 64; m2 <<= 1){ s += __shfl_xor(s, m2); s2 += __shfl_xor(s2, m2); }
    float mean = s*(1.f/DD), var = s2*(1.f/DD) - mean*mean;
    float rstd = rsqrtf(var + 1e-5f);
    int m = m0 + row;
    if (m < M){
      Xout[(long)m*DD + lane]      = (e0-mean)*rstd*g2[lane]      + b2[lane];
      Xout[(long)m*DD + 64 + lane] = (e1-mean)*rstd*g2[64 + lane] + b2[64 + lane];
    }
  }
}

// ---------- A_K = x@WKf + c1 ; A_V = x@WVf + c1 ----------
__global__ __launch_bounds__(256) void k2_proj(PP p){
  __shared__ float xt[32][132];
  int tid = threadIdx.x; int g0 = blockIdx.x * 32;
  for (int f = tid; f < 32*32; f += 256){
    int tok = f >> 5, pos = (f & 31) * 4;
    int gt = g0 + tok;
    float4 v = (gt < NTOT) ? *(const float4*)(p.x + (long)gt*DD + pos)
                           : make_float4(0.f,0.f,0.f,0.f);
    *(float4*)&xt[tok][pos] = v;
  }
  __syncthreads();
  int d = tid & 127, grp = tid >> 7;
  float aK[16], aV[16];
  float c1v = p.c1[d];
  #pragma unroll
  for (int t = 0; t < 16; t++){ aK[t] = c1v; aV[t] = c1v; }
  for (int kk = 0; kk < DD; kk += 4){
    float k0 = p.WKf[(kk+0)*DD+d], k1 = p.WKf[(kk+1)*DD+d], k2 = p.WKf[(kk+2)*DD+d], k3 = p.WKf[(kk+3)*DD+d];
    float v0 = p.WVf[(kk+0)*DD+d], v1 = p.WVf[(kk+1)*DD+d], v2 = p.WVf[(kk+2)*DD+d], v3 = p.WVf[(kk+3)*DD+d];
    #pragma unroll
    for (int t = 0; t < 16; t++){
      float4 xv = *(const float4*)&xt[grp*16+t][kk];
      aK[t] = fmaf(xv.x,k0, fmaf(xv.y,k1, fmaf(xv.z,k2, fmaf(xv.w,k3, aK[t]))));
      aV[t] = fmaf(xv.x,v0, fmaf(xv.y,v1, fmaf(xv.z,v2, fmaf(xv.w,v3, aV[t]))));
    }
  }
  #pragma unroll
  for (int t = 0; t < 16; t++){
    int gt = g0 + grp*16 + t;
    if (gt < NTOT){ p.A_K[(long)gt*DD+d] = aK[t]; p.A_V[(long)gt*DD+d] = aV[t]; }
  }
}

// ---------- phase0 ----------
__device__ void phase0g(const PP& p, int bs, int tid, float* scr, const float* sl,
                        float Sp0, float Sp1, float Ss0, float Ss1){
  float* sn   = scr;
  float* qv   = scr + 128;
  float* part = scr + 256;
  float* red  = scr + 512;
  int o = tid & 127, h = tid >> 7;
  float v = (tid < 128) ? sl[tid] : 0.f;
  float s1 = v, s2 = v*v;
  #pragma unroll
  for (int m = 1; m < 64; m <<= 1){ s1 += __shfl_xor(s1,m); s2 += __shfl_xor(s2,m); }
  if (tid < 128 && (tid & 63) == 0){ red[(tid>>6)*2] = s1; red[(tid>>6)*2+1] = s2; }
  __syncthreads();
  float mean = (red[0]+red[2])*(1.f/128.f);
  float var  = (red[1]+red[3])*(1.f/128.f) - mean*mean;
  float rstd = rsqrtf(var + 1e-5f);
  if (tid < 128) sn[tid] = (v-mean)*rstd*p.ln_g[tid] + p.ln_b[tid];
  __syncthreads();
  float acc = 0.f;
  for (int k = 0; k < 64; k++) acc = fmaf(sn[h*64+k], p.WQ[(h*64+k)*128+o], acc);
  part[h*128+o] = acc;
  __syncthreads();
  if (tid < 128) qv[tid] = part[tid] + part[128+tid];
  __syncthreads();
  float acc2 = 0.f;
  for (int k = 0; k < 64; k++) acc2 = fmaf(qv[h*64+k], p.Wf2T[(h*64+k)*128+o], acc2);
  part[h*128+o] = acc2;
  __syncthreads();
  if (tid < 128) p.qw_g[(long)bs*128+tid] = part[tid] + part[128+tid];
  float pb = (tid < 128) ? qv[tid]*p.bf2[tid] : 0.f;
  #pragma unroll
  for (int m = 1; m < 64; m <<= 1) pb += __shfl_xor(pb,m);
  if ((tid & 63) == 0) red[4 + (tid>>6)] = pb;
  __syncthreads();
  if (tid == 0){
    p.qb_g[bs] = FSCALE*(red[4]+red[5]+red[6]+red[7]);
    p.spss_g[bs*4+0] = Sp0; p.spss_g[bs*4+1] = Sp1;
    p.spss_g[bs*4+2] = 1.f/(Ss0*5.0f); p.spss_g[bs*4+3] = 1.f/(Ss1*5.0f);
  }
}

// ---------- init ----------
__global__ __launch_bounds__(256) void k_init(PP p){
  __shared__ float sl[128];
  __shared__ float scr[520];
  int bs = blockIdx.x, ss = bs & 7, tid = threadIdx.x;
  if (tid < 128){
    float v = p.slots_init[ss*128+tid];
    sl[tid] = v;
    p.slots_g[(long)bs*128+tid] = v;
  }
  __syncthreads();
  phase0g(p, bs, tid, scr, sl,
          p.Sp_init[ss*2], p.Sp_init[ss*2+1], p.Ss_init[ss*2], p.Ss_init[ss*2+1]);
}

// ---------- kA ----------
template<int LAST>
__global__ __launch_bounds__(256) void kA(PP p){
  int b = blockIdx.x / 7, tile = blockIdx.x % 7;
  int tid = threadIdx.x, wid = tid >> 6, lane = tid & 63;
  __shared__ float qws[8][132];
  __shared__ float qbs[8];
  __shared__ float spssL[32];
  __shared__ float agt[64][2];
  __shared__ float a_tile[8][64];
  __shared__ float hpartL[4][8][128];
  for (int f = tid; f < 8*128; f += 256){
    int s = f >> 7, d = f & 127;
    qws[s][(d&31)*4 + (d>>5)] = p.qw_g[((long)b*8+s)*128 + d];
  }
  if (tid < 8)  qbs[tid] = p.qb_g[b*8+tid];
  if (tid < 32) spssL[tid] = p.spss_g[b*32+tid];
  if (tid < 64){
    int j = tile*64 + tid;
    float g0 = 0.f, g1 = 0.f;
    if (j < NT){ int idx = p.tok_idx[b*NT+j]; g0 = p.abs_grid[idx*2]; g1 = p.abs_grid[idx*2+1]; }
    agt[tid][0] = g0; agt[tid][1] = g1;
  }
  __syncthreads();

  {
    int tl = lane >> 2, dg = lane & 3;
    int jtok = wid*16 + tl, j = tile*64 + jtok;
    bool valid = j < NT;
    int jc = valid ? j : 0;
    float aa[32], w0[32], w1[32];
    const float* src = p.A_K + ((long)(b*NT+jc))*DD + dg*32;
    #pragma unroll
    for (int i4 = 0; i4 < 8; i4++){
      float4 t = *(const float4*)(src + i4*4);
      aa[i4*4+0]=t.x; aa[i4*4+1]=t.y; aa[i4*4+2]=t.z; aa[i4*4+3]=t.w;
    }
    #pragma unroll
    for (int i4 = 0; i4 < 8; i4++){
      float4 t0 = *(const float4*)(p.Wg1 + dg*32 + i4*4);
      float4 t1 = *(const float4*)(p.Wg1 + DD + dg*32 + i4*4);
      w0[i4*4+0]=t0.x; w0[i4*4+1]=t0.y; w0[i4*4+2]=t0.z; w0[i4*4+3]=t0.w;
      w1[i4*4+0]=t1.x; w1[i4*4+1]=t1.y; w1[i4*4+2]=t1.z; w1[i4*4+3]=t1.w;
    }
    float ag0 = agt[jtok][0], ag1 = agt[jtok][1];
    float dv[8];
    #pragma unroll
    for (int s = 0; s < 8; s++){
      float rel0 = (ag0 - spssL[s*4+0])*spssL[s*4+2];
      float rel1 = (ag1 - spssL[s*4+1])*spssL[s*4+3];
      float acc = 0.f;
      #pragma unroll
      for (int i = 0; i < 32; i++){
        float hk = fmaxf(fmaf(rel0, w0[i], fmaf(rel1, w1[i], aa[i])), 0.f);
        acc = fmaf(hk, qws[s][i*4+dg], acc);
      }
      acc += __shfl_xor(acc, 1); acc += __shfl_xor(acc, 2);
      dv[s] = acc*FSCALE + qbs[s];
    }
    if (dg == 0){
      float m = -1e30f;
      #pragma unroll
      for (int s = 0; s < 8; s++) m = fmaxf(m, dv[s]);
      float tot = 0.f;
      #pragma unroll
      for (int s = 0; s < 8; s++){ dv[s] = expf(dv[s]-m); tot += dv[s]; }
      float inv = 1.f/tot;
      #pragma unroll
      for (int s = 0; s < 8; s++)
        a_tile[s][jtok] = valid ? (dv[s]*inv + 1e-8f) : 0.f;
    }
  }
  __syncthreads();

  #pragma unroll
  for (int si = 0; si < 2; si++){
    int s = wid*2 + si;
    float a = a_tile[s][lane];
    float g0 = agt[lane][0], g1 = agt[lane][1];
    float v0 = a, v1 = a*g0, v2 = a*g1, v3 = a*g0*g0, v4 = a*g1*g1;
    #pragma unroll
    for (int m = 1; m < 64; m <<= 1){
      v0 += __shfl_xor(v0,m); v1 += __shfl_xor(v1,m); v2 += __shfl_xor(v2,m);
      v3 += __shfl_xor(v3,m); v4 += __shfl_xor(v4,m);
    }
    if (lane == 0){
      float* st = p.hpart_g + ((long)(b*7+tile)*8 + s)*136 + 128;
      st[0]=v0; st[1]=v1; st[2]=v2; st[3]=v3; st[4]=v4;
    }
  }

  if (LAST){
    if ((b % 5) == 2){
      int clip = b/5;
      for (int f = tid; f < 8*64; f += 256){
        int s = f >> 6, jt = f & 63;
        int j = tile*64 + jt;
        if (j < NT) p.a_g[((long)clip*8 + s)*NT + j] = a_tile[s][jt];
      }
    }
    return;
  }

  {
    float sp0[8], sp1[8], si0[8], si1[8];
    #pragma unroll
    for (int s = 0; s < 8; s++){
      sp0[s]=spssL[s*4+0]; sp1[s]=spssL[s*4+1]; si0[s]=spssL[s*4+2]; si1[s]=spssL[s*4+3];
    }
    int d0 = lane, d1 = lane + 64;
    float wg0a = p.Wg1[d0], wg1a = p.Wg1[DD+d0];
    float wg0b = p.Wg1[d1], wg1b = p.Wg1[DD+d1];
    float acc0[8], acc1[8];
    #pragma unroll
    for (int s = 0; s < 8; s++){ acc0[s]=0.f; acc1[s]=0.f; }
    for (int jj = wid; jj < 64; jj += 4){
      int j = tile*64 + jj;
      if (j >= NT) continue;
      float av0 = p.A_V[((long)(b*NT+j))*DD + d0];
      float av1 = p.A_V[((long)(b*NT+j))*DD + d1];
      float g0 = agt[jj][0], g1 = agt[jj][1];
      #pragma unroll
      for (int s = 0; s < 8; s++){
        float rel0 = (g0 - sp0[s])*si0[s];
        float rel1 = (g1 - sp1[s])*si1[s];
        float a = a_tile[s][jj];
        float hv0 = fmaxf(fmaf(rel0, wg0a, fmaf(rel1, wg1a, av0)), 0.f);
        float hv1 = fmaxf(fmaf(rel0, wg0b, fmaf(rel1, wg1b, av1)), 0.f);
        acc0[s] = fmaf(a, hv0, acc0[s]);
        acc1[s] = fmaf(a, hv1, acc1[s]);
      }
    }
    #pragma unroll
    for (int s = 0; s < 8; s++){ hpartL[wid][s][d0] = acc0[s]; hpartL[wid][s][d1] = acc1[s]; }
    __syncthreads();
    for (int f = tid; f < 1024; f += 256){
      int s = f >> 7, d = f & 127;
      p.hpart_g[((long)(b*7+tile)*8 + s)*136 + d] =
        hpartL[0][s][d] + hpartL[1][s][d] + hpartL[2][s][d] + hpartL[3][s][d];
    }
  }
}

// ---------- kB ----------
template<int LAST>
__global__ __launch_bounds__(256) void kB(PP p){
  __shared__ float red[8];
  __shared__ float sl[128];
  __shared__ float hb[128];
  __shared__ float scr[2304];
  int bs = blockIdx.x, b = bs >> 3, ss = bs & 7, tid = threadIdx.x;
  if (tid < 5){
    float v = 0.f;
    #pragma unroll
    for (int t7 = 0; t7 < 7; t7++) v += p.hpart_g[((long)(b*7+t7)*8 + ss)*136 + 128 + tid];
    red[tid] = v;
  }
  __syncthreads();
  float SA = red[0], inv = 1.f/SA;
  float Sp0 = red[1]*inv, Sp1 = red[2]*inv;
  float Ss0 = sqrtf(fmaxf(red[3]*inv - Sp0*Sp0, 0.f));
  float Ss1 = sqrtf(fmaxf(red[4]*inv - Sp1*Sp1, 0.f));

  if (LAST){
    if ((b % 5) == 2){
      int clip = b/5;
      long base = (long)NB*NS*DD + ((long)clip*8 + ss)*NT;
      const float* arow = p.a_g + ((long)clip*8 + ss)*NT;
      for (int j = tid; j < NT; j += 256) p.out[base+j] = arow[j]*inv;
    }
    if (tid < 128) sl[tid] = p.slots_g[(long)bs*128+tid];
    __syncthreads();
    int o = tid & 127, h = tid >> 7;
    float acc = 0.f;
    for (int k = 0; k < 64; k++) acc = fmaf(sl[h*64+k], p.fin_w[(h*64+k)*128+o], acc);
    scr[h*128+o] = acc;
    __syncthreads();
    if (tid < 128) p.out[(long)bs*128+tid] = p.fin_b[tid] + scr[tid] + scr[128+tid];
    return;
  }

  if (tid < 128){
    float v = 0.f;
    #pragma unroll
    for (int t7 = 0; t7 < 7; t7++) v += p.hpart_g[((long)(b*7+t7)*8 + ss)*136 + tid];
    hb[tid] = v * inv;
    sl[tid] = p.slots_g[(long)bs*128+tid];
  }
  __syncthreads();
  float* part = scr;
  float* upd  = scr + 256;
  float* gil  = scr + 384;
  float* ghl  = scr + 768;
  float* hnl  = scr + 1152;
  float* yv   = scr + 1280;
  float* h1   = scr + 1408;
  int o = tid & 127, h = tid >> 7;
  float acc2 = 0.f;
  for (int k = 0; k < 64; k++) acc2 = fmaf(hb[h*64+k], p.Wf2[(h*64+k)*128+o], acc2);
  part[h*128+o] = acc2;
  __syncthreads();
  if (tid < 128) upd[tid] = part[tid] + part[128+tid] + p.bf2[tid];
  __syncthreads();
  int oA = tid, oB = tid + 256;
  float giA = p.gru_b_ih[oA], ghA = p.gru_b_hh[oA];
  float giB = 0.f, ghB = 0.f;
  if (tid < 128){ giB = p.gru_b_ih[oB]; ghB = p.gru_b_hh[oB]; }
  for (int k = 0; k < 128; k++){
    float uk = upd[k], sk = sl[k];
    giA = fmaf(uk, p.gru_w_ih[k*384+oA], giA);
    ghA = fmaf(sk, p.gru_w_hh[k*384+oA], ghA);
    if (tid < 128){
      giB = fmaf(uk, p.gru_w_ih[k*384+oB], giB);
      ghB = fmaf(sk, p.gru_w_hh[k*384+oB], ghB);
    }
  }
  gil[oA] = giA; ghl[oA] = ghA;
  if (tid < 128){ gil[oB] = giB; ghl[oB] = ghB; }
  __syncthreads();
  float hnv = 0.f;
  if (tid < 128){
    float r = 1.f/(1.f+expf(-(gil[tid]+ghl[tid])));
    float z = 1.f/(1.f+expf(-(gil[128+tid]+ghl[128+tid])));
    float n = tanhf(gil[256+tid] + r*ghl[256+tid]);
    hnv = (1.f-z)*n + z*sl[tid];
  }
  float t1 = hnv, t2 = hnv*hnv;
  #pragma unroll
  for (int m = 1; m < 64; m <<= 1){ t1 += __shfl_xor(t1,m); t2 += __shfl_xor(t2,m); }
  if (tid < 128 && (tid & 63) == 0){ red[(tid>>6)*2] = t1; red[(tid>>6)*2+1] = t2; }
  __syncthreads();
  float mean = (red[0]+red[2])*(1.f/128.f);
  float var  = (red[1]+red[3])*(1.f/128.f) - mean*mean;
  float rstd = rsqrtf(var + 1e-5f);
  if (tid < 128){
    hnl[tid] = hnv;
    yv[tid] = (hnv-mean)*rstd*p.mlp_ln_g[tid] + p.mlp_ln_b[tid];
  }
  __syncthreads();
  float m1A = p.mlp_b1[tid], m1B = p.mlp_b1[tid+256];
  for (int k = 0; k < 128; k++){
    float y = yv[k];
    m1A = fmaf(y, p.mlp_w1[k*512+tid], m1A);
    m1B = fmaf(y, p.mlp_w1[k*512+tid+256], m1B);
  }
  h1[tid] = fmaxf(m1A, 0.f); h1[tid+256] = fmaxf(m1B, 0.f);
  __syncthreads();
  float a2 = 0.f;
  for (int kk = 0; kk < 256; kk++) a2 = fmaf(h1[h*256+kk], p.mlp_w2[(h*256+kk)*128+o], a2);
  part[h*128+o] = a2;
  __syncthreads();
  if (tid < 128){
    float sln = hnl[tid] + p.mlp_b2[tid] + part[tid] + part[128+tid];
    sl[tid] = sln;
    p.slots_g[(long)bs*128+tid] = sln;
  }
  __syncthreads();
  phase0g(p, bs, tid, scr, sl, Sp0, Sp1, Ss0, Ss1);
}

extern "C" void kernel_launch(void* const* d_in, const int* in_sizes, int n_in,
                              void* d_out, int out_size, void* d_ws, size_t ws_size,
                              hipStream_t stream){
  PP p;
  p.inputs=(const float*)d_in[0]; p.tok_idx=(const int*)d_in[1]; p.abs_grid=(const float*)d_in[2];
  p.slots_init=(const float*)d_in[3]; p.Sp_init=(const float*)d_in[4]; p.Ss_init=(const float*)d_in[5];
  p.WQ=(const float*)d_in[6]; p.ln_g=(const float*)d_in[7]; p.ln_b=(const float*)d_in[8];
  p.gru_w_ih=(const float*)d_in[9]; p.gru_w_hh=(const float*)d_in[10];
  p.gru_b_ih=(const float*)d_in[11]; p.gru_b_hh=(const float*)d_in[12];
  p.mlp_ln_g=(const float*)d_in[13]; p.mlp_ln_b=(const float*)d_in[14];
  p.mlp_w1=(const float*)d_in[15]; p.mlp_b1=(const float*)d_in[16];
  p.mlp_w2=(const float*)d_in[17]; p.mlp_b2=(const float*)d_in[18];
  p.WK=(const float*)d_in[19]; p.WV=(const float*)d_in[20]; p.Wg=(const float*)d_in[21]; p.bg=(const float*)d_in[22];
  p.Wf1=(const float*)d_in[23]; p.bf1=(const float*)d_in[24]; p.Wf2=(const float*)d_in[25]; p.bf2=(const float*)d_in[26];
  p.im_ln1_g=(const float*)d_in[27]; p.im_ln1_b=(const float*)d_in[28];
  p.im_w1=(const float*)d_in[29]; p.im_b1=(const float*)d_in[30];
  p.im_w2=(const float*)d_in[31]; p.im_b2=(const float*)d_in[32];
  p.im_ln2_g=(const float*)d_in[33]; p.im_ln2_b=(const float*)d_in[34];
  p.fin_w=(const float*)d_in[35]; p.fin_b=(const float*)d_in[36];

  float* w = (float*)d_ws;
  size_t need = 0;
  auto alloc = [&](size_t nfl){ nfl = (nfl + 3) & ~(size_t)3; float* r = w + need; need += nfl; return r; };
  p.x    = alloc((size_t)NTOT*DD);
  p.A_K  = alloc((size_t)NTOT*DD);
  p.A_V  = alloc((size_t)NTOT*DD);
  p.WKf  = alloc(DD*DD);
  p.WVf  = alloc(DD*DD);
  p.Wg1  = alloc(2*DD);
  p.c1   = alloc(DD);
  p.Wf2T = alloc(DD*DD);
  p.slots_g = alloc(320*128);
  p.qw_g    = alloc(320*128);
  p.qb_g    = alloc(320);
  p.spss_g  = alloc(320*4);
  p.hpart_g = alloc((size_t)280*8*136);
  p.a_g     = alloc((size_t)8*8*NT);
  p.xnh  = (ushort*)alloc((size_t)NTOT*DIN/2);
  p.xnl  = (ushort*)alloc((size_t)NTOT*DIN/2);
  p.hh   = (ushort*)alloc((size_t)NTOT*DIN/2);
  p.hl   = (ushort*)alloc((size_t)NTOT*DIN/2);
  p.W1Th = (ushort*)alloc((size_t)DIN*DIN/2);
  p.W1Tl = (ushort*)alloc((size_t)DIN*DIN/2);
  p.W2Th = (ushort*)alloc((size_t)DD*DIN/2);
  p.W2Tl = (ushort*)alloc((size_t)DD*DIN/2);
  p.out = (float*)d_out;
  if (ws_size < need*sizeof(float)){
    fprintf(stderr, "kernel_launch: ws too small (%zu < %zu)\n", ws_size, need*sizeof(float));
    return;
  }

  prep_weights<<<dim3(DD), dim3(128), 0, stream>>>(p);
  transpose_split<<<dim3(DIN/64, DIN/64), dim3(256), 0, stream>>>(p.im_w1, p.W1Th, p.W1Tl, DIN, DIN);
  transpose_split<<<dim3(DIN/64, DD/64), dim3(256), 0, stream>>>(p.im_w2, p.W2Th, p.W2Tl, DIN, DD);
  ln1_split<<<dim3(NTOT/4), dim3(256), 0, stream>>>(p);
  gemm1_128<<<dim3(832), dim3(256), 0, stream>>>(p);
  gemm_split2<<<dim3(1, (NTOT+63)/64), dim3(256), 0, stream>>>(
      p.hh, p.hl, p.W2Th, p.W2Tl, p.im_b2,
      p.x, p.im_ln2_g, p.im_ln2_b, NTOT);
  k2_proj<<<dim3((NTOT+31)/32), dim3(256), 0, stream>>>(p);
  k_init<<<dim3(320), dim3(256), 0, stream>>>(p);

  for (int t = 0; t < 3; t++){
    kA<0><<<dim3(NB*7), dim3(256), 0, stream>>>(p);
    kB<0><<<dim3(320), dim3(256), 0, stream>>>(p);
  }
  kA<1><<<dim3(NB*7), dim3(256), 0, stream>>>(p);
  kB<1><<<dim3(320), dim3(256), 0, stream>>>(p);
}

// Round 12
// 438.245 us; speedup vs baseline: 3.3332x; 1.0534x over previous
//
#include <hip/hip_runtime.h>
#include <cstdio>

#define NB 40
#define NS 8
#define NT 441
#define DIN 768
#define DD 128
#define NTOT (NB*NT)
#define FSCALE 0.08838834764831843f

typedef short s8v __attribute__((ext_vector_type(8)));
typedef float f4v __attribute__((ext_vector_type(4)));

__device__ inline ushort f2bf(float f){
  unsigned u = __float_as_uint(f);
  unsigned r = (u + 0x7fffu + ((u >> 16) & 1u)) >> 16;
  return (ushort)r;
}
__device__ inline float bf2f(ushort h){ return __uint_as_float(((unsigned)h) << 16); }

struct PP {
  const float *inputs; const int *tok_idx; const float *abs_grid;
  const float *slots_init, *Sp_init, *Ss_init;
  const float *WQ, *ln_g, *ln_b;
  const float *gru_w_ih, *gru_w_hh, *gru_b_ih, *gru_b_hh;
  const float *mlp_ln_g, *mlp_ln_b, *mlp_w1, *mlp_b1, *mlp_w2, *mlp_b2;
  const float *WK, *WV, *Wg, *bg, *Wf1, *bf1, *Wf2, *bf2;
  const float *im_ln1_g, *im_ln1_b, *im_w1, *im_b1, *im_w2, *im_b2, *im_ln2_g, *im_ln2_b;
  const float *fin_w, *fin_b;
  float *A_K, *A_V, *Wg1, *c1, *Wf2T;
  float *slots_g, *qw_g, *qb_g, *spss_g, *hpart_g, *a_g;
  ushort *xnh, *xnl, *hh, *hl, *W1Th, *W1Tl, *W2Th, *W2Tl;
  ushort *WKfTh, *WKfTl, *WVfTh, *WVfTl;
  float *out;
};

// ---------- weight prep: WKfT/WVfT (bf16 split, [n][k]), Wg1, c1, Wf2T ----------
__global__ __launch_bounds__(128) void prep_weights(PP p){
  int r = blockIdx.x, d = threadIdx.x;     // r = k index, d = n index
  float accK = 0.f, accV = 0.f;
  for (int kk = 0; kk < DD; kk++){
    float w = p.Wf1[kk*DD + d];
    accK = fmaf(p.WK[r*DD+kk], w, accK);
    accV = fmaf(p.WV[r*DD+kk], w, accV);
  }
  ushort hk = f2bf(accK), hv = f2bf(accV);
  p.WKfTh[d*DD + r] = hk; p.WKfTl[d*DD + r] = f2bf(accK - bf2f(hk));
  p.WVfTh[d*DD + r] = hv; p.WVfTl[d*DD + r] = f2bf(accV - bf2f(hv));
  if (r < 2){
    float a = 0.f;
    for (int kk = 0; kk < DD; kk++) a = fmaf(p.Wg[r*DD+kk], p.Wf1[kk*DD+d], a);
    p.Wg1[r*DD+d] = a;
  }
  if (r == 2){
    float a = 0.f;
    for (int kk = 0; kk < DD; kk++) a = fmaf(p.bg[kk], p.Wf1[kk*DD+d], a);
    p.c1[d] = a + p.bf1[d];
  }
  p.Wf2T[d*DD + r] = p.Wf2[r*DD + d];
}

// ---------- combined transpose + bf16 split for im_w1 and im_w2 ----------
__global__ __launch_bounds__(256) void transpose_both(PP p){
  __shared__ float tile[64][65];
  int t = blockIdx.x;
  const float* W; ushort *WTh, *WTl; int N, k0, n0;
  if (t < 144){ W = p.im_w1; WTh = p.W1Th; WTl = p.W1Tl; N = 768; k0 = (t/12)*64; n0 = (t%12)*64; }
  else { t -= 144; W = p.im_w2; WTh = p.W2Th; WTl = p.W2Tl; N = 128; k0 = (t/2)*64; n0 = (t&1)*64; }
  int tid = threadIdx.x;
  #pragma unroll
  for (int i = 0; i < 4; i++){
    int k = i*16 + (tid >> 4);
    int n4 = (tid & 15) * 4;
    float4 v = *(const float4*)(W + (long)(k0+k)*N + n0 + n4);
    tile[k][n4+0] = v.x; tile[k][n4+1] = v.y; tile[k][n4+2] = v.z; tile[k][n4+3] = v.w;
  }
  __syncthreads();
  #pragma unroll
  for (int i = 0; i < 4; i++){
    int n = i*16 + (tid >> 4);
    int k4 = (tid & 15) * 4;
    ushort4 h4, l4;
    float v0 = tile[k4+0][n], v1 = tile[k4+1][n], v2 = tile[k4+2][n], v3 = tile[k4+3][n];
    h4.x = f2bf(v0); l4.x = f2bf(v0 - bf2f(h4.x));
    h4.y = f2bf(v1); l4.y = f2bf(v1 - bf2f(h4.y));
    h4.z = f2bf(v2); l4.z = f2bf(v2 - bf2f(h4.z));
    h4.w = f2bf(v3); l4.w = f2bf(v3 - bf2f(h4.w));
    *(ushort4*)(WTh + (long)(n0+n)*DIN + k0 + k4) = h4;
    *(ushort4*)(WTl + (long)(n0+n)*DIN + k0 + k4) = l4;
  }
}

// ---------- phase0 ----------
__device__ void phase0g(const PP& p, int bs, int tid, float* scr, const float* sl,
                        float Sp0, float Sp1, float Ss0, float Ss1){
  float* sn   = scr;
  float* qv   = scr + 128;
  float* part = scr + 256;
  float* red  = scr + 512;
  int o = tid & 127, h = tid >> 7;
  float v = (tid < 128) ? sl[tid] : 0.f;
  float s1 = v, s2 = v*v;
  #pragma unroll
  for (int m = 1; m < 64; m <<= 1){ s1 += __shfl_xor(s1,m); s2 += __shfl_xor(s2,m); }
  if (tid < 128 && (tid & 63) == 0){ red[(tid>>6)*2] = s1; red[(tid>>6)*2+1] = s2; }
  __syncthreads();
  float mean = (red[0]+red[2])*(1.f/128.f);
  float var  = (red[1]+red[3])*(1.f/128.f) - mean*mean;
  float rstd = rsqrtf(var + 1e-5f);
  if (tid < 128) sn[tid] = (v-mean)*rstd*p.ln_g[tid] + p.ln_b[tid];
  __syncthreads();
  float acc = 0.f;
  for (int k = 0; k < 64; k++) acc = fmaf(sn[h*64+k], p.WQ[(h*64+k)*128+o], acc);
  part[h*128+o] = acc;
  __syncthreads();
  if (tid < 128) qv[tid] = part[tid] + part[128+tid];
  __syncthreads();
  float acc2 = 0.f;
  for (int k = 0; k < 64; k++) acc2 = fmaf(qv[h*64+k], p.Wf2T[(h*64+k)*128+o], acc2);
  part[h*128+o] = acc2;
  __syncthreads();
  if (tid < 128) p.qw_g[(long)bs*128+tid] = part[tid] + part[128+tid];
  float pb = (tid < 128) ? qv[tid]*p.bf2[tid] : 0.f;
  #pragma unroll
  for (int m = 1; m < 64; m <<= 1) pb += __shfl_xor(pb,m);
  if ((tid & 63) == 0) red[4 + (tid>>6)] = pb;
  __syncthreads();
  if (tid == 0){
    p.qb_g[bs] = FSCALE*(red[4]+red[5]+red[6]+red[7]);
    p.spss_g[bs*4+0] = Sp0; p.spss_g[bs*4+1] = Sp1;
    p.spss_g[bs*4+2] = 1.f/(Ss0*5.0f); p.spss_g[bs*4+3] = 1.f/(Ss1*5.0f);
  }
}

// ---------- LN1+split (blocks 0..4409) and slot init (blocks 4410..4729) ----------
__global__ __launch_bounds__(256) void ln1_init(PP p){
  __shared__ float sl[128];
  __shared__ float scr[520];
  if (blockIdx.x < 4410){
    int tok = blockIdx.x*4 + (threadIdx.x >> 6);
    int l = threadIdx.x & 63;
    const float* src = p.inputs + (long)tok*DIN;
    float4 v[3];
    float s = 0.f, s2 = 0.f;
    #pragma unroll
    for (int pp = 0; pp < 3; pp++){
      v[pp] = *(const float4*)(src + pp*256 + l*4);
      s  += v[pp].x + v[pp].y + v[pp].z + v[pp].w;
      s2 += v[pp].x*v[pp].x + v[pp].y*v[pp].y + v[pp].z*v[pp].z + v[pp].w*v[pp].w;
    }
    #pragma unroll
    for (int m = 1; m < 64; m <<= 1){ s += __shfl_xor(s, m); s2 += __shfl_xor(s2, m); }
    float mean = s*(1.f/DIN), var = s2*(1.f/DIN) - mean*mean;
    float rstd = rsqrtf(var + 1e-5f);
    #pragma unroll
    for (int pp = 0; pp < 3; pp++){
      int idx = pp*256 + l*4;
      float4 g = *(const float4*)(p.im_ln1_g + idx);
      float4 b = *(const float4*)(p.im_ln1_b + idx);
      float y0 = (v[pp].x-mean)*rstd*g.x + b.x;
      float y1 = (v[pp].y-mean)*rstd*g.y + b.y;
      float y2 = (v[pp].z-mean)*rstd*g.z + b.z;
      float y3 = (v[pp].w-mean)*rstd*g.w + b.w;
      ushort4 h4, l4;
      h4.x = f2bf(y0); l4.x = f2bf(y0 - bf2f(h4.x));
      h4.y = f2bf(y1); l4.y = f2bf(y1 - bf2f(h4.y));
      h4.z = f2bf(y2); l4.z = f2bf(y2 - bf2f(h4.z));
      h4.w = f2bf(y3); l4.w = f2bf(y3 - bf2f(h4.w));
      *(ushort4*)(p.xnh + (long)tok*DIN + idx) = h4;
      *(ushort4*)(p.xnl + (long)tok*DIN + idx) = l4;
    }
  } else {
    int bs = blockIdx.x - 4410, ss = bs & 7, tid = threadIdx.x;
    if (tid < 128){
      float v = p.slots_init[ss*128+tid];
      sl[tid] = v;
      p.slots_g[(long)bs*128+tid] = v;
    }
    __syncthreads();
    phase0g(p, bs, tid, scr, sl,
            p.Sp_init[ss*2], p.Sp_init[ss*2+1], p.Ss_init[ss*2], p.Ss_init[ss*2+1]);
  }
}

// ---------- GEMM1: 128x128 tile, XCD-aware m-grouping, bias+relu+split epilogue ----------
__global__ __launch_bounds__(256) void gemm1_128(PP p){
  __shared__ __align__(16) ushort As[2][128][40];
  __shared__ __align__(16) ushort Bs[2][128][40];
  int id = blockIdx.x;
  int xcd = id & 7, idx = id >> 3;
  int m_t = xcd + 8*(idx/6), n_t = idx % 6;
  if (m_t >= 138) return;
  int m0 = m_t*128, n0 = n_t*128;
  int tid = threadIdx.x;
  int w = tid >> 6, lane = tid & 63;
  int wm = w >> 1, wn = w & 1;
  f4v acc[4][4];
  #pragma unroll
  for (int mf = 0; mf < 4; mf++)
    #pragma unroll
    for (int nf = 0; nf < 4; nf++) acc[mf][nf] = (f4v)(0.f);

  for (int kb = 0; kb < DIN; kb += 32){
    __syncthreads();
    #pragma unroll
    for (int i = 0; i < 4; i++){
      int c = tid + i*256;
      int s = c >> 9, rem = c & 511;
      int r = rem >> 2, kg = rem & 3;
      int gr = min(m0 + r, NTOT-1);
      const float4 va = *(const float4*)((s ? p.xnl : p.xnh) + (long)gr*DIN + kb + kg*8);
      *(float4*)(&As[s][r][kg*8]) = va;
      const float4 vb = *(const float4*)((s ? p.W1Tl : p.W1Th) + (long)(n0 + r)*DIN + kb + kg*8);
      *(float4*)(&Bs[s][r][kg*8]) = vb;
    }
    __syncthreads();
    int kg = lane >> 4, rA = lane & 15;
    s8v a0[4], a1[4], b0[4], b1[4];
    #pragma unroll
    for (int mf = 0; mf < 4; mf++){
      a0[mf] = *(const s8v*)(&As[0][wm*64 + mf*16 + rA][kg*8]);
      a1[mf] = *(const s8v*)(&As[1][wm*64 + mf*16 + rA][kg*8]);
    }
    #pragma unroll
    for (int nf = 0; nf < 4; nf++){
      b0[nf] = *(const s8v*)(&Bs[0][wn*64 + nf*16 + rA][kg*8]);
      b1[nf] = *(const s8v*)(&Bs[1][wn*64 + nf*16 + rA][kg*8]);
    }
    #pragma unroll
    for (int mf = 0; mf < 4; mf++)
      #pragma unroll
      for (int nf = 0; nf < 4; nf++){
        acc[mf][nf] = __builtin_amdgcn_mfma_f32_16x16x32_bf16(a0[mf], b0[nf], acc[mf][nf], 0, 0, 0);
        acc[mf][nf] = __builtin_amdgcn_mfma_f32_16x16x32_bf16(a0[mf], b1[nf], acc[mf][nf], 0, 0, 0);
        acc[mf][nf] = __builtin_amdgcn_mfma_f32_16x16x32_bf16(a1[mf], b0[nf], acc[mf][nf], 0, 0, 0);
      }
  }

  int rbase = (lane >> 4) * 4, cn = lane & 15;
  #pragma unroll
  for (int mf = 0; mf < 4; mf++)
    #pragma unroll
    for (int nf = 0; nf < 4; nf++){
      int n = n0 + wn*64 + nf*16 + cn;
      float bs = p.im_b1[n];
      #pragma unroll
      for (int r = 0; r < 4; r++){
        int m = m0 + wm*64 + mf*16 + rbase + r;
        if (m < NTOT){
          float v = fmaxf(acc[mf][nf][r] + bs, 0.f);
          ushort h = f2bf(v);
          p.hh[(long)m*DIN + n] = h;
          p.hl[(long)m*DIN + n] = f2bf(v - bf2f(h));
        }
      }
    }
}

// ---------- GEMM2 fused: h@W2 + b2 -> LN -> x (bf16 split in LDS) -> A_K/A_V via MFMA ----------
__global__ __launch_bounds__(256) void gemm2_fused(PP p){
  extern __shared__ __align__(16) char smem[];
  ushort* As = (ushort*)smem;                // [2][64][40]  = 10240 B
  ushort* Bs = (ushort*)(smem + 10240);      // [2][128][40] = 20480 B
  float*  Dl = (float*)smem;                 // [64][132]    = 33792 B (aliases As/Bs)
  ushort* xsh = (ushort*)(smem + 33792);     // [64][136]    = 17408 B
  ushort* xsl = (ushort*)(smem + 33792 + 17408);
  int m0 = blockIdx.x * 64;
  int tid = threadIdx.x, w = tid >> 6, lane = tid & 63;
  f4v acc[4][2];
  #pragma unroll
  for (int mf = 0; mf < 4; mf++)
    #pragma unroll
    for (int nf = 0; nf < 2; nf++) acc[mf][nf] = (f4v)(0.f);

  for (int kb = 0; kb < DIN; kb += 32){
    __syncthreads();
    #pragma unroll
    for (int i = 0; i < 2; i++){
      int c = tid + i*256;
      int s = c >> 8, r = (c >> 2) & 63, kg = c & 3;
      int gr = min(m0 + r, NTOT-1);
      const float4 va = *(const float4*)((s ? p.hl : p.hh) + (long)gr*DIN + kb + kg*8);
      *(float4*)(As + s*2560 + r*40 + kg*8) = va;
    }
    #pragma unroll
    for (int i = 0; i < 4; i++){
      int c = tid + i*256;
      int s = c >> 9, r = (c >> 2) & 127, kg = c & 3;
      const float4 vb = *(const float4*)((s ? p.W2Tl : p.W2Th) + (long)r*DIN + kb + kg*8);
      *(float4*)(Bs + s*5120 + r*40 + kg*8) = vb;
    }
    __syncthreads();
    int kg = lane >> 4, rA = lane & 15;
    s8v a0[4], a1[4], b0[2], b1[2];
    #pragma unroll
    for (int mf = 0; mf < 4; mf++){
      a0[mf] = *(const s8v*)(As +        (mf*16 + rA)*40 + kg*8);
      a1[mf] = *(const s8v*)(As + 2560 + (mf*16 + rA)*40 + kg*8);
    }
    #pragma unroll
    for (int nf = 0; nf < 2; nf++){
      int rb = w*32 + nf*16 + rA;
      b0[nf] = *(const s8v*)(Bs +        rb*40 + kg*8);
      b1[nf] = *(const s8v*)(Bs + 5120 + rb*40 + kg*8);
    }
    #pragma unroll
    for (int mf = 0; mf < 4; mf++)
      #pragma unroll
      for (int nf = 0; nf < 2; nf++){
        acc[mf][nf] = __builtin_amdgcn_mfma_f32_16x16x32_bf16(a0[mf], b0[nf], acc[mf][nf], 0, 0, 0);
        acc[mf][nf] = __builtin_amdgcn_mfma_f32_16x16x32_bf16(a0[mf], b1[nf], acc[mf][nf], 0, 0, 0);
        acc[mf][nf] = __builtin_amdgcn_mfma_f32_16x16x32_bf16(a1[mf], b0[nf], acc[mf][nf], 0, 0, 0);
      }
  }

  int rbase = (lane >> 4) * 4, cn = lane & 15;
  __syncthreads();
  #pragma unroll
  for (int mf = 0; mf < 4; mf++)
    #pragma unroll
    for (int nf = 0; nf < 2; nf++){
      int n = w*32 + nf*16 + cn;
      float bs = p.im_b2[n];
      #pragma unroll
      for (int r = 0; r < 4; r++)
        Dl[(mf*16 + rbase + r)*132 + n] = acc[mf][nf][r] + bs;
    }
  __syncthreads();
  // LN per row -> bf16 split into xsh/xsl
  for (int rr = 0; rr < 16; rr++){
    int row = w*16 + rr;
    float e0 = Dl[row*132 + lane], e1 = Dl[row*132 + 64 + lane];
    float s = e0 + e1, s2 = e0*e0 + e1*e1;
    #pragma unroll
    for (int m2 = 1; m2 < 64; m2 <<= 1){ s += __shfl_xor(s, m2); s2 += __shfl_xor(s2, m2); }
    float mean = s*(1.f/DD), var = s2*(1.f/DD) - mean*mean;
    float rstd = rsqrtf(var + 1e-5f);
    float x0 = (e0-mean)*rstd*p.im_ln2_g[lane]    + p.im_ln2_b[lane];
    float x1 = (e1-mean)*rstd*p.im_ln2_g[64+lane] + p.im_ln2_b[64+lane];
    ushort h0 = f2bf(x0), h1 = f2bf(x1);
    xsh[row*136 + lane]      = h0;  xsl[row*136 + lane]      = f2bf(x0 - bf2f(h0));
    xsh[row*136 + 64 + lane] = h1;  xsl[row*136 + 64 + lane] = f2bf(x1 - bf2f(h1));
  }
  __syncthreads();
  // A_K/A_V: wave w -> rows w*16..w*16+15, 3-pass split MFMA vs WKfT/WVfT
  int kg = lane >> 4, rA = lane & 15;
  f4v aK[8], aV[8];
  #pragma unroll
  for (int nf = 0; nf < 8; nf++){ aK[nf] = (f4v)(0.f); aV[nf] = (f4v)(0.f); }
  #pragma unroll
  for (int kb2 = 0; kb2 < 4; kb2++){
    s8v ah = *(const s8v*)&xsh[(w*16+rA)*136 + kb2*32 + kg*8];
    s8v al = *(const s8v*)&xsl[(w*16+rA)*136 + kb2*32 + kg*8];
    #pragma unroll
    for (int nf = 0; nf < 8; nf++){
      int n = nf*16 + rA;
      s8v bh = *(const s8v*)(p.WKfTh + n*DD + kb2*32 + kg*8);
      s8v bl = *(const s8v*)(p.WKfTl + n*DD + kb2*32 + kg*8);
      aK[nf] = __builtin_amdgcn_mfma_f32_16x16x32_bf16(ah, bh, aK[nf], 0, 0, 0);
      aK[nf] = __builtin_amdgcn_mfma_f32_16x16x32_bf16(ah, bl, aK[nf], 0, 0, 0);
      aK[nf] = __builtin_amdgcn_mfma_f32_16x16x32_bf16(al, bh, aK[nf], 0, 0, 0);
      s8v ch = *(const s8v*)(p.WVfTh + n*DD + kb2*32 + kg*8);
      s8v cl = *(const s8v*)(p.WVfTl + n*DD + kb2*32 + kg*8);
      aV[nf] = __builtin_amdgcn_mfma_f32_16x16x32_bf16(ah, ch, aV[nf], 0, 0, 0);
      aV[nf] = __builtin_amdgcn_mfma_f32_16x16x32_bf16(ah, cl, aV[nf], 0, 0, 0);
      aV[nf] = __builtin_amdgcn_mfma_f32_16x16x32_bf16(al, ch, aV[nf], 0, 0, 0);
    }
  }
  #pragma unroll
  for (int nf = 0; nf < 8; nf++){
    int n = nf*16 + cn;
    float c = p.c1[n];
    #pragma unroll
    for (int r = 0; r < 4; r++){
      int m = m0 + w*16 + rbase + r;
      if (m < NTOT){
        p.A_K[(long)m*DD + n] = aK[nf][r] + c;
        p.A_V[(long)m*DD + n] = aV[nf][r] + c;
      }
    }
  }
}

// ---------- kA ----------
template<int LAST>
__global__ __launch_bounds__(256) void kA(PP p){
  int b = blockIdx.x / 7, tile = blockIdx.x % 7;
  int tid = threadIdx.x, wid = tid >> 6, lane = tid & 63;
  __shared__ float qws[8][132];
  __shared__ float qbs[8];
  __shared__ float spssL[32];
  __shared__ float agt[64][2];
  __shared__ float a_tile[8][64];
  __shared__ float hpartL[4][8][128];
  for (int f = tid; f < 8*128; f += 256){
    int s = f >> 7, d = f & 127;
    qws[s][(d&31)*4 + (d>>5)] = p.qw_g[((long)b*8+s)*128 + d];
  }
  if (tid < 8)  qbs[tid] = p.qb_g[b*8+tid];
  if (tid < 32) spssL[tid] = p.spss_g[b*32+tid];
  if (tid < 64){
    int j = tile*64 + tid;
    float g0 = 0.f, g1 = 0.f;
    if (j < NT){ int idx = p.tok_idx[b*NT+j]; g0 = p.abs_grid[idx*2]; g1 = p.abs_grid[idx*2+1]; }
    agt[tid][0] = g0; agt[tid][1] = g1;
  }
  __syncthreads();

  {
    int tl = lane >> 2, dg = lane & 3;
    int jtok = wid*16 + tl, j = tile*64 + jtok;
    bool valid = j < NT;
    int jc = valid ? j : 0;
    float aa[32], w0[32], w1[32];
    const float* src = p.A_K + ((long)(b*NT+jc))*DD + dg*32;
    #pragma unroll
    for (int i4 = 0; i4 < 8; i4++){
      float4 t = *(const float4*)(src + i4*4);
      aa[i4*4+0]=t.x; aa[i4*4+1]=t.y; aa[i4*4+2]=t.z; aa[i4*4+3]=t.w;
    }
    #pragma unroll
    for (int i4 = 0; i4 < 8; i4++){
      float4 t0 = *(const float4*)(p.Wg1 + dg*32 + i4*4);
      float4 t1 = *(const float4*)(p.Wg1 + DD + dg*32 + i4*4);
      w0[i4*4+0]=t0.x; w0[i4*4+1]=t0.y; w0[i4*4+2]=t0.z; w0[i4*4+3]=t0.w;
      w1[i4*4+0]=t1.x; w1[i4*4+1]=t1.y; w1[i4*4+2]=t1.z; w1[i4*4+3]=t1.w;
    }
    float ag0 = agt[jtok][0], ag1 = agt[jtok][1];
    float dv[8];
    #pragma unroll
    for (int s = 0; s < 8; s++){
      float rel0 = (ag0 - spssL[s*4+0])*spssL[s*4+2];
      float rel1 = (ag1 - spssL[s*4+1])*spssL[s*4+3];
      float acc = 0.f;
      #pragma unroll
      for (int i = 0; i < 32; i++){
        float hk = fmaxf(fmaf(rel0, w0[i], fmaf(rel1, w1[i], aa[i])), 0.f);
        acc = fmaf(hk, qws[s][i*4+dg], acc);
      }
      acc += __shfl_xor(acc, 1); acc += __shfl_xor(acc, 2);
      dv[s] = acc*FSCALE + qbs[s];
    }
    if (dg == 0){
      float m = -1e30f;
      #pragma unroll
      for (int s = 0; s < 8; s++) m = fmaxf(m, dv[s]);
      float tot = 0.f;
      #pragma unroll
      for (int s = 0; s < 8; s++){ dv[s] = expf(dv[s]-m); tot += dv[s]; }
      float inv = 1.f/tot;
      #pragma unroll
      for (int s = 0; s < 8; s++)
        a_tile[s][jtok] = valid ? (dv[s]*inv + 1e-8f) : 0.f;
    }
  }
  __syncthreads();

  #pragma unroll
  for (int si = 0; si < 2; si++){
    int s = wid*2 + si;
    float a = a_tile[s][lane];
    float g0 = agt[lane][0], g1 = agt[lane][1];
    float v0 = a, v1 = a*g0, v2 = a*g1, v3 = a*g0*g0, v4 = a*g1*g1;
    #pragma unroll
    for (int m = 1; m < 64; m <<= 1){
      v0 += __shfl_xor(v0,m); v1 += __shfl_xor(v1,m); v2 += __shfl_xor(v2,m);
      v3 += __shfl_xor(v3,m); v4 += __shfl_xor(v4,m);
    }
    if (lane == 0){
      float* st = p.hpart_g + ((long)(b*7+tile)*8 + s)*136 + 128;
      st[0]=v0; st[1]=v1; st[2]=v2; st[3]=v3; st[4]=v4;
    }
  }

  if (LAST){
    if ((b % 5) == 2){
      int clip = b/5;
      for (int f = tid; f < 8*64; f += 256){
        int s = f >> 6, jt = f & 63;
        int j = tile*64 + jt;
        if (j < NT) p.a_g[((long)clip*8 + s)*NT + j] = a_tile[s][jt];
      }
    }
    return;
  }

  {
    float sp0[8], sp1[8], si0[8], si1[8];
    #pragma unroll
    for (int s = 0; s < 8; s++){
      sp0[s]=spssL[s*4+0]; sp1[s]=spssL[s*4+1]; si0[s]=spssL[s*4+2]; si1[s]=spssL[s*4+3];
    }
    int d0 = lane, d1 = lane + 64;
    float wg0a = p.Wg1[d0], wg1a = p.Wg1[DD+d0];
    float wg0b = p.Wg1[d1], wg1b = p.Wg1[DD+d1];
    float acc0[8], acc1[8];
    #pragma unroll
    for (int s = 0; s < 8; s++){ acc0[s]=0.f; acc1[s]=0.f; }
    for (int jj = wid; jj < 64; jj += 4){
      int j = tile*64 + jj;
      if (j >= NT) continue;
      float av0 = p.A_V[((long)(b*NT+j))*DD + d0];
      float av1 = p.A_V[((long)(b*NT+j))*DD + d1];
      float g0 = agt[jj][0], g1 = agt[jj][1];
      #pragma unroll
      for (int s = 0; s < 8; s++){
        float rel0 = (g0 - sp0[s])*si0[s];
        float rel1 = (g1 - sp1[s])*si1[s];
        float a = a_tile[s][jj];
        float hv0 = fmaxf(fmaf(rel0, wg0a, fmaf(rel1, wg1a, av0)), 0.f);
        float hv1 = fmaxf(fmaf(rel0, wg0b, fmaf(rel1, wg1b, av1)), 0.f);
        acc0[s] = fmaf(a, hv0, acc0[s]);
        acc1[s] = fmaf(a, hv1, acc1[s]);
      }
    }
    #pragma unroll
    for (int s = 0; s < 8; s++){ hpartL[wid][s][d0] = acc0[s]; hpartL[wid][s][d1] = acc1[s]; }
    __syncthreads();
    for (int f = tid; f < 1024; f += 256){
      int s = f >> 7, d = f & 127;
      p.hpart_g[((long)(b*7+tile)*8 + s)*136 + d] =
        hpartL[0][s][d] + hpartL[1][s][d] + hpartL[2][s][d] + hpartL[3][s][d];
    }
  }
}

// ---------- kB ----------
template<int LAST>
__global__ __launch_bounds__(256) void kB(PP p){
  __shared__ float red[8];
  __shared__ float sl[128];
  __shared__ float hb[128];
  __shared__ float scr[2304];
  int bs = blockIdx.x, b = bs >> 3, ss = bs & 7, tid = threadIdx.x;
  if (tid < 5){
    float v = 0.f;
    #pragma unroll
    for (int t7 = 0; t7 < 7; t7++) v += p.hpart_g[((long)(b*7+t7)*8 + ss)*136 + 128 + tid];
    red[tid] = v;
  }
  __syncthreads();
  float SA = red[0], inv = 1.f/SA;
  float Sp0 = red[1]*inv, Sp1 = red[2]*inv;
  float Ss0 = sqrtf(fmaxf(red[3]*inv - Sp0*Sp0, 0.f));
  float Ss1 = sqrtf(fmaxf(red[4]*inv - Sp1*Sp1, 0.f));

  if (LAST){
    if ((b % 5) == 2){
      int clip = b/5;
      long base = (long)NB*NS*DD + ((long)clip*8 + ss)*NT;
      const float* arow = p.a_g + ((long)clip*8 + ss)*NT;
      for (int j = tid; j < NT; j += 256) p.out[base+j] = arow[j]*inv;
    }
    if (tid < 128) sl[tid] = p.slots_g[(long)bs*128+tid];
    __syncthreads();
    int o = tid & 127, h = tid >> 7;
    float acc = 0.f;
    for (int k = 0; k < 64; k++) acc = fmaf(sl[h*64+k], p.fin_w[(h*64+k)*128+o], acc);
    scr[h*128+o] = acc;
    __syncthreads();
    if (tid < 128) p.out[(long)bs*128+tid] = p.fin_b[tid] + scr[tid] + scr[128+tid];
    return;
  }

  if (tid < 128){
    float v = 0.f;
    #pragma unroll
    for (int t7 = 0; t7 < 7; t7++) v += p.hpart_g[((long)(b*7+t7)*8 + ss)*136 + tid];
    hb[tid] = v * inv;
    sl[tid] = p.slots_g[(long)bs*128+tid];
  }
  __syncthreads();
  float* part = scr;
  float* upd  = scr + 256;
  float* gil  = scr + 384;
  float* ghl  = scr + 768;
  float* hnl  = scr + 1152;
  float* yv   = scr + 1280;
  float* h1   = scr + 1408;
  int o = tid & 127, h = tid >> 7;
  float acc2 = 0.f;
  for (int k = 0; k < 64; k++) acc2 = fmaf(hb[h*64+k], p.Wf2[(h*64+k)*128+o], acc2);
  part[h*128+o] = acc2;
  __syncthreads();
  if (tid < 128) upd[tid] = part[tid] + part[128+tid] + p.bf2[tid];
  __syncthreads();
  int oA = tid, oB = tid + 256;
  float giA = p.gru_b_ih[oA], ghA = p.gru_b_hh[oA];
  float giB = 0.f, ghB = 0.f;
  if (tid < 128){ giB = p.gru_b_ih[oB]; ghB = p.gru_b_hh[oB]; }
  for (int k = 0; k < 128; k++){
    float uk = upd[k], sk = sl[k];
    giA = fmaf(uk, p.gru_w_ih[k*384+oA], giA);
    ghA = fmaf(sk, p.gru_w_hh[k*384+oA], ghA);
    if (tid < 128){
      giB = fmaf(uk, p.gru_w_ih[k*384+oB], giB);
      ghB = fmaf(sk, p.gru_w_hh[k*384+oB], ghB);
    }
  }
  gil[oA] = giA; ghl[oA] = ghA;
  if (tid < 128){ gil[oB] = giB; ghl[oB] = ghB; }
  __syncthreads();
  float hnv = 0.f;
  if (tid < 128){
    float r = 1.f/(1.f+expf(-(gil[tid]+ghl[tid])));
    float z = 1.f/(1.f+expf(-(gil[128+tid]+ghl[128+tid])));
    float n = tanhf(gil[256+tid] + r*ghl[256+tid]);
    hnv = (1.f-z)*n + z*sl[tid];
  }
  float t1 = hnv, t2 = hnv*hnv;
  #pragma unroll
  for (int m = 1; m < 64; m <<= 1){ t1 += __shfl_xor(t1,m); t2 += __shfl_xor(t2,m); }
  if (tid < 128 && (tid & 63) == 0){ red[(tid>>6)*2] = t1; red[(tid>>6)*2+1] = t2; }
  __syncthreads();
  float mean = (red[0]+red[2])*(1.f/128.f);
  float var  = (red[1]+red[3])*(1.f/128.f) - mean*mean;
  float rstd = rsqrtf(var + 1e-5f);
  if (tid < 128){
    hnl[tid] = hnv;
    yv[tid] = (hnv-mean)*rstd*p.mlp_ln_g[tid] + p.mlp_ln_b[tid];
  }
  __syncthreads();
  float m1A = p.mlp_b1[tid], m1B = p.mlp_b1[tid+256];
  for (int k = 0; k < 128; k++){
    float y = yv[k];
    m1A = fmaf(y, p.mlp_w1[k*512+tid], m1A);
    m1B = fmaf(y, p.mlp_w1[k*512+tid+256], m1B);
  }
  h1[tid] = fmaxf(m1A, 0.f); h1[tid+256] = fmaxf(m1B, 0.f);
  __syncthreads();
  float a2 = 0.f;
  for (int kk = 0; kk < 256; kk++) a2 = fmaf(h1[h*256+kk], p.mlp_w2[(h*256+kk)*128+o], a2);
  part[h*128+o] = a2;
  __syncthreads();
  if (tid < 128){
    float sln = hnl[tid] + p.mlp_b2[tid] + part[tid] + part[128+tid];
    sl[tid] = sln;
    p.slots_g[(long)bs*128+tid] = sln;
  }
  __syncthreads();
  phase0g(p, bs, tid, scr, sl, Sp0, Sp1, Ss0, Ss1);
}

extern "C" void kernel_launch(void* const* d_in, const int* in_sizes, int n_in,
                              void* d_out, int out_size, void* d_ws, size_t ws_size,
                              hipStream_t stream){
  PP p;
  p.inputs=(const float*)d_in[0]; p.tok_idx=(const int*)d_in[1]; p.abs_grid=(const float*)d_in[2];
  p.slots_init=(const float*)d_in[3]; p.Sp_init=(const float*)d_in[4]; p.Ss_init=(const float*)d_in[5];
  p.WQ=(const float*)d_in[6]; p.ln_g=(const float*)d_in[7]; p.ln_b=(const float*)d_in[8];
  p.gru_w_ih=(const float*)d_in[9]; p.gru_w_hh=(const float*)d_in[10];
  p.gru_b_ih=(const float*)d_in[11]; p.gru_b_hh=(const float*)d_in[12];
  p.mlp_ln_g=(const float*)d_in[13]; p.mlp_ln_b=(const float*)d_in[14];
  p.mlp_w1=(const float*)d_in[15]; p.mlp_b1=(const float*)d_in[16];
  p.mlp_w2=(const float*)d_in[17]; p.mlp_b2=(const float*)d_in[18];
  p.WK=(const float*)d_in[19]; p.WV=(const float*)d_in[20]; p.Wg=(const float*)d_in[21]; p.bg=(const float*)d_in[22];
  p.Wf1=(const float*)d_in[23]; p.bf1=(const float*)d_in[24]; p.Wf2=(const float*)d_in[25]; p.bf2=(const float*)d_in[26];
  p.im_ln1_g=(const float*)d_in[27]; p.im_ln1_b=(const float*)d_in[28];
  p.im_w1=(const float*)d_in[29]; p.im_b1=(const float*)d_in[30];
  p.im_w2=(const float*)d_in[31]; p.im_b2=(const float*)d_in[32];
  p.im_ln2_g=(const float*)d_in[33]; p.im_ln2_b=(const float*)d_in[34];
  p.fin_w=(const float*)d_in[35]; p.fin_b=(const float*)d_in[36];

  float* w = (float*)d_ws;
  size_t need = 0;
  auto alloc = [&](size_t nfl){ nfl = (nfl + 3) & ~(size_t)3; float* r = w + need; need += nfl; return r; };
  p.A_K  = alloc((size_t)NTOT*DD);
  p.A_V  = alloc((size_t)NTOT*DD);
  p.Wg1  = alloc(2*DD);
  p.c1   = alloc(DD);
  p.Wf2T = alloc(DD*DD);
  p.slots_g = alloc(320*128);
  p.qw_g    = alloc(320*128);
  p.qb_g    = alloc(320);
  p.spss_g  = alloc(320*4);
  p.hpart_g = alloc((size_t)280*8*136);
  p.a_g     = alloc((size_t)8*8*NT);
  p.xnh  = (ushort*)alloc((size_t)NTOT*DIN/2);
  p.xnl  = (ushort*)alloc((size_t)NTOT*DIN/2);
  p.hh   = (ushort*)alloc((size_t)NTOT*DIN/2);
  p.hl   = (ushort*)alloc((size_t)NTOT*DIN/2);
  p.W1Th = (ushort*)alloc((size_t)DIN*DIN/2);
  p.W1Tl = (ushort*)alloc((size_t)DIN*DIN/2);
  p.W2Th = (ushort*)alloc((size_t)DD*DIN/2);
  p.W2Tl = (ushort*)alloc((size_t)DD*DIN/2);
  p.WKfTh = (ushort*)alloc(DD*DD/2);
  p.WKfTl = (ushort*)alloc(DD*DD/2);
  p.WVfTh = (ushort*)alloc(DD*DD/2);
  p.WVfTl = (ushort*)alloc(DD*DD/2);
  p.out = (float*)d_out;
  if (ws_size < need*sizeof(float)){
    fprintf(stderr, "kernel_launch: ws too small (%zu < %zu)\n", ws_size, need*sizeof(float));
    return;
  }

  prep_weights<<<dim3(DD), dim3(128), 0, stream>>>(p);
  transpose_both<<<dim3(168), dim3(256), 0, stream>>>(p);
  ln1_init<<<dim3(4730), dim3(256), 0, stream>>>(p);
  gemm1_128<<<dim3(832), dim3(256), 0, stream>>>(p);
  gemm2_fused<<<dim3((NTOT+63)/64), dim3(256), 68608, stream>>>(p);

  for (int t = 0; t < 3; t++){
    kA<0><<<dim3(NB*7), dim3(256), 0, stream>>>(p);
    kB<0><<<dim3(320), dim3(256), 0, stream>>>(p);
  }
  kA<1><<<dim3(NB*7), dim3(256), 0, stream>>>(p);
  kB<1><<<dim3(320), dim3(256), 0, stream>>>(p);
}